// Round 5
// baseline (1213.770 us; speedup 1.0000x reference)
//
#include <hip/hip_runtime.h>
#include <cstdint>

namespace {
constexpr int kN = 50000;          // nodes per encoder
constexpr int kE = 200000;         // directed edges per encoder (pre self-loop)
constexpr int kE2 = kE + kN;       // with self loops (per encoder)
constexpr int kG = 256;            // graphs per encoder
constexpr float kNegSlope = 0.2f;
}

using half8   = __attribute__((ext_vector_type(8))) _Float16;
using half4   = __attribute__((ext_vector_type(4))) _Float16;
using floatx4 = __attribute__((ext_vector_type(4))) float;

__device__ __forceinline__ void gld_lds16(const void* g, void* l) {
  __builtin_amdgcn_global_load_lds(
      (const __attribute__((address_space(1))) unsigned int*)g,
      (__attribute__((address_space(3))) unsigned int*)l, 16, 0, 0);
}

// ---------------- f16x3 MFMA GEMM: C[M,N] = A[M,K] @ B[K,N] ----------
// A row-major hi/lo f16 [M,K]; B pre-transposed hi/lo f16 [N,K].
// 128x128 tile, BK=32, 256 threads = 4 waves (64x64 each).
// LDS slot s holds (row=(s>>6)*16+(s&15), kchunk=(s>>4)&3); fragment read
// g*1024 + lane*16 => conflict-free ds_read_b128, lane-contiguous staging.
__global__ __launch_bounds__(256) void gemm_f16x3(
    const _Float16* __restrict__ Ah, const _Float16* __restrict__ Al,
    const _Float16* __restrict__ Bh, const _Float16* __restrict__ Bl,
    float* __restrict__ C, int M, int N, int K) {
  __shared__ alignas(16) char smem[32768];
  char* sAh = smem;
  char* sAl = smem + 8192;
  char* sBh = smem + 16384;
  char* sBl = smem + 24576;
  const int t = threadIdx.x;
  const int w = t >> 6;
  const int l = t & 63;
  const int bm = blockIdx.x * 128;
  const int bn = blockIdx.y * 128;
  const int wm = (w & 1) * 64;
  const int wn = (w >> 1) * 64;
  const int quad = l >> 4;
  const int lrow = l & 15;

  floatx4 acc[4][4];
#pragma unroll
  for (int mi = 0; mi < 4; ++mi)
#pragma unroll
    for (int ni = 0; ni < 4; ++ni) acc[mi][ni] = (floatx4){0.f, 0.f, 0.f, 0.f};

  for (int k0 = 0; k0 < K; k0 += 32) {
#pragma unroll
    for (int j = 0; j < 2; ++j) {
      const int s = w * 128 + j * 64 + l;          // slot id 0..511
      const int row = ((s >> 6) << 4) + (s & 15);  // 0..127
      const int q = (s >> 4) & 3;
      int ga = bm + row;
      ga = (ga < M) ? ga : (M - 1);                // clamp: keep lanes active
      const size_t aofs = (size_t)ga * K + k0 + q * 8;
      const size_t bofs = (size_t)(bn + row) * K + k0 + q * 8;
      gld_lds16(Ah + aofs, sAh + s * 16);
      gld_lds16(Al + aofs, sAl + s * 16);
      gld_lds16(Bh + bofs, sBh + s * 16);
      gld_lds16(Bl + bofs, sBl + s * 16);
    }
    __syncthreads();
    half8 fah[4], fal[4], fbh[4], fbl[4];
#pragma unroll
    for (int mi = 0; mi < 4; ++mi) {
      const int g = (wm >> 4) + mi;
      fah[mi] = *(const half8*)(sAh + g * 1024 + l * 16);
      fal[mi] = *(const half8*)(sAl + g * 1024 + l * 16);
    }
#pragma unroll
    for (int ni = 0; ni < 4; ++ni) {
      const int g = (wn >> 4) + ni;
      fbh[ni] = *(const half8*)(sBh + g * 1024 + l * 16);
      fbl[ni] = *(const half8*)(sBl + g * 1024 + l * 16);
    }
#pragma unroll
    for (int mi = 0; mi < 4; ++mi)
#pragma unroll
      for (int ni = 0; ni < 4; ++ni) {
        acc[mi][ni] = __builtin_amdgcn_mfma_f32_16x16x32_f16(fal[mi], fbh[ni],
                                                             acc[mi][ni], 0, 0, 0);
        acc[mi][ni] = __builtin_amdgcn_mfma_f32_16x16x32_f16(fah[mi], fbl[ni],
                                                             acc[mi][ni], 0, 0, 0);
        acc[mi][ni] = __builtin_amdgcn_mfma_f32_16x16x32_f16(fah[mi], fbh[ni],
                                                             acc[mi][ni], 0, 0, 0);
      }
    __syncthreads();
  }
  // epilogue: C/D layout col=lane&15, row=quad*4+reg
#pragma unroll
  for (int mi = 0; mi < 4; ++mi) {
    const int rbase = bm + wm + mi * 16 + quad * 4;
#pragma unroll
    for (int r = 0; r < 4; ++r) {
      const int grow = rbase + r;
      if (grow < M) {
#pragma unroll
        for (int ni = 0; ni < 4; ++ni) {
          C[(size_t)grow * N + bn + wn + ni * 16 + lrow] = acc[mi][ni][r];
        }
      }
    }
  }
}

// ---------------- weight transpose + f16 split: W[K,N] -> Wt[N,K] -----
__global__ void wt_split(const float* __restrict__ W, _Float16* __restrict__ Th,
                         _Float16* __restrict__ Tl, int K, int N) {
  const int idx = blockIdx.x * blockDim.x + threadIdx.x;
  if (idx >= K * N) return;
  const int k = idx / N;
  const int n = idx - k * N;
  const float v = W[idx];
  const _Float16 h = (_Float16)v;
  Th[n * K + k] = h;
  Tl[n * K + k] = (_Float16)(v - (float)h);
}

// ---------------- row-major fp32 -> f16 hi/lo split -------------------
__global__ void split16(const float* __restrict__ X, _Float16* __restrict__ Xh,
                        _Float16* __restrict__ Xl, int total) {
  const int idx = blockIdx.x * blockDim.x + threadIdx.x;
  if (idx >= total) return;
  const float v = X[idx];
  const _Float16 h = (_Float16)v;
  Xh[idx] = h;
  Xl[idx] = (_Float16)(v - (float)h);
}

// ---------------- per-node attention dots -----------------------------
template <int VPL>
__global__ void node_alpha(const float* __restrict__ h,
                           const float* __restrict__ a_src,
                           const float* __restrict__ a_dst,
                           float* __restrict__ asrc,
                           float* __restrict__ adst, int n_nodes) {
  constexpr int WTOT = VPL * 64;
  constexpr int NH = WTOT / 128;
  constexpr int GRP = 128 / VPL;  // lanes per head
  const int gtid = blockIdx.x * blockDim.x + threadIdx.x;
  const int node = gtid >> 6;
  const int lane = threadIdx.x & 63;
  if (node >= n_nodes) return;
  const int head = (lane * VPL) >> 7;
  const float* hrow = h + (size_t)node * WTOT + lane * VPL;
  float s1 = 0.f, s2 = 0.f;
#pragma unroll
  for (int j = 0; j < VPL; ++j) {
    const float v = hrow[j];
    s1 = fmaf(v, a_src[lane * VPL + j], s1);
    s2 = fmaf(v, a_dst[lane * VPL + j], s2);
  }
#pragma unroll
  for (int off = 1; off < GRP; off <<= 1) {
    s1 += __shfl_xor(s1, off);
    s2 += __shfl_xor(s2, off);
  }
  if ((lane & (GRP - 1)) == 0) {
    asrc[node * NH + head] = s1;
    adst[node * NH + head] = s2;
  }
}

// ---------------- CSR (by dst) build ----------------------------------
__global__ void init_counts(int* __restrict__ cnt, int* __restrict__ total, int n) {
  const int i = blockIdx.x * blockDim.x + threadIdx.x;
  if (i < n) cnt[i] = 1;  // the self loop
  if (i == 0) *total = 0;
}
__global__ void count_edges(const int* __restrict__ dst, int* __restrict__ cnt,
                            int ne, int node_off) {
  const int i = blockIdx.x * blockDim.x + threadIdx.x;
  if (i < ne) atomicAdd(&cnt[dst[i] + node_off], 1);
}
// Range allocation; also places the self-loop at slot start[i].
__global__ void alloc_ranges(const int* __restrict__ cnt, int* __restrict__ start,
                             int* __restrict__ cursor, int* __restrict__ total,
                             int* __restrict__ csr, int* __restrict__ csrd, int n) {
  const int i = blockIdx.x * blockDim.x + threadIdx.x;
  const int lane = threadIdx.x & 63;
  const int v = (i < n) ? cnt[i] : 0;
  int sc = v;
#pragma unroll
  for (int off = 1; off < 64; off <<= 1) {
    const int t = __shfl_up(sc, off);
    if (lane >= off) sc += t;
  }
  const int wtot = __shfl(sc, 63);
  int base = 0;
  if (lane == 63) base = atomicAdd(total, wtot);
  base = __shfl(base, 63);
  const int st = base + sc - v;
  if (i < n) {
    start[i] = st;
    cursor[i] = st + 1;
    csr[st] = i;   // self loop first
    csrd[st] = i;
  }
}
__global__ void fill_edges(const int* __restrict__ src, const int* __restrict__ dst,
                           int* __restrict__ cursor, int* __restrict__ csr,
                           int* __restrict__ csrd, int ne, int node_off) {
  const int i = blockIdx.x * blockDim.x + threadIdx.x;
  if (i < ne) {
    const int d = dst[i] + node_off;
    const int p = atomicAdd(&cursor[d], 1);
    csr[p] = src[i] + node_off;
    csrd[p] = d;
  }
}

// ---------------- edge-parallel p = exp(leaky(e)) (CSR order) ---------
// Softmax is shift-invariant; scores are bounded (|e| << 88) so no max
// subtraction is needed — removes a whole serial pass per node.
template <int NH>
__global__ void edge_scores(const int* __restrict__ csr_src,
                            const int* __restrict__ csr_dst,
                            const float* __restrict__ asrc,
                            const float* __restrict__ adst,
                            float* __restrict__ esc, int ne) {
  const int idx = blockIdx.x * blockDim.x + threadIdx.x;
  if (idx >= ne * NH) return;
  const int p = idx / NH;
  const int hh = idx - p * NH;
  const float e = asrc[csr_src[p] * NH + hh] + adst[csr_dst[p] * NH + hh];
  esc[idx] = expf((e > 0.f) ? e : kNegSlope * e);
}

// ---------------- GAT aggregate, layers 1-2 ---------------------------
// 2 waves per node, lane owns 4 contiguous channels (float4 gathers).
// Inner loop is pure load+fma (exp precomputed), unrolled x2.
__global__ void gat_agg4(const float* __restrict__ h, const float* __restrict__ esc,
                         const int* __restrict__ start, const int* __restrict__ cnt,
                         const int* __restrict__ csr_src,
                         const float* __restrict__ bias,
                         _Float16* __restrict__ outH, _Float16* __restrict__ outL,
                         int n_nodes) {
  const int gtid = blockIdx.x * blockDim.x + threadIdx.x;
  const int wid = gtid >> 6;
  const int node = wid >> 1;
  const int sub = wid & 1;
  const int lane = threadIdx.x & 63;
  if (node >= n_nodes) return;
  const int ch = sub * 256 + lane * 4;
  const int head = ch >> 7;
  const int s = start[node];
  const int c = cnt[node];
  float4 a0 = make_float4(0.f, 0.f, 0.f, 0.f);
  float4 a1 = make_float4(0.f, 0.f, 0.f, 0.f);
  float d0 = 0.f, d1 = 0.f;
  int i = 0;
  for (; i + 2 <= c; i += 2) {
    const float w0 = esc[(size_t)(s + i) * 4 + head];
    const float w1 = esc[(size_t)(s + i + 1) * 4 + head];
    const int s0 = csr_src[s + i];
    const int s1 = csr_src[s + i + 1];
    const float4 v0 = *(const float4*)(h + (size_t)s0 * 512 + ch);
    const float4 v1 = *(const float4*)(h + (size_t)s1 * 512 + ch);
    d0 += w0;
    d1 += w1;
    a0.x = fmaf(w0, v0.x, a0.x); a1.x = fmaf(w1, v1.x, a1.x);
    a0.y = fmaf(w0, v0.y, a0.y); a1.y = fmaf(w1, v1.y, a1.y);
    a0.z = fmaf(w0, v0.z, a0.z); a1.z = fmaf(w1, v1.z, a1.z);
    a0.w = fmaf(w0, v0.w, a0.w); a1.w = fmaf(w1, v1.w, a1.w);
  }
  if (i < c) {
    const float w0 = esc[(size_t)(s + i) * 4 + head];
    const int s0 = csr_src[s + i];
    const float4 v0 = *(const float4*)(h + (size_t)s0 * 512 + ch);
    d0 += w0;
    a0.x = fmaf(w0, v0.x, a0.x);
    a0.y = fmaf(w0, v0.y, a0.y);
    a0.z = fmaf(w0, v0.z, a0.z);
    a0.w = fmaf(w0, v0.w, a0.w);
  }
  const float inv = 1.f / (d0 + d1 + 1e-16f);
  float res[4] = {a0.x + a1.x, a0.y + a1.y, a0.z + a1.z, a0.w + a1.w};
  half4 H, L;
#pragma unroll
  for (int j = 0; j < 4; ++j) {
    float v = res[j] * inv + bias[ch + j];
    v = (v > 0.f) ? v : expm1f(v);  // elu
    const _Float16 hv = (_Float16)v;
    H[j] = hv;
    L[j] = (_Float16)(v - (float)hv);
  }
  *(half4*)(outH + (size_t)node * 512 + ch) = H;
  *(half4*)(outL + (size_t)node * 512 + ch) = L;
}

// ---------------- GAT aggregate, layer 3 (H=1, fp32 out, no elu) ------
__global__ void gat_agg_l3(const float* __restrict__ h, const float* __restrict__ esc,
                           const int* __restrict__ start, const int* __restrict__ cnt,
                           const int* __restrict__ csr_src,
                           const float* __restrict__ bias,
                           float* __restrict__ out, int n_nodes) {
  const int gtid = blockIdx.x * blockDim.x + threadIdx.x;
  const int node = gtid >> 6;
  const int lane = threadIdx.x & 63;
  if (node >= n_nodes) return;
  const int s = start[node];
  const int c = cnt[node];
  float2 a0 = make_float2(0.f, 0.f);
  float2 a1 = make_float2(0.f, 0.f);
  float d0 = 0.f, d1 = 0.f;
  int i = 0;
  for (; i + 2 <= c; i += 2) {
    const float w0 = esc[s + i];
    const float w1 = esc[s + i + 1];
    const int s0 = csr_src[s + i];
    const int s1 = csr_src[s + i + 1];
    const float2 v0 = *(const float2*)(h + (size_t)s0 * 128 + lane * 2);
    const float2 v1 = *(const float2*)(h + (size_t)s1 * 128 + lane * 2);
    d0 += w0;
    d1 += w1;
    a0.x = fmaf(w0, v0.x, a0.x); a1.x = fmaf(w1, v1.x, a1.x);
    a0.y = fmaf(w0, v0.y, a0.y); a1.y = fmaf(w1, v1.y, a1.y);
  }
  if (i < c) {
    const float w0 = esc[s + i];
    const int s0 = csr_src[s + i];
    const float2 v0 = *(const float2*)(h + (size_t)s0 * 128 + lane * 2);
    d0 += w0;
    a0.x = fmaf(w0, v0.x, a0.x);
    a0.y = fmaf(w0, v0.y, a0.y);
  }
  const float inv = 1.f / (d0 + d1 + 1e-16f);
  *(float2*)(out + (size_t)node * 128 + lane * 2) =
      make_float2((a0.x + a1.x) * inv + bias[lane * 2],
                  (a0.y + a1.y) * inv + bias[lane * 2 + 1]);
}

// ---------------- global max pool over sorted batch -------------------
__global__ void pool_max(const float* __restrict__ x, const int* __restrict__ batch,
                         float* __restrict__ emb, int n_nodes) {
  __shared__ int lohi[2];
  const int g = blockIdx.x;
  if (threadIdx.x == 0) {
    int lo = 0, hi = n_nodes;
    while (lo < hi) {
      const int mid = (lo + hi) >> 1;
      if (batch[mid] < g) lo = mid + 1; else hi = mid;
    }
    lohi[0] = lo;
    hi = n_nodes;
    while (lo < hi) {
      const int mid = (lo + hi) >> 1;
      if (batch[mid] < g + 1) lo = mid + 1; else hi = mid;
    }
    lohi[1] = lo;
  }
  __syncthreads();
  const int lo = lohi[0], hi = lohi[1];
  const int c = threadIdx.x;  // 128 channels
  float m = -1e30f;
  for (int nid = lo; nid < hi; ++nid) m = fmaxf(m, x[(size_t)nid * 128 + c]);
  emb[g * 128 + c] = (lo < hi) ? m : 0.f;
}

// ---------------- final MLP head --------------------------------------
__global__ void mlp_head(const float* __restrict__ e1, const float* __restrict__ e2,
                         const float* __restrict__ mw1, const float* __restrict__ mb1,
                         const float* __restrict__ mw2, const float* __restrict__ mb2,
                         float* __restrict__ out) {
  __shared__ float z[256];
  __shared__ float red[128];
  const int g = blockIdx.x;
  const int j = threadIdx.x;  // 128
  z[j] = e1[g * 128 + j];
  z[j + 128] = e2[g * 128 + j];
  __syncthreads();
  float acc = mb1[j];
  for (int k = 0; k < 256; ++k) acc = fmaf(z[k], mw1[k * 128 + j], acc);
  acc = fmaxf(acc, 0.f) * mw2[j];
  red[j] = acc;
  __syncthreads();
  for (int s = 64; s > 0; s >>= 1) {
    if (j < s) red[j] += red[j + s];
    __syncthreads();
  }
  if (j == 0) out[g] = red[0] + mb2[0];
}

// ---------------- launcher --------------------------------------------
namespace {
struct Bufs {
  _Float16 *R1h, *R1l;
  float *R1f, *R2, *asrc, *adst;
  int *cnt, *start, *cursor, *csr, *csrd, *total;
  float* esc;
  _Float16 *Wth1, *Wtl1, *Wth2, *Wtl2, *Wth3, *Wtl3;
  float* emb;
  size_t need;
};

Bufs plan(void* d_ws, int M, int ETOT) {
  Bufs b;
  char* w = (char*)d_ws;
  size_t off = 0;
  auto take = [&](size_t bytes) -> void* {
    void* p = w + off;
    off += (bytes + 255) & ~(size_t)255;
    return p;
  };
  b.R1h = (_Float16*)take((size_t)M * 512 * 4);  // act hi/lo pair
  b.R1l = b.R1h + (size_t)M * 512;
  b.R1f = (float*)b.R1h;                         // layer-3 out alias
  b.R2 = (float*)take((size_t)M * 512 * 4);      // h (GEMM out, fp32)
  b.asrc = (float*)take((size_t)M * 4 * 4);
  b.adst = (float*)take((size_t)M * 4 * 4);
  b.cnt = (int*)take((size_t)M * 4);
  b.start = (int*)take((size_t)M * 4);
  b.cursor = (int*)take((size_t)M * 4);
  b.csr = (int*)take((size_t)ETOT * 4);
  b.csrd = (int*)take((size_t)ETOT * 4);
  b.esc = (float*)take((size_t)ETOT * 4 * 4);
  b.total = (int*)take(256);
  b.Wth1 = (_Float16*)take((size_t)64 * 512 * 2);
  b.Wtl1 = (_Float16*)take((size_t)64 * 512 * 2);
  b.Wth2 = (_Float16*)take((size_t)512 * 512 * 2);
  b.Wtl2 = (_Float16*)take((size_t)512 * 512 * 2);
  b.Wth3 = (_Float16*)take((size_t)512 * 128 * 2);
  b.Wtl3 = (_Float16*)take((size_t)512 * 128 * 2);
  b.emb = (float*)take((size_t)2 * kG * 128 * 4);
  b.need = off;
  return b;
}

// Launch the 3-layer GAT stack for M nodes / ETOT csr slots.
void run_layers(const Bufs& b, void* const* d_in, int M, int ETOT,
                hipStream_t stream) {
  const float* b1 = (const float*)d_in[9];
  const float* as1 = (const float*)d_in[7];
  const float* ad1 = (const float*)d_in[8];
  const float* b2 = (const float*)d_in[13];
  const float* as2 = (const float*)d_in[11];
  const float* ad2 = (const float*)d_in[12];
  const float* b3 = (const float*)d_in[17];
  const float* as3 = (const float*)d_in[15];
  const float* ad3 = (const float*)d_in[16];

  const int nodeBlocks = (M * 64 + 255) / 256;       // 1 wave/node
  const int aggBlocks4 = (M * 2 * 64 + 255) / 256;   // 2 waves/node
  const dim3 g4((M + 127) / 128, 4), g1((M + 127) / 128, 1);

  _Float16* A1h = b.R1h;
  _Float16* A1l = b.R1h + (size_t)M * 64;

  // layer 1: [M,64] @ [64,512]
  gemm_f16x3<<<g4, 256, 0, stream>>>(A1h, A1l, b.Wth1, b.Wtl1, b.R2, M, 512, 64);
  node_alpha<8><<<nodeBlocks, 256, 0, stream>>>(b.R2, as1, ad1, b.asrc, b.adst, M);
  edge_scores<4><<<(ETOT * 4 + 255) / 256, 256, 0, stream>>>(b.csr, b.csrd, b.asrc,
                                                             b.adst, b.esc, ETOT);
  gat_agg4<<<aggBlocks4, 256, 0, stream>>>(b.R2, b.esc, b.start, b.cnt, b.csr, b1,
                                           b.R1h, b.R1l, M);
  // layer 2: [M,512] @ [512,512]
  gemm_f16x3<<<g4, 256, 0, stream>>>(b.R1h, b.R1l, b.Wth2, b.Wtl2, b.R2, M, 512, 512);
  node_alpha<8><<<nodeBlocks, 256, 0, stream>>>(b.R2, as2, ad2, b.asrc, b.adst, M);
  edge_scores<4><<<(ETOT * 4 + 255) / 256, 256, 0, stream>>>(b.csr, b.csrd, b.asrc,
                                                             b.adst, b.esc, ETOT);
  gat_agg4<<<aggBlocks4, 256, 0, stream>>>(b.R2, b.esc, b.start, b.cnt, b.csr, b2,
                                           b.R1h, b.R1l, M);
  // layer 3: [M,512] @ [512,128], H=1, no elu, fp32 out
  gemm_f16x3<<<g1, 256, 0, stream>>>(b.R1h, b.R1l, b.Wth3, b.Wtl3, b.R2, M, 128, 512);
  node_alpha<2><<<nodeBlocks, 256, 0, stream>>>(b.R2, as3, ad3, b.asrc, b.adst, M);
  edge_scores<1><<<(ETOT + 255) / 256, 256, 0, stream>>>(b.csr, b.csrd, b.asrc,
                                                         b.adst, b.esc, ETOT);
  gat_agg_l3<<<nodeBlocks, 256, 0, stream>>>(b.R2, b.esc, b.start, b.cnt, b.csr, b3,
                                             b.R1f, M);
}
}  // namespace

extern "C" void kernel_launch(void* const* d_in, const int* in_sizes, int n_in,
                              void* d_out, int out_size, void* d_ws, size_t ws_size,
                              hipStream_t stream) {
  (void)in_sizes; (void)n_in; (void)out_size;
  const float* W1 = (const float*)d_in[6];
  const float* W2 = (const float*)d_in[10];
  const float* W3 = (const float*)d_in[14];
  const float* mw1 = (const float*)d_in[18];
  const float* mb1 = (const float*)d_in[19];
  const float* mw2 = (const float*)d_in[20];
  const float* mb2 = (const float*)d_in[21];

  // Prefer the combined (both encoders batched, M=2N) layout if it fits.
  Bufs bc = plan(d_ws, 2 * kN, 2 * kE2);
  const bool combined = bc.need <= ws_size;
  Bufs b = combined ? bc : plan(d_ws, kN, kE2);
  const int M = combined ? 2 * kN : kN;
  const int ETOT = combined ? 2 * kE2 : kE2;

  wt_split<<<(64 * 512 + 255) / 256, 256, 0, stream>>>(W1, b.Wth1, b.Wtl1, 64, 512);
  wt_split<<<(512 * 512 + 255) / 256, 256, 0, stream>>>(W2, b.Wth2, b.Wtl2, 512, 512);
  wt_split<<<(512 * 128 + 255) / 256, 256, 0, stream>>>(W3, b.Wth3, b.Wtl3, 512, 128);

  if (combined) {
    // one CSR over both encoders (encoder-2 node ids offset by kN)
    init_counts<<<(M + 255) / 256, 256, 0, stream>>>(b.cnt, b.total, M);
    for (int enc = 0; enc < 2; ++enc) {
      const int* ei = (const int*)d_in[enc * 3 + 1];
      count_edges<<<(kE + 255) / 256, 256, 0, stream>>>(ei + kE, b.cnt, kE, enc * kN);
    }
    alloc_ranges<<<(M + 255) / 256, 256, 0, stream>>>(b.cnt, b.start, b.cursor,
                                                      b.total, b.csr, b.csrd, M);
    for (int enc = 0; enc < 2; ++enc) {
      const int* ei = (const int*)d_in[enc * 3 + 1];
      fill_edges<<<(kE + 255) / 256, 256, 0, stream>>>(ei, ei + kE, b.cursor, b.csr,
                                                       b.csrd, kE, enc * kN);
    }
    // layer-1 input split for both encoders into [2N,64] hi/lo
    _Float16* A1h = b.R1h;
    _Float16* A1l = b.R1h + (size_t)M * 64;
    for (int enc = 0; enc < 2; ++enc) {
      const float* x = (const float*)d_in[enc * 3 + 0];
      split16<<<(kN * 64 + 255) / 256, 256, 0, stream>>>(
          x, A1h + (size_t)enc * kN * 64, A1l + (size_t)enc * kN * 64, kN * 64);
    }
    run_layers(b, d_in, M, ETOT, stream);
    for (int enc = 0; enc < 2; ++enc) {
      const int* batch = (const int*)d_in[enc * 3 + 2];
      pool_max<<<kG, 128, 0, stream>>>(b.R1f + (size_t)enc * kN * 128, batch,
                                       b.emb + (size_t)enc * kG * 128, kN);
    }
  } else {
    for (int enc = 0; enc < 2; ++enc) {
      const float* x = (const float*)d_in[enc * 3 + 0];
      const int* ei = (const int*)d_in[enc * 3 + 1];
      const int* batch = (const int*)d_in[enc * 3 + 2];
      init_counts<<<(kN + 255) / 256, 256, 0, stream>>>(b.cnt, b.total, kN);
      count_edges<<<(kE + 255) / 256, 256, 0, stream>>>(ei + kE, b.cnt, kE, 0);
      alloc_ranges<<<(kN + 255) / 256, 256, 0, stream>>>(b.cnt, b.start, b.cursor,
                                                         b.total, b.csr, b.csrd, kN);
      fill_edges<<<(kE + 255) / 256, 256, 0, stream>>>(ei, ei + kE, b.cursor, b.csr,
                                                       b.csrd, kE, 0);
      _Float16* A1h = b.R1h;
      _Float16* A1l = b.R1h + (size_t)kN * 64;
      split16<<<(kN * 64 + 255) / 256, 256, 0, stream>>>(x, A1h, A1l, kN * 64);
      run_layers(b, d_in, kN, kE2, stream);
      pool_max<<<kG, 128, 0, stream>>>(b.R1f, batch, b.emb + (size_t)enc * kG * 128,
                                       kN);
    }
  }
  mlp_head<<<kG, 128, 0, stream>>>(b.emb, b.emb + (size_t)kG * 128, mw1, mb1, mw2,
                                   mb2, (float*)d_out);
}

// Round 6
// 1202.642 us; speedup vs baseline: 1.0093x; 1.0093x over previous
//
#include <hip/hip_runtime.h>
#include <cstdint>

namespace {
constexpr int kN = 50000;          // nodes per encoder
constexpr int kE = 200000;         // directed edges per encoder (pre self-loop)
constexpr int kE2 = kE + kN;       // with self loops (per encoder)
constexpr int kG = 256;            // graphs per encoder
constexpr float kNegSlope = 0.2f;
}

using half8   = __attribute__((ext_vector_type(8))) _Float16;
using half4   = __attribute__((ext_vector_type(4))) _Float16;
using floatx4 = __attribute__((ext_vector_type(4))) float;

__device__ __forceinline__ void gld_lds16(const void* g, void* l) {
  __builtin_amdgcn_global_load_lds(
      (const __attribute__((address_space(1))) unsigned int*)g,
      (__attribute__((address_space(3))) unsigned int*)l, 16, 0, 0);
}

// ---------------- f16x3 MFMA GEMM: C[M,N] = A[M,K] @ B[K,N] ----------
// A row-major hi/lo f16 [M,K]; B pre-transposed hi/lo f16 [N,K].
// 128x128 tile, BK=32, 256 threads = 4 waves (64x64 each).
// blockIdx.z = split-K chunk; chunk z covers K/gridDim.z and writes
// C + z*czstride (caller reduces). LDS slot s holds (row=(s>>6)*16+(s&15),
// kchunk=(s>>4)&3); fragment read g*1024 + lane*16 => conflict-free
// ds_read_b128, lane-contiguous staging (global_load_lds-legal).
__global__ __launch_bounds__(256) void gemm_f16x3(
    const _Float16* __restrict__ Ah, const _Float16* __restrict__ Al,
    const _Float16* __restrict__ Bh, const _Float16* __restrict__ Bl,
    float* __restrict__ C, int M, int N, int K, size_t czstride) {
  __shared__ alignas(16) char smem[32768];
  char* sAh = smem;
  char* sAl = smem + 8192;
  char* sBh = smem + 16384;
  char* sBl = smem + 24576;
  const int t = threadIdx.x;
  const int w = t >> 6;
  const int l = t & 63;
  const int bm = blockIdx.x * 128;
  const int bn = blockIdx.y * 128;
  const int wm = (w & 1) * 64;
  const int wn = (w >> 1) * 64;
  const int quad = l >> 4;
  const int lrow = l & 15;
  const int Ksub = K / gridDim.z;
  const int kbeg = blockIdx.z * Ksub;
  C += (size_t)blockIdx.z * czstride;

  floatx4 acc[4][4];
#pragma unroll
  for (int mi = 0; mi < 4; ++mi)
#pragma unroll
    for (int ni = 0; ni < 4; ++ni) acc[mi][ni] = (floatx4){0.f, 0.f, 0.f, 0.f};

  for (int k0 = kbeg; k0 < kbeg + Ksub; k0 += 32) {
#pragma unroll
    for (int j = 0; j < 2; ++j) {
      const int s = w * 128 + j * 64 + l;          // slot id 0..511
      const int row = ((s >> 6) << 4) + (s & 15);  // 0..127
      const int q = (s >> 4) & 3;
      int ga = bm + row;
      ga = (ga < M) ? ga : (M - 1);                // clamp: keep lanes active
      const size_t aofs = (size_t)ga * K + k0 + q * 8;
      const size_t bofs = (size_t)(bn + row) * K + k0 + q * 8;
      gld_lds16(Ah + aofs, sAh + s * 16);
      gld_lds16(Al + aofs, sAl + s * 16);
      gld_lds16(Bh + bofs, sBh + s * 16);
      gld_lds16(Bl + bofs, sBl + s * 16);
    }
    __syncthreads();
    half8 fah[4], fal[4], fbh[4], fbl[4];
#pragma unroll
    for (int mi = 0; mi < 4; ++mi) {
      const int g = (wm >> 4) + mi;
      fah[mi] = *(const half8*)(sAh + g * 1024 + l * 16);
      fal[mi] = *(const half8*)(sAl + g * 1024 + l * 16);
    }
#pragma unroll
    for (int ni = 0; ni < 4; ++ni) {
      const int g = (wn >> 4) + ni;
      fbh[ni] = *(const half8*)(sBh + g * 1024 + l * 16);
      fbl[ni] = *(const half8*)(sBl + g * 1024 + l * 16);
    }
#pragma unroll
    for (int mi = 0; mi < 4; ++mi)
#pragma unroll
      for (int ni = 0; ni < 4; ++ni) {
        acc[mi][ni] = __builtin_amdgcn_mfma_f32_16x16x32_f16(fal[mi], fbh[ni],
                                                             acc[mi][ni], 0, 0, 0);
        acc[mi][ni] = __builtin_amdgcn_mfma_f32_16x16x32_f16(fah[mi], fbl[ni],
                                                             acc[mi][ni], 0, 0, 0);
        acc[mi][ni] = __builtin_amdgcn_mfma_f32_16x16x32_f16(fah[mi], fbh[ni],
                                                             acc[mi][ni], 0, 0, 0);
      }
    __syncthreads();
  }
  // epilogue: C/D layout col=lane&15, row=quad*4+reg
#pragma unroll
  for (int mi = 0; mi < 4; ++mi) {
    const int rbase = bm + wm + mi * 16 + quad * 4;
#pragma unroll
    for (int r = 0; r < 4; ++r) {
      const int grow = rbase + r;
      if (grow < M) {
#pragma unroll
        for (int ni = 0; ni < 4; ++ni) {
          C[(size_t)grow * N + bn + wn + ni * 16 + lrow] = acc[mi][ni][r];
        }
      }
    }
  }
}

// ------- all three weight transposes + f16 splits in one kernel -------
__global__ void wt_split_all(const float* __restrict__ W1, _Float16* Th1,
                             _Float16* Tl1, const float* __restrict__ W2,
                             _Float16* Th2, _Float16* Tl2,
                             const float* __restrict__ W3, _Float16* Th3,
                             _Float16* Tl3) {
  int idx = blockIdx.x * blockDim.x + threadIdx.x;
  const float* W;
  _Float16 *Th, *Tl;
  int K, N;
  if (idx < 64 * 512) {
    W = W1; Th = Th1; Tl = Tl1; K = 64; N = 512;
  } else if (idx < 64 * 512 + 512 * 512) {
    idx -= 64 * 512;
    W = W2; Th = Th2; Tl = Tl2; K = 512; N = 512;
  } else if (idx < 64 * 512 + 512 * 512 + 512 * 128) {
    idx -= 64 * 512 + 512 * 512;
    W = W3; Th = Th3; Tl = Tl3; K = 512; N = 128;
  } else {
    return;
  }
  const int k = idx / N;
  const int n = idx - k * N;
  const float v = W[idx];
  const _Float16 h = (_Float16)v;
  Th[n * K + k] = h;
  Tl[n * K + k] = (_Float16)(v - (float)h);
}

// ------- per-encoder prep: x fp32->hi/lo split, cnt=1, total=0 --------
__global__ void prep(const float* __restrict__ X, _Float16* __restrict__ Xh,
                     _Float16* __restrict__ Xl, int* __restrict__ cnt,
                     int* __restrict__ total, int nsplit, int n) {
  const int idx = blockIdx.x * blockDim.x + threadIdx.x;
  if (idx < nsplit) {
    const float v = X[idx];
    const _Float16 h = (_Float16)v;
    Xh[idx] = h;
    Xl[idx] = (_Float16)(v - (float)h);
  }
  if (idx < n) cnt[idx] = 1;  // the self loop
  if (idx == 0) *total = 0;
}

// ---------------- per-node attention dots (layers 1-2) ----------------
template <int VPL>
__global__ void node_alpha(const float* __restrict__ h,
                           const float* __restrict__ a_src,
                           const float* __restrict__ a_dst,
                           float* __restrict__ asrc,
                           float* __restrict__ adst, int n_nodes) {
  constexpr int WTOT = VPL * 64;
  constexpr int NH = WTOT / 128;
  constexpr int GRP = 128 / VPL;  // lanes per head
  const int gtid = blockIdx.x * blockDim.x + threadIdx.x;
  const int node = gtid >> 6;
  const int lane = threadIdx.x & 63;
  if (node >= n_nodes) return;
  const int head = (lane * VPL) >> 7;
  const float* hrow = h + (size_t)node * WTOT + lane * VPL;
  float s1 = 0.f, s2 = 0.f;
#pragma unroll
  for (int j = 0; j < VPL; ++j) {
    const float v = hrow[j];
    s1 = fmaf(v, a_src[lane * VPL + j], s1);
    s2 = fmaf(v, a_dst[lane * VPL + j], s2);
  }
#pragma unroll
  for (int off = 1; off < GRP; off <<= 1) {
    s1 += __shfl_xor(s1, off);
    s2 += __shfl_xor(s2, off);
  }
  if ((lane & (GRP - 1)) == 0) {
    asrc[node * NH + head] = s1;
    adst[node * NH + head] = s2;
  }
}

// ------- layer-3 alpha: sums split-K halves in place + dots (H=1) -----
__global__ void node_alpha_l3(float* __restrict__ ha, const float* __restrict__ hb,
                              const float* __restrict__ a_src,
                              const float* __restrict__ a_dst,
                              float* __restrict__ asrc, float* __restrict__ adst,
                              int n_nodes) {
  const int gtid = blockIdx.x * blockDim.x + threadIdx.x;
  const int node = gtid >> 6;
  const int lane = threadIdx.x & 63;
  if (node >= n_nodes) return;
  const size_t o = (size_t)node * 128 + lane * 2;
  const float2 va = *(const float2*)(ha + o);
  const float2 vb = *(const float2*)(hb + o);
  const float2 v = make_float2(va.x + vb.x, va.y + vb.y);
  *(float2*)(ha + o) = v;
  float s1 = fmaf(v.x, a_src[lane * 2], v.y * a_src[lane * 2 + 1]);
  float s2 = fmaf(v.x, a_dst[lane * 2], v.y * a_dst[lane * 2 + 1]);
#pragma unroll
  for (int off = 1; off < 64; off <<= 1) {
    s1 += __shfl_xor(s1, off);
    s2 += __shfl_xor(s2, off);
  }
  if (lane == 0) {
    asrc[node] = s1;
    adst[node] = s2;
  }
}

// ---------------- CSR (by dst) build ----------------------------------
__global__ void count_edges(const int* __restrict__ dst, int* __restrict__ cnt,
                            int ne) {
  const int i = blockIdx.x * blockDim.x + threadIdx.x;
  if (i < ne) atomicAdd(&cnt[dst[i]], 1);
}
// Range allocation; also places the self-loop at slot start[i].
__global__ void alloc_ranges(const int* __restrict__ cnt, int* __restrict__ start,
                             int* __restrict__ cursor, int* __restrict__ total,
                             int* __restrict__ csr, int n) {
  const int i = blockIdx.x * blockDim.x + threadIdx.x;
  const int lane = threadIdx.x & 63;
  const int v = (i < n) ? cnt[i] : 0;
  int sc = v;
#pragma unroll
  for (int off = 1; off < 64; off <<= 1) {
    const int t = __shfl_up(sc, off);
    if (lane >= off) sc += t;
  }
  const int wtot = __shfl(sc, 63);
  int base = 0;
  if (lane == 63) base = atomicAdd(total, wtot);
  base = __shfl(base, 63);
  const int st = base + sc - v;
  if (i < n) {
    start[i] = st;
    cursor[i] = st + 1;
    csr[st] = i;  // self loop first
  }
}
__global__ void fill_edges(const int* __restrict__ src, const int* __restrict__ dst,
                           int* __restrict__ cursor, int* __restrict__ csr, int ne) {
  const int i = blockIdx.x * blockDim.x + threadIdx.x;
  if (i < ne) {
    const int p = atomicAdd(&cursor[dst[i]], 1);
    csr[p] = src[i];
  }
}

// ---------------- GAT aggregate, layers 1-2 (fused scores) ------------
// 2 waves per node, lane owns 4 contiguous channels (float4 gathers).
// p = exp(leaky(asrc[src]+adst[node])) computed inline — softmax is
// shift-invariant and scores are bounded, so no max pass (R4 result).
__global__ void gat_agg4(const float* __restrict__ h,
                         const float* __restrict__ asrc,
                         const float* __restrict__ adst,
                         const int* __restrict__ start, const int* __restrict__ cnt,
                         const int* __restrict__ csr_src,
                         const float* __restrict__ bias,
                         _Float16* __restrict__ outH, _Float16* __restrict__ outL,
                         int n_nodes) {
  const int gtid = blockIdx.x * blockDim.x + threadIdx.x;
  const int wid = gtid >> 6;
  const int node = wid >> 1;
  const int sub = wid & 1;
  const int lane = threadIdx.x & 63;
  if (node >= n_nodes) return;
  const int ch = sub * 256 + lane * 4;
  const int head = ch >> 7;
  const int s = start[node];
  const int c = cnt[node];
  const float ad = adst[node * 4 + head];
  float4 a0 = make_float4(0.f, 0.f, 0.f, 0.f);
  float4 a1 = make_float4(0.f, 0.f, 0.f, 0.f);
  float d0 = 0.f, d1 = 0.f;
  int i = 0;
  for (; i + 2 <= c; i += 2) {
    const int s0 = csr_src[s + i];
    const int s1 = csr_src[s + i + 1];
    float e0 = asrc[s0 * 4 + head] + ad;
    float e1 = asrc[s1 * 4 + head] + ad;
    e0 = (e0 > 0.f) ? e0 : kNegSlope * e0;
    e1 = (e1 > 0.f) ? e1 : kNegSlope * e1;
    const float w0 = expf(e0);
    const float w1 = expf(e1);
    const float4 v0 = *(const float4*)(h + (size_t)s0 * 512 + ch);
    const float4 v1 = *(const float4*)(h + (size_t)s1 * 512 + ch);
    d0 += w0;
    d1 += w1;
    a0.x = fmaf(w0, v0.x, a0.x); a1.x = fmaf(w1, v1.x, a1.x);
    a0.y = fmaf(w0, v0.y, a0.y); a1.y = fmaf(w1, v1.y, a1.y);
    a0.z = fmaf(w0, v0.z, a0.z); a1.z = fmaf(w1, v1.z, a1.z);
    a0.w = fmaf(w0, v0.w, a0.w); a1.w = fmaf(w1, v1.w, a1.w);
  }
  if (i < c) {
    const int s0 = csr_src[s + i];
    float e0 = asrc[s0 * 4 + head] + ad;
    e0 = (e0 > 0.f) ? e0 : kNegSlope * e0;
    const float w0 = expf(e0);
    const float4 v0 = *(const float4*)(h + (size_t)s0 * 512 + ch);
    d0 += w0;
    a0.x = fmaf(w0, v0.x, a0.x);
    a0.y = fmaf(w0, v0.y, a0.y);
    a0.z = fmaf(w0, v0.z, a0.z);
    a0.w = fmaf(w0, v0.w, a0.w);
  }
  const float inv = 1.f / (d0 + d1 + 1e-16f);
  float res[4] = {a0.x + a1.x, a0.y + a1.y, a0.z + a1.z, a0.w + a1.w};
  half4 H, L;
#pragma unroll
  for (int j = 0; j < 4; ++j) {
    float v = res[j] * inv + bias[ch + j];
    v = (v > 0.f) ? v : expm1f(v);  // elu
    const _Float16 hv = (_Float16)v;
    H[j] = hv;
    L[j] = (_Float16)(v - (float)hv);
  }
  *(half4*)(outH + (size_t)node * 512 + ch) = H;
  *(half4*)(outL + (size_t)node * 512 + ch) = L;
}

// ---------- GAT aggregate, layer 3 (H=1, fp32 out, fused scores) ------
__global__ void gat_agg_l3(const float* __restrict__ h,
                           const float* __restrict__ asrc,
                           const float* __restrict__ adst,
                           const int* __restrict__ start, const int* __restrict__ cnt,
                           const int* __restrict__ csr_src,
                           const float* __restrict__ bias,
                           float* __restrict__ out, int n_nodes) {
  const int gtid = blockIdx.x * blockDim.x + threadIdx.x;
  const int node = gtid >> 6;
  const int lane = threadIdx.x & 63;
  if (node >= n_nodes) return;
  const int s = start[node];
  const int c = cnt[node];
  const float ad = adst[node];
  float2 a0 = make_float2(0.f, 0.f);
  float2 a1 = make_float2(0.f, 0.f);
  float d0 = 0.f, d1 = 0.f;
  int i = 0;
  for (; i + 2 <= c; i += 2) {
    const int s0 = csr_src[s + i];
    const int s1 = csr_src[s + i + 1];
    float e0 = asrc[s0] + ad;
    float e1 = asrc[s1] + ad;
    e0 = (e0 > 0.f) ? e0 : kNegSlope * e0;
    e1 = (e1 > 0.f) ? e1 : kNegSlope * e1;
    const float w0 = expf(e0);
    const float w1 = expf(e1);
    const float2 v0 = *(const float2*)(h + (size_t)s0 * 128 + lane * 2);
    const float2 v1 = *(const float2*)(h + (size_t)s1 * 128 + lane * 2);
    d0 += w0;
    d1 += w1;
    a0.x = fmaf(w0, v0.x, a0.x); a1.x = fmaf(w1, v1.x, a1.x);
    a0.y = fmaf(w0, v0.y, a0.y); a1.y = fmaf(w1, v1.y, a1.y);
  }
  if (i < c) {
    const int s0 = csr_src[s + i];
    float e0 = asrc[s0] + ad;
    e0 = (e0 > 0.f) ? e0 : kNegSlope * e0;
    const float w0 = expf(e0);
    const float2 v0 = *(const float2*)(h + (size_t)s0 * 128 + lane * 2);
    d0 += w0;
    a0.x = fmaf(w0, v0.x, a0.x);
    a0.y = fmaf(w0, v0.y, a0.y);
  }
  const float inv = 1.f / (d0 + d1 + 1e-16f);
  *(float2*)(out + (size_t)node * 128 + lane * 2) =
      make_float2((a0.x + a1.x) * inv + bias[lane * 2],
                  (a0.y + a1.y) * inv + bias[lane * 2 + 1]);
}

// ---------------- global max pool over sorted batch -------------------
__global__ void pool_max(const float* __restrict__ x, const int* __restrict__ batch,
                         float* __restrict__ emb, int n_nodes) {
  __shared__ int lohi[2];
  const int g = blockIdx.x;
  if (threadIdx.x == 0) {
    int lo = 0, hi = n_nodes;
    while (lo < hi) {
      const int mid = (lo + hi) >> 1;
      if (batch[mid] < g) lo = mid + 1; else hi = mid;
    }
    lohi[0] = lo;
    hi = n_nodes;
    while (lo < hi) {
      const int mid = (lo + hi) >> 1;
      if (batch[mid] < g + 1) lo = mid + 1; else hi = mid;
    }
    lohi[1] = lo;
  }
  __syncthreads();
  const int lo = lohi[0], hi = lohi[1];
  const int c = threadIdx.x;  // 128 channels
  float m = -1e30f;
  for (int nid = lo; nid < hi; ++nid) m = fmaxf(m, x[(size_t)nid * 128 + c]);
  emb[g * 128 + c] = (lo < hi) ? m : 0.f;
}

// ---------------- final MLP head --------------------------------------
__global__ void mlp_head(const float* __restrict__ e1, const float* __restrict__ e2,
                         const float* __restrict__ mw1, const float* __restrict__ mb1,
                         const float* __restrict__ mw2, const float* __restrict__ mb2,
                         float* __restrict__ out) {
  __shared__ float z[256];
  __shared__ float red[128];
  const int g = blockIdx.x;
  const int j = threadIdx.x;  // 128
  z[j] = e1[g * 128 + j];
  z[j + 128] = e2[g * 128 + j];
  __syncthreads();
  float acc = mb1[j];
  for (int k = 0; k < 256; ++k) acc = fmaf(z[k], mw1[k * 128 + j], acc);
  acc = fmaxf(acc, 0.f) * mw2[j];
  red[j] = acc;
  __syncthreads();
  for (int s = 64; s > 0; s >>= 1) {
    if (j < s) red[j] += red[j + s];
    __syncthreads();
  }
  if (j == 0) out[g] = red[0] + mb2[0];
}

// ---------------- launcher --------------------------------------------
extern "C" void kernel_launch(void* const* d_in, const int* in_sizes, int n_in,
                              void* d_out, int out_size, void* d_ws, size_t ws_size,
                              hipStream_t stream) {
  (void)in_sizes; (void)n_in; (void)out_size;
  const float* W1 = (const float*)d_in[6];
  const float* as1 = (const float*)d_in[7];
  const float* ad1 = (const float*)d_in[8];
  const float* b1 = (const float*)d_in[9];
  const float* W2 = (const float*)d_in[10];
  const float* as2 = (const float*)d_in[11];
  const float* ad2 = (const float*)d_in[12];
  const float* b2 = (const float*)d_in[13];
  const float* W3 = (const float*)d_in[14];
  const float* as3 = (const float*)d_in[15];
  const float* ad3 = (const float*)d_in[16];
  const float* b3 = (const float*)d_in[17];
  const float* mw1 = (const float*)d_in[18];
  const float* mb1 = (const float*)d_in[19];
  const float* mw2 = (const float*)d_in[20];
  const float* mb2 = (const float*)d_in[21];

  char* w = (char*)d_ws;
  size_t off = 0;
  auto take = [&](size_t bytes) -> void* {
    void* p = w + off;
    off += (bytes + 255) & ~(size_t)255;
    return p;
  };
  _Float16* R1h = (_Float16*)take((size_t)kN * 512 * 4);  // act hi/lo pair
  _Float16* R1l = R1h + (size_t)kN * 512;
  float* R1f = (float*)R1h;                               // layer-3 out alias
  float* R2 = (float*)take((size_t)kN * 512 * 4);         // h (GEMM out, fp32)
  float* R2b = R2 + (size_t)kN * 128;                     // l3 split-K half 2
  float* asrc = (float*)take((size_t)kN * 4 * 4);
  float* adst = (float*)take((size_t)kN * 4 * 4);
  int* cnt    = (int*)take((size_t)kN * 4);
  int* start  = (int*)take((size_t)kN * 4);
  int* cursor = (int*)take((size_t)kN * 4);
  int* csr    = (int*)take((size_t)kE2 * 4);
  int* total  = (int*)take(256);
  _Float16* Wth1 = (_Float16*)take((size_t)64 * 512 * 2);
  _Float16* Wtl1 = (_Float16*)take((size_t)64 * 512 * 2);
  _Float16* Wth2 = (_Float16*)take((size_t)512 * 512 * 2);
  _Float16* Wtl2 = (_Float16*)take((size_t)512 * 512 * 2);
  _Float16* Wth3 = (_Float16*)take((size_t)512 * 128 * 2);
  _Float16* Wtl3 = (_Float16*)take((size_t)512 * 128 * 2);
  float* emb = (float*)take((size_t)2 * kG * 128 * 4);
  if (off > ws_size) return;

  const int wtot = 64 * 512 + 512 * 512 + 512 * 128;
  wt_split_all<<<(wtot + 255) / 256, 256, 0, stream>>>(W1, Wth1, Wtl1, W2, Wth2,
                                                       Wtl2, W3, Wth3, Wtl3);

  const int nodeBlocks = (kN * 64) / 256;       // 1 wave/node
  const int aggBlocks4 = (kN * 2 * 64) / 256;   // 2 waves/node
  const dim3 g4((kN + 127) / 128, 4, 1);
  const dim3 g3((kN + 127) / 128, 1, 2);        // layer-3 split-K=2

  for (int enc = 0; enc < 2; ++enc) {
    const float* x = (const float*)d_in[enc * 3 + 0];
    const int* ei = (const int*)d_in[enc * 3 + 1];
    const int* batch = (const int*)d_in[enc * 3 + 2];
    float* embp = emb + (size_t)enc * kG * 128;

    _Float16* A1h = R1h;
    _Float16* A1l = R1h + (size_t)kN * 64;
    // x split + cnt=1 + total=0 in one pass
    prep<<<(kN * 64 + 255) / 256, 256, 0, stream>>>(x, A1h, A1l, cnt, total,
                                                    kN * 64, kN);
    count_edges<<<(kE + 255) / 256, 256, 0, stream>>>(ei + kE, cnt, kE);
    alloc_ranges<<<(kN + 255) / 256, 256, 0, stream>>>(cnt, start, cursor, total,
                                                       csr, kN);
    fill_edges<<<(kE + 255) / 256, 256, 0, stream>>>(ei, ei + kE, cursor, csr, kE);

    // layer 1: [N,64] @ [64,512]
    gemm_f16x3<<<g4, 256, 0, stream>>>(A1h, A1l, Wth1, Wtl1, R2, kN, 512, 64, 0);
    node_alpha<8><<<nodeBlocks, 256, 0, stream>>>(R2, as1, ad1, asrc, adst, kN);
    gat_agg4<<<aggBlocks4, 256, 0, stream>>>(R2, asrc, adst, start, cnt, csr, b1,
                                             R1h, R1l, kN);
    // layer 2: [N,512] @ [512,512]
    gemm_f16x3<<<g4, 256, 0, stream>>>(R1h, R1l, Wth2, Wtl2, R2, kN, 512, 512, 0);
    node_alpha<8><<<nodeBlocks, 256, 0, stream>>>(R2, as2, ad2, asrc, adst, kN);
    gat_agg4<<<aggBlocks4, 256, 0, stream>>>(R2, asrc, adst, start, cnt, csr, b2,
                                             R1h, R1l, kN);
    // layer 3: [N,512] @ [512,128], split-K=2, H=1, no elu, fp32 out
    gemm_f16x3<<<g3, 256, 0, stream>>>(R1h, R1l, Wth3, Wtl3, R2, kN, 128, 512,
                                       (size_t)kN * 128);
    node_alpha_l3<<<nodeBlocks, 256, 0, stream>>>(R2, R2b, as3, ad3, asrc, adst, kN);
    gat_agg_l3<<<nodeBlocks, 256, 0, stream>>>(R2, asrc, adst, start, cnt, csr, b3,
                                               R1f, kN);
    pool_max<<<kG, 128, 0, stream>>>(R1f, batch, embp, kN);
  }
  mlp_head<<<kG, 128, 0, stream>>>(emb, emb + (size_t)kG * 128, mw1, mb1, mw2, mb2,
                                   (float*)d_out);
}

// Round 7
// 1024.947 us; speedup vs baseline: 1.1842x; 1.1734x over previous
//
#include <hip/hip_runtime.h>
#include <cstdint>

namespace {
constexpr int kN = 50000;          // nodes per encoder
constexpr int kE = 200000;         // directed edges per encoder (pre self-loop)
constexpr int kE2 = kE + kN;       // with self loops (per encoder)
constexpr int kG = 256;            // graphs per encoder
constexpr float kNegSlope = 0.2f;
}

using half8   = __attribute__((ext_vector_type(8))) _Float16;
using half4   = __attribute__((ext_vector_type(4))) _Float16;
using floatx4 = __attribute__((ext_vector_type(4))) float;

__device__ __forceinline__ void gld_lds16(const void* g, void* l) {
  __builtin_amdgcn_global_load_lds(
      (const __attribute__((address_space(1))) unsigned int*)g,
      (__attribute__((address_space(3))) unsigned int*)l, 16, 0, 0);
}

// ---------------- fp16 MFMA GEMM: C[M,N] = A[M,K] @ B[K,N] -----------
// Single-product fp16 (fp32 accumulate). A row-major f16 [M,K]; B
// pre-transposed f16 [N,K]. 128x128 tile, BK=32, 256 threads = 4 waves.
// Per K-tile: 4 global_load_lds_dwordx4 + 8 ds_read_b128 + 16 MFMA/wave
// (the m97 shape). blockIdx.z = split-K chunk writing C + z*czstride.
// LDS slot s holds (row=(s>>6)*16+(s&15), kchunk=(s>>4)&3); fragment read
// g*1024 + lane*16 => conflict-free ds_read_b128, lane-contiguous staging.
__global__ __launch_bounds__(256) void gemm_f16(
    const _Float16* __restrict__ A, const _Float16* __restrict__ B,
    float* __restrict__ C, int M, int N, int K, size_t czstride) {
  __shared__ alignas(16) char smem[16384];
  char* sA = smem;
  char* sB = smem + 8192;
  const int t = threadIdx.x;
  const int w = t >> 6;
  const int l = t & 63;
  const int bm = blockIdx.x * 128;
  const int bn = blockIdx.y * 128;
  const int wm = (w & 1) * 64;
  const int wn = (w >> 1) * 64;
  const int quad = l >> 4;
  const int lrow = l & 15;
  const int Ksub = K / gridDim.z;
  const int kbeg = blockIdx.z * Ksub;
  C += (size_t)blockIdx.z * czstride;

  floatx4 acc[4][4];
#pragma unroll
  for (int mi = 0; mi < 4; ++mi)
#pragma unroll
    for (int ni = 0; ni < 4; ++ni) acc[mi][ni] = (floatx4){0.f, 0.f, 0.f, 0.f};

  for (int k0 = kbeg; k0 < kbeg + Ksub; k0 += 32) {
#pragma unroll
    for (int j = 0; j < 2; ++j) {
      const int s = w * 128 + j * 64 + l;          // slot id 0..511
      const int row = ((s >> 6) << 4) + (s & 15);  // 0..127
      const int q = (s >> 4) & 3;
      int ga = bm + row;
      ga = (ga < M) ? ga : (M - 1);                // clamp: keep lanes active
      gld_lds16(A + (size_t)ga * K + k0 + q * 8, sA + s * 16);
      gld_lds16(B + (size_t)(bn + row) * K + k0 + q * 8, sB + s * 16);
    }
    __syncthreads();
    half8 fa[4], fb[4];
#pragma unroll
    for (int mi = 0; mi < 4; ++mi)
      fa[mi] = *(const half8*)(sA + ((wm >> 4) + mi) * 1024 + l * 16);
#pragma unroll
    for (int ni = 0; ni < 4; ++ni)
      fb[ni] = *(const half8*)(sB + ((wn >> 4) + ni) * 1024 + l * 16);
#pragma unroll
    for (int mi = 0; mi < 4; ++mi)
#pragma unroll
      for (int ni = 0; ni < 4; ++ni)
        acc[mi][ni] = __builtin_amdgcn_mfma_f32_16x16x32_f16(fa[mi], fb[ni],
                                                             acc[mi][ni], 0, 0, 0);
    __syncthreads();
  }
  // epilogue: C/D layout col=lane&15, row=quad*4+reg
#pragma unroll
  for (int mi = 0; mi < 4; ++mi) {
    const int rbase = bm + wm + mi * 16 + quad * 4;
#pragma unroll
    for (int r = 0; r < 4; ++r) {
      const int grow = rbase + r;
      if (grow < M) {
#pragma unroll
        for (int ni = 0; ni < 4; ++ni) {
          C[(size_t)grow * N + bn + wn + ni * 16 + lrow] = acc[mi][ni][r];
        }
      }
    }
  }
}

// ------- all three weight transposes + f16 casts in one kernel --------
__global__ void wt_split_all(const float* __restrict__ W1, _Float16* Th1,
                             const float* __restrict__ W2, _Float16* Th2,
                             const float* __restrict__ W3, _Float16* Th3) {
  int idx = blockIdx.x * blockDim.x + threadIdx.x;
  const float* W;
  _Float16* Th;
  int K, N;
  if (idx < 64 * 512) {
    W = W1; Th = Th1; K = 64; N = 512;
  } else if (idx < 64 * 512 + 512 * 512) {
    idx -= 64 * 512;
    W = W2; Th = Th2; K = 512; N = 512;
  } else if (idx < 64 * 512 + 512 * 512 + 512 * 128) {
    idx -= 64 * 512 + 512 * 512;
    W = W3; Th = Th3; K = 512; N = 128;
  } else {
    return;
  }
  const int k = idx / N;
  const int n = idx - k * N;
  Th[n * K + k] = (_Float16)W[idx];
}

// ------- per-encoder prep: x fp32->f16 cast, cnt=1, total=0 -----------
__global__ void prep(const float* __restrict__ X, _Float16* __restrict__ Xh,
                     int* __restrict__ cnt, int* __restrict__ total, int nsplit,
                     int n) {
  const int idx = blockIdx.x * blockDim.x + threadIdx.x;
  if (idx < nsplit) Xh[idx] = (_Float16)X[idx];
  if (idx < n) cnt[idx] = 1;  // the self loop
  if (idx == 0) *total = 0;
}

// ---------------- per-node attention dots (layers 1-2) ----------------
template <int VPL>
__global__ void node_alpha(const float* __restrict__ h,
                           const float* __restrict__ a_src,
                           const float* __restrict__ a_dst,
                           float* __restrict__ asrc,
                           float* __restrict__ adst, int n_nodes) {
  constexpr int WTOT = VPL * 64;
  constexpr int NH = WTOT / 128;
  constexpr int GRP = 128 / VPL;  // lanes per head
  const int gtid = blockIdx.x * blockDim.x + threadIdx.x;
  const int node = gtid >> 6;
  const int lane = threadIdx.x & 63;
  if (node >= n_nodes) return;
  const int head = (lane * VPL) >> 7;
  const float* hrow = h + (size_t)node * WTOT + lane * VPL;
  float s1 = 0.f, s2 = 0.f;
#pragma unroll
  for (int j = 0; j < VPL; ++j) {
    const float v = hrow[j];
    s1 = fmaf(v, a_src[lane * VPL + j], s1);
    s2 = fmaf(v, a_dst[lane * VPL + j], s2);
  }
#pragma unroll
  for (int off = 1; off < GRP; off <<= 1) {
    s1 += __shfl_xor(s1, off);
    s2 += __shfl_xor(s2, off);
  }
  if ((lane & (GRP - 1)) == 0) {
    asrc[node * NH + head] = s1;
    adst[node * NH + head] = s2;
  }
}

// ------- layer-3 alpha: sums split-K halves in place + dots (H=1) -----
__global__ void node_alpha_l3(float* __restrict__ ha, const float* __restrict__ hb,
                              const float* __restrict__ a_src,
                              const float* __restrict__ a_dst,
                              float* __restrict__ asrc, float* __restrict__ adst,
                              int n_nodes) {
  const int gtid = blockIdx.x * blockDim.x + threadIdx.x;
  const int node = gtid >> 6;
  const int lane = threadIdx.x & 63;
  if (node >= n_nodes) return;
  const size_t o = (size_t)node * 128 + lane * 2;
  const float2 va = *(const float2*)(ha + o);
  const float2 vb = *(const float2*)(hb + o);
  const float2 v = make_float2(va.x + vb.x, va.y + vb.y);
  *(float2*)(ha + o) = v;
  float s1 = fmaf(v.x, a_src[lane * 2], v.y * a_src[lane * 2 + 1]);
  float s2 = fmaf(v.x, a_dst[lane * 2], v.y * a_dst[lane * 2 + 1]);
#pragma unroll
  for (int off = 1; off < 64; off <<= 1) {
    s1 += __shfl_xor(s1, off);
    s2 += __shfl_xor(s2, off);
  }
  if (lane == 0) {
    asrc[node] = s1;
    adst[node] = s2;
  }
}

// ---------------- CSR (by dst) build ----------------------------------
__global__ void count_edges(const int* __restrict__ dst, int* __restrict__ cnt,
                            int ne) {
  const int i = blockIdx.x * blockDim.x + threadIdx.x;
  if (i < ne) atomicAdd(&cnt[dst[i]], 1);
}
// Range allocation; also places the self-loop at slot start[i].
__global__ void alloc_ranges(const int* __restrict__ cnt, int* __restrict__ start,
                             int* __restrict__ cursor, int* __restrict__ total,
                             int* __restrict__ csr, int n) {
  const int i = blockIdx.x * blockDim.x + threadIdx.x;
  const int lane = threadIdx.x & 63;
  const int v = (i < n) ? cnt[i] : 0;
  int sc = v;
#pragma unroll
  for (int off = 1; off < 64; off <<= 1) {
    const int t = __shfl_up(sc, off);
    if (lane >= off) sc += t;
  }
  const int wtot = __shfl(sc, 63);
  int base = 0;
  if (lane == 63) base = atomicAdd(total, wtot);
  base = __shfl(base, 63);
  const int st = base + sc - v;
  if (i < n) {
    start[i] = st;
    cursor[i] = st + 1;
    csr[st] = i;  // self loop first
  }
}
__global__ void fill_edges(const int* __restrict__ src, const int* __restrict__ dst,
                           int* __restrict__ cursor, int* __restrict__ csr, int ne) {
  const int i = blockIdx.x * blockDim.x + threadIdx.x;
  if (i < ne) {
    const int p = atomicAdd(&cursor[dst[i]], 1);
    csr[p] = src[i];
  }
}

// ---------------- GAT aggregate, layers 1-2 (fused scores) ------------
// 2 waves per node, lane owns 4 contiguous channels (float4 gathers).
// p = exp(leaky(asrc[src]+adst[node])) inline; no max pass (shift-inv).
// Output: f16 activation (next GEMM's A operand).
__global__ void gat_agg4(const float* __restrict__ h,
                         const float* __restrict__ asrc,
                         const float* __restrict__ adst,
                         const int* __restrict__ start, const int* __restrict__ cnt,
                         const int* __restrict__ csr_src,
                         const float* __restrict__ bias,
                         _Float16* __restrict__ outH, int n_nodes) {
  const int gtid = blockIdx.x * blockDim.x + threadIdx.x;
  const int wid = gtid >> 6;
  const int node = wid >> 1;
  const int sub = wid & 1;
  const int lane = threadIdx.x & 63;
  if (node >= n_nodes) return;
  const int ch = sub * 256 + lane * 4;
  const int head = ch >> 7;
  const int s = start[node];
  const int c = cnt[node];
  const float ad = adst[node * 4 + head];
  float4 a0 = make_float4(0.f, 0.f, 0.f, 0.f);
  float4 a1 = make_float4(0.f, 0.f, 0.f, 0.f);
  float d0 = 0.f, d1 = 0.f;
  int i = 0;
  for (; i + 2 <= c; i += 2) {
    const int s0 = csr_src[s + i];
    const int s1 = csr_src[s + i + 1];
    float e0 = asrc[s0 * 4 + head] + ad;
    float e1 = asrc[s1 * 4 + head] + ad;
    e0 = (e0 > 0.f) ? e0 : kNegSlope * e0;
    e1 = (e1 > 0.f) ? e1 : kNegSlope * e1;
    const float w0 = expf(e0);
    const float w1 = expf(e1);
    const float4 v0 = *(const float4*)(h + (size_t)s0 * 512 + ch);
    const float4 v1 = *(const float4*)(h + (size_t)s1 * 512 + ch);
    d0 += w0;
    d1 += w1;
    a0.x = fmaf(w0, v0.x, a0.x); a1.x = fmaf(w1, v1.x, a1.x);
    a0.y = fmaf(w0, v0.y, a0.y); a1.y = fmaf(w1, v1.y, a1.y);
    a0.z = fmaf(w0, v0.z, a0.z); a1.z = fmaf(w1, v1.z, a1.z);
    a0.w = fmaf(w0, v0.w, a0.w); a1.w = fmaf(w1, v1.w, a1.w);
  }
  if (i < c) {
    const int s0 = csr_src[s + i];
    float e0 = asrc[s0 * 4 + head] + ad;
    e0 = (e0 > 0.f) ? e0 : kNegSlope * e0;
    const float w0 = expf(e0);
    const float4 v0 = *(const float4*)(h + (size_t)s0 * 512 + ch);
    d0 += w0;
    a0.x = fmaf(w0, v0.x, a0.x);
    a0.y = fmaf(w0, v0.y, a0.y);
    a0.z = fmaf(w0, v0.z, a0.z);
    a0.w = fmaf(w0, v0.w, a0.w);
  }
  const float inv = 1.f / (d0 + d1 + 1e-16f);
  float res[4] = {a0.x + a1.x, a0.y + a1.y, a0.z + a1.z, a0.w + a1.w};
  half4 H;
#pragma unroll
  for (int j = 0; j < 4; ++j) {
    float v = res[j] * inv + bias[ch + j];
    v = (v > 0.f) ? v : expm1f(v);  // elu
    H[j] = (_Float16)v;
  }
  *(half4*)(outH + (size_t)node * 512 + ch) = H;
}

// ---------- GAT aggregate, layer 3 (H=1, fp32 out, fused scores) ------
__global__ void gat_agg_l3(const float* __restrict__ h,
                           const float* __restrict__ asrc,
                           const float* __restrict__ adst,
                           const int* __restrict__ start, const int* __restrict__ cnt,
                           const int* __restrict__ csr_src,
                           const float* __restrict__ bias,
                           float* __restrict__ out, int n_nodes) {
  const int gtid = blockIdx.x * blockDim.x + threadIdx.x;
  const int node = gtid >> 6;
  const int lane = threadIdx.x & 63;
  if (node >= n_nodes) return;
  const int s = start[node];
  const int c = cnt[node];
  const float ad = adst[node];
  float2 a0 = make_float2(0.f, 0.f);
  float2 a1 = make_float2(0.f, 0.f);
  float d0 = 0.f, d1 = 0.f;
  int i = 0;
  for (; i + 2 <= c; i += 2) {
    const int s0 = csr_src[s + i];
    const int s1 = csr_src[s + i + 1];
    float e0 = asrc[s0] + ad;
    float e1 = asrc[s1] + ad;
    e0 = (e0 > 0.f) ? e0 : kNegSlope * e0;
    e1 = (e1 > 0.f) ? e1 : kNegSlope * e1;
    const float w0 = expf(e0);
    const float w1 = expf(e1);
    const float2 v0 = *(const float2*)(h + (size_t)s0 * 128 + lane * 2);
    const float2 v1 = *(const float2*)(h + (size_t)s1 * 128 + lane * 2);
    d0 += w0;
    d1 += w1;
    a0.x = fmaf(w0, v0.x, a0.x); a1.x = fmaf(w1, v1.x, a1.x);
    a0.y = fmaf(w0, v0.y, a0.y); a1.y = fmaf(w1, v1.y, a1.y);
  }
  if (i < c) {
    const int s0 = csr_src[s + i];
    float e0 = asrc[s0] + ad;
    e0 = (e0 > 0.f) ? e0 : kNegSlope * e0;
    const float w0 = expf(e0);
    const float2 v0 = *(const float2*)(h + (size_t)s0 * 128 + lane * 2);
    d0 += w0;
    a0.x = fmaf(w0, v0.x, a0.x);
    a0.y = fmaf(w0, v0.y, a0.y);
  }
  const float inv = 1.f / (d0 + d1 + 1e-16f);
  *(float2*)(out + (size_t)node * 128 + lane * 2) =
      make_float2((a0.x + a1.x) * inv + bias[lane * 2],
                  (a0.y + a1.y) * inv + bias[lane * 2 + 1]);
}

// ---------------- global max pool over sorted batch -------------------
__global__ void pool_max(const float* __restrict__ x, const int* __restrict__ batch,
                         float* __restrict__ emb, int n_nodes) {
  __shared__ int lohi[2];
  const int g = blockIdx.x;
  if (threadIdx.x == 0) {
    int lo = 0, hi = n_nodes;
    while (lo < hi) {
      const int mid = (lo + hi) >> 1;
      if (batch[mid] < g) lo = mid + 1; else hi = mid;
    }
    lohi[0] = lo;
    hi = n_nodes;
    while (lo < hi) {
      const int mid = (lo + hi) >> 1;
      if (batch[mid] < g + 1) lo = mid + 1; else hi = mid;
    }
    lohi[1] = lo;
  }
  __syncthreads();
  const int lo = lohi[0], hi = lohi[1];
  const int c = threadIdx.x;  // 128 channels
  float m = -1e30f;
  for (int nid = lo; nid < hi; ++nid) m = fmaxf(m, x[(size_t)nid * 128 + c]);
  emb[g * 128 + c] = (lo < hi) ? m : 0.f;
}

// ---------------- final MLP head --------------------------------------
__global__ void mlp_head(const float* __restrict__ e1, const float* __restrict__ e2,
                         const float* __restrict__ mw1, const float* __restrict__ mb1,
                         const float* __restrict__ mw2, const float* __restrict__ mb2,
                         float* __restrict__ out) {
  __shared__ float z[256];
  __shared__ float red[128];
  const int g = blockIdx.x;
  const int j = threadIdx.x;  // 128
  z[j] = e1[g * 128 + j];
  z[j + 128] = e2[g * 128 + j];
  __syncthreads();
  float acc = mb1[j];
  for (int k = 0; k < 256; ++k) acc = fmaf(z[k], mw1[k * 128 + j], acc);
  acc = fmaxf(acc, 0.f) * mw2[j];
  red[j] = acc;
  __syncthreads();
  for (int s = 64; s > 0; s >>= 1) {
    if (j < s) red[j] += red[j + s];
    __syncthreads();
  }
  if (j == 0) out[g] = red[0] + mb2[0];
}

// ---------------- launcher --------------------------------------------
extern "C" void kernel_launch(void* const* d_in, const int* in_sizes, int n_in,
                              void* d_out, int out_size, void* d_ws, size_t ws_size,
                              hipStream_t stream) {
  (void)in_sizes; (void)n_in; (void)out_size;
  const float* W1 = (const float*)d_in[6];
  const float* as1 = (const float*)d_in[7];
  const float* ad1 = (const float*)d_in[8];
  const float* b1 = (const float*)d_in[9];
  const float* W2 = (const float*)d_in[10];
  const float* as2 = (const float*)d_in[11];
  const float* ad2 = (const float*)d_in[12];
  const float* b2 = (const float*)d_in[13];
  const float* W3 = (const float*)d_in[14];
  const float* as3 = (const float*)d_in[15];
  const float* ad3 = (const float*)d_in[16];
  const float* b3 = (const float*)d_in[17];
  const float* mw1 = (const float*)d_in[18];
  const float* mb1 = (const float*)d_in[19];
  const float* mw2 = (const float*)d_in[20];
  const float* mb2 = (const float*)d_in[21];

  char* w = (char*)d_ws;
  size_t off = 0;
  auto take = [&](size_t bytes) -> void* {
    void* p = w + off;
    off += (bytes + 255) & ~(size_t)255;
    return p;
  };
  _Float16* R1h = (_Float16*)take((size_t)kN * 512 * 2);  // f16 activations
  float* R1f = (float*)R1h;                               // layer-3 out alias
  float* R2 = (float*)take((size_t)kN * 512 * 4);         // h (GEMM out, fp32)
  float* R2b = R2 + (size_t)kN * 128;                     // l3 split-K half 2
  float* asrc = (float*)take((size_t)kN * 4 * 4);
  float* adst = (float*)take((size_t)kN * 4 * 4);
  int* cnt    = (int*)take((size_t)kN * 4);
  int* start  = (int*)take((size_t)kN * 4);
  int* cursor = (int*)take((size_t)kN * 4);
  int* csr    = (int*)take((size_t)kE2 * 4);
  int* total  = (int*)take(256);
  _Float16* Wth1 = (_Float16*)take((size_t)64 * 512 * 2);
  _Float16* Wth2 = (_Float16*)take((size_t)512 * 512 * 2);
  _Float16* Wth3 = (_Float16*)take((size_t)512 * 128 * 2);
  float* emb = (float*)take((size_t)2 * kG * 128 * 4);
  if (off > ws_size) return;

  const int wtot = 64 * 512 + 512 * 512 + 512 * 128;
  wt_split_all<<<(wtot + 255) / 256, 256, 0, stream>>>(W1, Wth1, W2, Wth2, W3, Wth3);

  const int nodeBlocks = (kN * 64) / 256;       // 1 wave/node
  const int aggBlocks4 = (kN * 2 * 64) / 256;   // 2 waves/node
  const dim3 g4((kN + 127) / 128, 4, 1);
  const dim3 g3((kN + 127) / 128, 1, 2);        // layer-3 split-K=2

  for (int enc = 0; enc < 2; ++enc) {
    const float* x = (const float*)d_in[enc * 3 + 0];
    const int* ei = (const int*)d_in[enc * 3 + 1];
    const int* batch = (const int*)d_in[enc * 3 + 2];
    float* embp = emb + (size_t)enc * kG * 128;

    _Float16* A1h = R1h;  // [N,64] f16, dies after layer-1 GEMM
    prep<<<(kN * 64 + 255) / 256, 256, 0, stream>>>(x, A1h, cnt, total, kN * 64, kN);
    count_edges<<<(kE + 255) / 256, 256, 0, stream>>>(ei + kE, cnt, kE);
    alloc_ranges<<<(kN + 255) / 256, 256, 0, stream>>>(cnt, start, cursor, total,
                                                       csr, kN);
    fill_edges<<<(kE + 255) / 256, 256, 0, stream>>>(ei, ei + kE, cursor, csr, kE);

    // layer 1: [N,64] @ [64,512]
    gemm_f16<<<g4, 256, 0, stream>>>(A1h, Wth1, R2, kN, 512, 64, 0);
    node_alpha<8><<<nodeBlocks, 256, 0, stream>>>(R2, as1, ad1, asrc, adst, kN);
    gat_agg4<<<aggBlocks4, 256, 0, stream>>>(R2, asrc, adst, start, cnt, csr, b1,
                                             R1h, kN);
    // layer 2: [N,512] @ [512,512]
    gemm_f16<<<g4, 256, 0, stream>>>(R1h, Wth2, R2, kN, 512, 512, 0);
    node_alpha<8><<<nodeBlocks, 256, 0, stream>>>(R2, as2, ad2, asrc, adst, kN);
    gat_agg4<<<aggBlocks4, 256, 0, stream>>>(R2, asrc, adst, start, cnt, csr, b2,
                                             R1h, kN);
    // layer 3: [N,512] @ [512,128], split-K=2, H=1, no elu, fp32 out
    gemm_f16<<<g3, 256, 0, stream>>>(R1h, Wth3, R2, kN, 128, 512, (size_t)kN * 128);
    node_alpha_l3<<<nodeBlocks, 256, 0, stream>>>(R2, R2b, as3, ad3, asrc, adst, kN);
    gat_agg_l3<<<nodeBlocks, 256, 0, stream>>>(R2, asrc, adst, start, cnt, csr, b3,
                                               R1f, kN);
    pool_max<<<kG, 128, 0, stream>>>(R1f, batch, embp, kN);
  }
  mlp_head<<<kG, 128, 0, stream>>>(emb, emb + (size_t)kG * 128, mw1, mb1, mw2, mb2,
                                   (float*)d_out);
}

// Round 8
// 917.901 us; speedup vs baseline: 1.3223x; 1.1166x over previous
//
#include <hip/hip_runtime.h>
#include <cstdint>

namespace {
constexpr int kN = 50000;          // nodes per encoder
constexpr int kE = 200000;         // directed edges per encoder (pre self-loop)
constexpr int kE2 = kE + kN;       // with self loops (per encoder)
constexpr int kG = 256;            // graphs per encoder
constexpr float kNegSlope = 0.2f;
}

using half8   = __attribute__((ext_vector_type(8))) _Float16;
using floatx4 = __attribute__((ext_vector_type(4))) float;

__device__ __forceinline__ void gld_lds16(const void* g, void* l) {
  __builtin_amdgcn_global_load_lds(
      (const __attribute__((address_space(1))) unsigned int*)g,
      (__attribute__((address_space(3))) unsigned int*)l, 16, 0, 0);
}

// ---------------- fp16 MFMA GEMM: C[M,N] = A[M,K] @ B[K,N] -----------
// Single-product fp16 (fp32 accumulate). A row-major f16 [M,K]; B
// pre-transposed f16 [N,K]. 128x128 tile, BK=32, 256 threads = 4 waves.
// OUTF16: C stored as f16 (layers 1-2 h) vs fp32 (layer-3 split-K).
// blockIdx.z = split-K chunk writing C + z*czstride elements.
__global__ __launch_bounds__(256) void gemm_f16_template_dummy() {}

template <int OUTF16>
__global__ __launch_bounds__(256) void gemm_f16(
    const _Float16* __restrict__ A, const _Float16* __restrict__ B,
    void* __restrict__ Cv, int M, int N, int K, size_t czstride) {
  __shared__ alignas(16) char smem[16384];
  char* sA = smem;
  char* sB = smem + 8192;
  const int t = threadIdx.x;
  const int w = t >> 6;
  const int l = t & 63;
  const int bm = blockIdx.x * 128;
  const int bn = blockIdx.y * 128;
  const int wm = (w & 1) * 64;
  const int wn = (w >> 1) * 64;
  const int quad = l >> 4;
  const int lrow = l & 15;
  const int Ksub = K / gridDim.z;
  const int kbeg = blockIdx.z * Ksub;

  floatx4 acc[4][4];
#pragma unroll
  for (int mi = 0; mi < 4; ++mi)
#pragma unroll
    for (int ni = 0; ni < 4; ++ni) acc[mi][ni] = (floatx4){0.f, 0.f, 0.f, 0.f};

  for (int k0 = kbeg; k0 < kbeg + Ksub; k0 += 32) {
#pragma unroll
    for (int j = 0; j < 2; ++j) {
      const int s = w * 128 + j * 64 + l;          // slot id 0..511
      const int row = ((s >> 6) << 4) + (s & 15);  // 0..127
      const int q = (s >> 4) & 3;
      int ga = bm + row;
      ga = (ga < M) ? ga : (M - 1);                // clamp: keep lanes active
      gld_lds16(A + (size_t)ga * K + k0 + q * 8, sA + s * 16);
      gld_lds16(B + (size_t)(bn + row) * K + k0 + q * 8, sB + s * 16);
    }
    __syncthreads();
    half8 fa[4], fb[4];
#pragma unroll
    for (int mi = 0; mi < 4; ++mi)
      fa[mi] = *(const half8*)(sA + ((wm >> 4) + mi) * 1024 + l * 16);
#pragma unroll
    for (int ni = 0; ni < 4; ++ni)
      fb[ni] = *(const half8*)(sB + ((wn >> 4) + ni) * 1024 + l * 16);
#pragma unroll
    for (int mi = 0; mi < 4; ++mi)
#pragma unroll
      for (int ni = 0; ni < 4; ++ni)
        acc[mi][ni] = __builtin_amdgcn_mfma_f32_16x16x32_f16(fa[mi], fb[ni],
                                                             acc[mi][ni], 0, 0, 0);
    __syncthreads();
  }
  // epilogue: C/D layout col=lane&15, row=quad*4+reg
  const int colbase = bn + wn + lrow;
#pragma unroll
  for (int mi = 0; mi < 4; ++mi) {
    const int rbase = bm + wm + mi * 16 + quad * 4;
#pragma unroll
    for (int r = 0; r < 4; ++r) {
      const int grow = rbase + r;
      if (grow < M) {
        if constexpr (OUTF16) {
          _Float16* C = (_Float16*)Cv;
#pragma unroll
          for (int ni = 0; ni < 4; ++ni)
            C[(size_t)grow * N + colbase + ni * 16] = (_Float16)acc[mi][ni][r];
        } else {
          float* C = (float*)Cv + (size_t)blockIdx.z * czstride;
#pragma unroll
          for (int ni = 0; ni < 4; ++ni)
            C[(size_t)grow * N + colbase + ni * 16] = acc[mi][ni][r];
        }
      }
    }
  }
}

// ------- all three weight transposes + f16 casts in one kernel --------
__global__ void wt_split_all(const float* __restrict__ W1, _Float16* Th1,
                             const float* __restrict__ W2, _Float16* Th2,
                             const float* __restrict__ W3, _Float16* Th3) {
  int idx = blockIdx.x * blockDim.x + threadIdx.x;
  const float* W;
  _Float16* Th;
  int K, N;
  if (idx < 64 * 512) {
    W = W1; Th = Th1; K = 64; N = 512;
  } else if (idx < 64 * 512 + 512 * 512) {
    idx -= 64 * 512;
    W = W2; Th = Th2; K = 512; N = 512;
  } else if (idx < 64 * 512 + 512 * 512 + 512 * 128) {
    idx -= 64 * 512 + 512 * 512;
    W = W3; Th = Th3; K = 512; N = 128;
  } else {
    return;
  }
  const int k = idx / N;
  const int n = idx - k * N;
  Th[n * K + k] = (_Float16)W[idx];
}

// ------- per-encoder prep: x fp32->f16 cast, cnt=1, total=0 -----------
__global__ void prep(const float* __restrict__ X, _Float16* __restrict__ Xh,
                     int* __restrict__ cnt, int* __restrict__ total, int nsplit,
                     int n) {
  const int idx = blockIdx.x * blockDim.x + threadIdx.x;
  if (idx < nsplit) Xh[idx] = (_Float16)X[idx];
  if (idx < n) cnt[idx] = 1;  // the self loop
  if (idx == 0) *total = 0;
}

// ------- per-node attention dots (layers 1-2, f16 h) ------------------
// 1 wave/node, lane owns 8 channels (16B half8 load); head = lane>>4.
__global__ void node_alpha8(const _Float16* __restrict__ h,
                            const float* __restrict__ a_src,
                            const float* __restrict__ a_dst,
                            float* __restrict__ asrc,
                            float* __restrict__ adst, int n_nodes) {
  const int gtid = blockIdx.x * blockDim.x + threadIdx.x;
  const int node = gtid >> 6;
  const int lane = threadIdx.x & 63;
  if (node >= n_nodes) return;
  const int head = lane >> 4;
  const half8 hv = *(const half8*)(h + (size_t)node * 512 + lane * 8);
  float s1 = 0.f, s2 = 0.f;
#pragma unroll
  for (int j = 0; j < 8; ++j) {
    const float v = (float)hv[j];
    s1 = fmaf(v, a_src[lane * 8 + j], s1);
    s2 = fmaf(v, a_dst[lane * 8 + j], s2);
  }
#pragma unroll
  for (int off = 1; off < 16; off <<= 1) {
    s1 += __shfl_xor(s1, off);
    s2 += __shfl_xor(s2, off);
  }
  if ((lane & 15) == 0) {
    asrc[node * 4 + head] = s1;
    adst[node * 4 + head] = s2;
  }
}

// ------- layer-3 alpha: sums split-K halves in place + dots (H=1) -----
__global__ void node_alpha_l3(float* __restrict__ ha, const float* __restrict__ hb,
                              const float* __restrict__ a_src,
                              const float* __restrict__ a_dst,
                              float* __restrict__ asrc, float* __restrict__ adst,
                              int n_nodes) {
  const int gtid = blockIdx.x * blockDim.x + threadIdx.x;
  const int node = gtid >> 6;
  const int lane = threadIdx.x & 63;
  if (node >= n_nodes) return;
  const size_t o = (size_t)node * 128 + lane * 2;
  const float2 va = *(const float2*)(ha + o);
  const float2 vb = *(const float2*)(hb + o);
  const float2 v = make_float2(va.x + vb.x, va.y + vb.y);
  *(float2*)(ha + o) = v;
  float s1 = fmaf(v.x, a_src[lane * 2], v.y * a_src[lane * 2 + 1]);
  float s2 = fmaf(v.x, a_dst[lane * 2], v.y * a_dst[lane * 2 + 1]);
#pragma unroll
  for (int off = 1; off < 64; off <<= 1) {
    s1 += __shfl_xor(s1, off);
    s2 += __shfl_xor(s2, off);
  }
  if (lane == 0) {
    asrc[node] = s1;
    adst[node] = s2;
  }
}

// ---------------- CSR (by dst) build ----------------------------------
__global__ void count_edges(const int* __restrict__ dst, int* __restrict__ cnt,
                            int ne) {
  const int i = blockIdx.x * blockDim.x + threadIdx.x;
  if (i < ne) atomicAdd(&cnt[dst[i]], 1);
}
// Range allocation; also places the self-loop at slot start[i].
__global__ void alloc_ranges(const int* __restrict__ cnt, int* __restrict__ start,
                             int* __restrict__ cursor, int* __restrict__ total,
                             int* __restrict__ csr, int n) {
  const int i = blockIdx.x * blockDim.x + threadIdx.x;
  const int lane = threadIdx.x & 63;
  const int v = (i < n) ? cnt[i] : 0;
  int sc = v;
#pragma unroll
  for (int off = 1; off < 64; off <<= 1) {
    const int t = __shfl_up(sc, off);
    if (lane >= off) sc += t;
  }
  const int wtot = __shfl(sc, 63);
  int base = 0;
  if (lane == 63) base = atomicAdd(total, wtot);
  base = __shfl(base, 63);
  const int st = base + sc - v;
  if (i < n) {
    start[i] = st;
    cursor[i] = st + 1;
    csr[st] = i;  // self loop first
  }
}
__global__ void fill_edges(const int* __restrict__ src, const int* __restrict__ dst,
                           int* __restrict__ cursor, int* __restrict__ csr, int ne) {
  const int i = blockIdx.x * blockDim.x + threadIdx.x;
  if (i < ne) {
    const int p = atomicAdd(&cursor[dst[i]], 1);
    csr[p] = src[i];
  }
}

// ---------------- GAT aggregate, layers 1-2 (f16 h, fused scores) -----
// 1 wave/node, lane owns 8 contiguous channels (16B half8 gathers).
// p = exp(leaky(asrc[src]+adst[node])) inline; no max pass (shift-inv).
__global__ void gat_agg4(const _Float16* __restrict__ h,
                         const float* __restrict__ asrc,
                         const float* __restrict__ adst,
                         const int* __restrict__ start, const int* __restrict__ cnt,
                         const int* __restrict__ csr_src,
                         const float* __restrict__ bias,
                         _Float16* __restrict__ outH, int n_nodes) {
  const int gtid = blockIdx.x * blockDim.x + threadIdx.x;
  const int node = gtid >> 6;
  const int lane = threadIdx.x & 63;
  if (node >= n_nodes) return;
  const int ch = lane * 8;
  const int head = lane >> 4;
  const int s = start[node];
  const int c = cnt[node];
  const float ad = adst[node * 4 + head];
  float a0[8], a1[8];
#pragma unroll
  for (int j = 0; j < 8; ++j) { a0[j] = 0.f; a1[j] = 0.f; }
  float d0 = 0.f, d1 = 0.f;
  int i = 0;
  for (; i + 2 <= c; i += 2) {
    const int s0 = csr_src[s + i];
    const int s1 = csr_src[s + i + 1];
    float e0 = asrc[s0 * 4 + head] + ad;
    float e1 = asrc[s1 * 4 + head] + ad;
    e0 = (e0 > 0.f) ? e0 : kNegSlope * e0;
    e1 = (e1 > 0.f) ? e1 : kNegSlope * e1;
    const float w0 = expf(e0);
    const float w1 = expf(e1);
    const half8 v0 = *(const half8*)(h + (size_t)s0 * 512 + ch);
    const half8 v1 = *(const half8*)(h + (size_t)s1 * 512 + ch);
    d0 += w0;
    d1 += w1;
#pragma unroll
    for (int j = 0; j < 8; ++j) {
      a0[j] = fmaf(w0, (float)v0[j], a0[j]);
      a1[j] = fmaf(w1, (float)v1[j], a1[j]);
    }
  }
  if (i < c) {
    const int s0 = csr_src[s + i];
    float e0 = asrc[s0 * 4 + head] + ad;
    e0 = (e0 > 0.f) ? e0 : kNegSlope * e0;
    const float w0 = expf(e0);
    const half8 v0 = *(const half8*)(h + (size_t)s0 * 512 + ch);
    d0 += w0;
#pragma unroll
    for (int j = 0; j < 8; ++j) a0[j] = fmaf(w0, (float)v0[j], a0[j]);
  }
  const float inv = 1.f / (d0 + d1 + 1e-16f);
  half8 H;
#pragma unroll
  for (int j = 0; j < 8; ++j) {
    float v = (a0[j] + a1[j]) * inv + bias[ch + j];
    v = (v > 0.f) ? v : expm1f(v);  // elu
    H[j] = (_Float16)v;
  }
  *(half8*)(outH + (size_t)node * 512 + ch) = H;
}

// ---------- GAT aggregate, layer 3 (H=1, fp32, fused scores) ----------
__global__ void gat_agg_l3(const float* __restrict__ h,
                           const float* __restrict__ asrc,
                           const float* __restrict__ adst,
                           const int* __restrict__ start, const int* __restrict__ cnt,
                           const int* __restrict__ csr_src,
                           const float* __restrict__ bias,
                           float* __restrict__ out, int n_nodes) {
  const int gtid = blockIdx.x * blockDim.x + threadIdx.x;
  const int node = gtid >> 6;
  const int lane = threadIdx.x & 63;
  if (node >= n_nodes) return;
  const int s = start[node];
  const int c = cnt[node];
  const float ad = adst[node];
  float2 a0 = make_float2(0.f, 0.f);
  float2 a1 = make_float2(0.f, 0.f);
  float d0 = 0.f, d1 = 0.f;
  int i = 0;
  for (; i + 2 <= c; i += 2) {
    const int s0 = csr_src[s + i];
    const int s1 = csr_src[s + i + 1];
    float e0 = asrc[s0] + ad;
    float e1 = asrc[s1] + ad;
    e0 = (e0 > 0.f) ? e0 : kNegSlope * e0;
    e1 = (e1 > 0.f) ? e1 : kNegSlope * e1;
    const float w0 = expf(e0);
    const float w1 = expf(e1);
    const float2 v0 = *(const float2*)(h + (size_t)s0 * 128 + lane * 2);
    const float2 v1 = *(const float2*)(h + (size_t)s1 * 128 + lane * 2);
    d0 += w0;
    d1 += w1;
    a0.x = fmaf(w0, v0.x, a0.x); a1.x = fmaf(w1, v1.x, a1.x);
    a0.y = fmaf(w0, v0.y, a0.y); a1.y = fmaf(w1, v1.y, a1.y);
  }
  if (i < c) {
    const int s0 = csr_src[s + i];
    float e0 = asrc[s0] + ad;
    e0 = (e0 > 0.f) ? e0 : kNegSlope * e0;
    const float w0 = expf(e0);
    const float2 v0 = *(const float2*)(h + (size_t)s0 * 128 + lane * 2);
    d0 += w0;
    a0.x = fmaf(w0, v0.x, a0.x);
    a0.y = fmaf(w0, v0.y, a0.y);
  }
  const float inv = 1.f / (d0 + d1 + 1e-16f);
  *(float2*)(out + (size_t)node * 128 + lane * 2) =
      make_float2((a0.x + a1.x) * inv + bias[lane * 2],
                  (a0.y + a1.y) * inv + bias[lane * 2 + 1]);
}

// ---------------- global max pool over sorted batch -------------------
__global__ void pool_max(const float* __restrict__ x, const int* __restrict__ batch,
                         float* __restrict__ emb, int n_nodes) {
  __shared__ int lohi[2];
  const int g = blockIdx.x;
  if (threadIdx.x == 0) {
    int lo = 0, hi = n_nodes;
    while (lo < hi) {
      const int mid = (lo + hi) >> 1;
      if (batch[mid] < g) lo = mid + 1; else hi = mid;
    }
    lohi[0] = lo;
    hi = n_nodes;
    while (lo < hi) {
      const int mid = (lo + hi) >> 1;
      if (batch[mid] < g + 1) lo = mid + 1; else hi = mid;
    }
    lohi[1] = lo;
  }
  __syncthreads();
  const int lo = lohi[0], hi = lohi[1];
  const int c = threadIdx.x;  // 128 channels
  float m = -1e30f;
  for (int nid = lo; nid < hi; ++nid) m = fmaxf(m, x[(size_t)nid * 128 + c]);
  emb[g * 128 + c] = (lo < hi) ? m : 0.f;
}

// ---------------- final MLP head --------------------------------------
__global__ void mlp_head(const float* __restrict__ e1, const float* __restrict__ e2,
                         const float* __restrict__ mw1, const float* __restrict__ mb1,
                         const float* __restrict__ mw2, const float* __restrict__ mb2,
                         float* __restrict__ out) {
  __shared__ float z[256];
  __shared__ float red[128];
  const int g = blockIdx.x;
  const int j = threadIdx.x;  // 128
  z[j] = e1[g * 128 + j];
  z[j + 128] = e2[g * 128 + j];
  __syncthreads();
  float acc = mb1[j];
  for (int k = 0; k < 256; ++k) acc = fmaf(z[k], mw1[k * 128 + j], acc);
  acc = fmaxf(acc, 0.f) * mw2[j];
  red[j] = acc;
  __syncthreads();
  for (int s = 64; s > 0; s >>= 1) {
    if (j < s) red[j] += red[j + s];
    __syncthreads();
  }
  if (j == 0) out[g] = red[0] + mb2[0];
}

// ---------------- launcher --------------------------------------------
extern "C" void kernel_launch(void* const* d_in, const int* in_sizes, int n_in,
                              void* d_out, int out_size, void* d_ws, size_t ws_size,
                              hipStream_t stream) {
  (void)in_sizes; (void)n_in; (void)out_size;
  const float* W1 = (const float*)d_in[6];
  const float* as1 = (const float*)d_in[7];
  const float* ad1 = (const float*)d_in[8];
  const float* b1 = (const float*)d_in[9];
  const float* W2 = (const float*)d_in[10];
  const float* as2 = (const float*)d_in[11];
  const float* ad2 = (const float*)d_in[12];
  const float* b2 = (const float*)d_in[13];
  const float* W3 = (const float*)d_in[14];
  const float* as3 = (const float*)d_in[15];
  const float* ad3 = (const float*)d_in[16];
  const float* b3 = (const float*)d_in[17];
  const float* mw1 = (const float*)d_in[18];
  const float* mb1 = (const float*)d_in[19];
  const float* mw2 = (const float*)d_in[20];
  const float* mb2 = (const float*)d_in[21];

  char* w = (char*)d_ws;
  size_t off = 0;
  auto take = [&](size_t bytes) -> void* {
    void* p = w + off;
    off += (bytes + 255) & ~(size_t)255;
    return p;
  };
  _Float16* R1h = (_Float16*)take((size_t)kN * 512 * 2);  // f16 activations
  float* R1f = (float*)R1h;                               // layer-3 out alias
  // R2: layers 1-2 h as f16 [N,512]; layer 3 re-uses as fp32 [N,128] x2
  _Float16* R2h = (_Float16*)take((size_t)kN * 512 * 2);
  float* R2f = (float*)R2h;
  float* R2fb = R2f + (size_t)kN * 128;                   // l3 split-K half 2
  float* asrc = (float*)take((size_t)kN * 4 * 4);
  float* adst = (float*)take((size_t)kN * 4 * 4);
  int* cnt    = (int*)take((size_t)kN * 4);
  int* start  = (int*)take((size_t)kN * 4);
  int* cursor = (int*)take((size_t)kN * 4);
  int* csr    = (int*)take((size_t)kE2 * 4);
  int* total  = (int*)take(256);
  _Float16* Wth1 = (_Float16*)take((size_t)64 * 512 * 2);
  _Float16* Wth2 = (_Float16*)take((size_t)512 * 512 * 2);
  _Float16* Wth3 = (_Float16*)take((size_t)512 * 128 * 2);
  float* emb = (float*)take((size_t)2 * kG * 128 * 4);
  if (off > ws_size) return;

  const int wtot = 64 * 512 + 512 * 512 + 512 * 128;
  wt_split_all<<<(wtot + 255) / 256, 256, 0, stream>>>(W1, Wth1, W2, Wth2, W3, Wth3);

  const int nodeBlocks = (kN * 64) / 256;       // 1 wave/node
  const dim3 g4((kN + 127) / 128, 4, 1);
  const dim3 g3((kN + 127) / 128, 1, 2);        // layer-3 split-K=2

  for (int enc = 0; enc < 2; ++enc) {
    const float* x = (const float*)d_in[enc * 3 + 0];
    const int* ei = (const int*)d_in[enc * 3 + 1];
    const int* batch = (const int*)d_in[enc * 3 + 2];
    float* embp = emb + (size_t)enc * kG * 128;

    _Float16* A1h = R1h;  // [N,64] f16, dies after layer-1 GEMM
    prep<<<(kN * 64 + 255) / 256, 256, 0, stream>>>(x, A1h, cnt, total, kN * 64, kN);
    count_edges<<<(kE + 255) / 256, 256, 0, stream>>>(ei + kE, cnt, kE);
    alloc_ranges<<<(kN + 255) / 256, 256, 0, stream>>>(cnt, start, cursor, total,
                                                       csr, kN);
    fill_edges<<<(kE + 255) / 256, 256, 0, stream>>>(ei, ei + kE, cursor, csr, kE);

    // layer 1: [N,64] @ [64,512], h -> f16
    gemm_f16<1><<<g4, 256, 0, stream>>>(A1h, Wth1, R2h, kN, 512, 64, 0);
    node_alpha8<<<nodeBlocks, 256, 0, stream>>>(R2h, as1, ad1, asrc, adst, kN);
    gat_agg4<<<nodeBlocks, 256, 0, stream>>>(R2h, asrc, adst, start, cnt, csr, b1,
                                             R1h, kN);
    // layer 2: [N,512] @ [512,512], h -> f16
    gemm_f16<1><<<g4, 256, 0, stream>>>(R1h, Wth2, R2h, kN, 512, 512, 0);
    node_alpha8<<<nodeBlocks, 256, 0, stream>>>(R2h, as2, ad2, asrc, adst, kN);
    gat_agg4<<<nodeBlocks, 256, 0, stream>>>(R2h, asrc, adst, start, cnt, csr, b2,
                                             R1h, kN);
    // layer 3: [N,512] @ [512,128], split-K=2, H=1, no elu, fp32 out
    gemm_f16<0><<<g3, 256, 0, stream>>>(R1h, Wth3, R2f, kN, 128, 512,
                                        (size_t)kN * 128);
    node_alpha_l3<<<nodeBlocks, 256, 0, stream>>>(R2f, R2fb, as3, ad3, asrc, adst,
                                                  kN);
    gat_agg_l3<<<nodeBlocks, 256, 0, stream>>>(R2f, asrc, adst, start, cnt, csr, b3,
                                               R1f, kN);
    pool_max<<<kG, 128, 0, stream>>>(R1f, batch, embp, kN);
  }
  mlp_head<<<kG, 128, 0, stream>>>(emb, emb + (size_t)kG * 128, mw1, mb1, mw2, mb2,
                                   (float*)d_out);
}

// Round 9
// 853.518 us; speedup vs baseline: 1.4221x; 1.0754x over previous
//
#include <hip/hip_runtime.h>
#include <cstdint>

namespace {
constexpr int kN = 50000;          // nodes per encoder
constexpr int kE = 200000;         // directed edges per encoder (pre self-loop)
constexpr int kE2 = kE + kN;       // with self loops (per encoder)
constexpr int kG = 256;            // graphs per encoder
constexpr float kNegSlope = 0.2f;
}

using half8   = __attribute__((ext_vector_type(8))) _Float16;
using floatx4 = __attribute__((ext_vector_type(4))) float;

__device__ __forceinline__ void gld_lds16(const void* g, void* l) {
  __builtin_amdgcn_global_load_lds(
      (const __attribute__((address_space(1))) unsigned int*)g,
      (__attribute__((address_space(3))) unsigned int*)l, 16, 0, 0);
}

// ---------------- fp16 MFMA GEMM: C[M,N] = A[M,K] @ B[K,N] -----------
// Single-product fp16 (fp32 accumulate). A row-major f16 [M,K]; B
// pre-transposed f16 [N,K]. 128x128 tile, BK=32, 256 threads = 4 waves.
// OUTF16: C stored as f16 (layers 1-2 h) vs fp32 (layer-3 split-K).
template <int OUTF16>
__global__ __launch_bounds__(256) void gemm_f16(
    const _Float16* __restrict__ A, const _Float16* __restrict__ B,
    void* __restrict__ Cv, int M, int N, int K, size_t czstride) {
  __shared__ alignas(16) char smem[16384];
  char* sA = smem;
  char* sB = smem + 8192;
  const int t = threadIdx.x;
  const int w = t >> 6;
  const int l = t & 63;
  const int bm = blockIdx.x * 128;
  const int bn = blockIdx.y * 128;
  const int wm = (w & 1) * 64;
  const int wn = (w >> 1) * 64;
  const int quad = l >> 4;
  const int lrow = l & 15;
  const int Ksub = K / gridDim.z;
  const int kbeg = blockIdx.z * Ksub;

  floatx4 acc[4][4];
#pragma unroll
  for (int mi = 0; mi < 4; ++mi)
#pragma unroll
    for (int ni = 0; ni < 4; ++ni) acc[mi][ni] = (floatx4){0.f, 0.f, 0.f, 0.f};

  for (int k0 = kbeg; k0 < kbeg + Ksub; k0 += 32) {
#pragma unroll
    for (int j = 0; j < 2; ++j) {
      const int s = w * 128 + j * 64 + l;          // slot id 0..511
      const int row = ((s >> 6) << 4) + (s & 15);  // 0..127
      const int q = (s >> 4) & 3;
      int ga = bm + row;
      ga = (ga < M) ? ga : (M - 1);                // clamp: keep lanes active
      gld_lds16(A + (size_t)ga * K + k0 + q * 8, sA + s * 16);
      gld_lds16(B + (size_t)(bn + row) * K + k0 + q * 8, sB + s * 16);
    }
    __syncthreads();
    half8 fa[4], fb[4];
#pragma unroll
    for (int mi = 0; mi < 4; ++mi)
      fa[mi] = *(const half8*)(sA + ((wm >> 4) + mi) * 1024 + l * 16);
#pragma unroll
    for (int ni = 0; ni < 4; ++ni)
      fb[ni] = *(const half8*)(sB + ((wn >> 4) + ni) * 1024 + l * 16);
#pragma unroll
    for (int mi = 0; mi < 4; ++mi)
#pragma unroll
      for (int ni = 0; ni < 4; ++ni)
        acc[mi][ni] = __builtin_amdgcn_mfma_f32_16x16x32_f16(fa[mi], fb[ni],
                                                             acc[mi][ni], 0, 0, 0);
    __syncthreads();
  }
  // epilogue: C/D layout col=lane&15, row=quad*4+reg
  const int colbase = bn + wn + lrow;
#pragma unroll
  for (int mi = 0; mi < 4; ++mi) {
    const int rbase = bm + wm + mi * 16 + quad * 4;
#pragma unroll
    for (int r = 0; r < 4; ++r) {
      const int grow = rbase + r;
      if (grow < M) {
        if constexpr (OUTF16) {
          _Float16* C = (_Float16*)Cv;
#pragma unroll
          for (int ni = 0; ni < 4; ++ni)
            C[(size_t)grow * N + colbase + ni * 16] = (_Float16)acc[mi][ni][r];
        } else {
          float* C = (float*)Cv + (size_t)blockIdx.z * czstride;
#pragma unroll
          for (int ni = 0; ni < 4; ++ni)
            C[(size_t)grow * N + colbase + ni * 16] = acc[mi][ni][r];
        }
      }
    }
  }
}

// ------- all three weight transposes + f16 casts in one kernel --------
__global__ void wt_split_all(const float* __restrict__ W1, _Float16* Th1,
                             const float* __restrict__ W2, _Float16* Th2,
                             const float* __restrict__ W3, _Float16* Th3) {
  int idx = blockIdx.x * blockDim.x + threadIdx.x;
  const float* W;
  _Float16* Th;
  int K, N;
  if (idx < 64 * 512) {
    W = W1; Th = Th1; K = 64; N = 512;
  } else if (idx < 64 * 512 + 512 * 512) {
    idx -= 64 * 512;
    W = W2; Th = Th2; K = 512; N = 512;
  } else if (idx < 64 * 512 + 512 * 512 + 512 * 128) {
    idx -= 64 * 512 + 512 * 512;
    W = W3; Th = Th3; K = 512; N = 128;
  } else {
    return;
  }
  const int k = idx / N;
  const int n = idx - k * N;
  Th[n * K + k] = (_Float16)W[idx];
}

// ------- combined prep: both x casts + cnt=1 (2N) + total=0 -----------
__global__ void prep2(const float* __restrict__ x0, const float* __restrict__ x1,
                      _Float16* __restrict__ Xh, int* __restrict__ cnt,
                      int* __restrict__ total) {
  const int idx = blockIdx.x * blockDim.x + threadIdx.x;
  const int half = kN * 64;
  if (idx < half) Xh[idx] = (_Float16)x0[idx];
  else if (idx < 2 * half) Xh[idx] = (_Float16)x1[idx - half];
  if (idx < 2 * kN) cnt[idx] = 1;  // the self loop
  if (idx == 0) *total = 0;
}
// ------- single-encoder prep (fallback path) --------------------------
__global__ void prep(const float* __restrict__ X, _Float16* __restrict__ Xh,
                     int* __restrict__ cnt, int* __restrict__ total, int nsplit,
                     int n) {
  const int idx = blockIdx.x * blockDim.x + threadIdx.x;
  if (idx < nsplit) Xh[idx] = (_Float16)X[idx];
  if (idx < n) cnt[idx] = 1;
  if (idx == 0) *total = 0;
}

// ------- per-node attention dots (layers 1-2, f16 h) ------------------
__global__ void node_alpha8(const _Float16* __restrict__ h,
                            const float* __restrict__ a_src,
                            const float* __restrict__ a_dst,
                            float* __restrict__ asrc,
                            float* __restrict__ adst, int n_nodes) {
  const int gtid = blockIdx.x * blockDim.x + threadIdx.x;
  const int node = gtid >> 6;
  const int lane = threadIdx.x & 63;
  if (node >= n_nodes) return;
  const int head = lane >> 4;
  const half8 hv = *(const half8*)(h + (size_t)node * 512 + lane * 8);
  float s1 = 0.f, s2 = 0.f;
#pragma unroll
  for (int j = 0; j < 8; ++j) {
    const float v = (float)hv[j];
    s1 = fmaf(v, a_src[lane * 8 + j], s1);
    s2 = fmaf(v, a_dst[lane * 8 + j], s2);
  }
#pragma unroll
  for (int off = 1; off < 16; off <<= 1) {
    s1 += __shfl_xor(s1, off);
    s2 += __shfl_xor(s2, off);
  }
  if ((lane & 15) == 0) {
    asrc[node * 4 + head] = s1;
    adst[node * 4 + head] = s2;
  }
}

// ------- layer-3 alpha: sums split-K halves in place + dots (H=1) -----
__global__ void node_alpha_l3(float* __restrict__ ha, const float* __restrict__ hb,
                              const float* __restrict__ a_src,
                              const float* __restrict__ a_dst,
                              float* __restrict__ asrc, float* __restrict__ adst,
                              int n_nodes) {
  const int gtid = blockIdx.x * blockDim.x + threadIdx.x;
  const int node = gtid >> 6;
  const int lane = threadIdx.x & 63;
  if (node >= n_nodes) return;
  const size_t o = (size_t)node * 128 + lane * 2;
  const float2 va = *(const float2*)(ha + o);
  const float2 vb = *(const float2*)(hb + o);
  const float2 v = make_float2(va.x + vb.x, va.y + vb.y);
  *(float2*)(ha + o) = v;
  float s1 = fmaf(v.x, a_src[lane * 2], v.y * a_src[lane * 2 + 1]);
  float s2 = fmaf(v.x, a_dst[lane * 2], v.y * a_dst[lane * 2 + 1]);
#pragma unroll
  for (int off = 1; off < 64; off <<= 1) {
    s1 += __shfl_xor(s1, off);
    s2 += __shfl_xor(s2, off);
  }
  if (lane == 0) {
    asrc[node] = s1;
    adst[node] = s2;
  }
}

// ---------------- CSR (by dst) build ----------------------------------
__global__ void count_edges(const int* __restrict__ dst, int* __restrict__ cnt,
                            int ne, int node_off) {
  const int i = blockIdx.x * blockDim.x + threadIdx.x;
  if (i < ne) atomicAdd(&cnt[dst[i] + node_off], 1);
}
__global__ void alloc_ranges(const int* __restrict__ cnt, int* __restrict__ start,
                             int* __restrict__ cursor, int* __restrict__ total,
                             int* __restrict__ csr, int n) {
  const int i = blockIdx.x * blockDim.x + threadIdx.x;
  const int lane = threadIdx.x & 63;
  const int v = (i < n) ? cnt[i] : 0;
  int sc = v;
#pragma unroll
  for (int off = 1; off < 64; off <<= 1) {
    const int t = __shfl_up(sc, off);
    if (lane >= off) sc += t;
  }
  const int wtot = __shfl(sc, 63);
  int base = 0;
  if (lane == 63) base = atomicAdd(total, wtot);
  base = __shfl(base, 63);
  const int st = base + sc - v;
  if (i < n) {
    start[i] = st;
    cursor[i] = st + 1;
    csr[st] = i;  // self loop first
  }
}
__global__ void fill_edges(const int* __restrict__ src, const int* __restrict__ dst,
                           int* __restrict__ cursor, int* __restrict__ csr, int ne,
                           int node_off) {
  const int i = blockIdx.x * blockDim.x + threadIdx.x;
  if (i < ne) {
    const int p = atomicAdd(&cursor[dst[i] + node_off], 1);
    csr[p] = src[i] + node_off;
  }
}

// ---------------- GAT aggregate, layers 1-2 (f16 h, fused scores) -----
__global__ void gat_agg4(const _Float16* __restrict__ h,
                         const float* __restrict__ asrc,
                         const float* __restrict__ adst,
                         const int* __restrict__ start, const int* __restrict__ cnt,
                         const int* __restrict__ csr_src,
                         const float* __restrict__ bias,
                         _Float16* __restrict__ outH, int n_nodes) {
  const int gtid = blockIdx.x * blockDim.x + threadIdx.x;
  const int node = gtid >> 6;
  const int lane = threadIdx.x & 63;
  if (node >= n_nodes) return;
  const int ch = lane * 8;
  const int head = lane >> 4;
  const int s = start[node];
  const int c = cnt[node];
  const float ad = adst[node * 4 + head];
  float a0[8], a1[8];
#pragma unroll
  for (int j = 0; j < 8; ++j) { a0[j] = 0.f; a1[j] = 0.f; }
  float d0 = 0.f, d1 = 0.f;
  int i = 0;
  for (; i + 2 <= c; i += 2) {
    const int s0 = csr_src[s + i];
    const int s1 = csr_src[s + i + 1];
    float e0 = asrc[s0 * 4 + head] + ad;
    float e1 = asrc[s1 * 4 + head] + ad;
    e0 = (e0 > 0.f) ? e0 : kNegSlope * e0;
    e1 = (e1 > 0.f) ? e1 : kNegSlope * e1;
    const float w0 = expf(e0);
    const float w1 = expf(e1);
    const half8 v0 = *(const half8*)(h + (size_t)s0 * 512 + ch);
    const half8 v1 = *(const half8*)(h + (size_t)s1 * 512 + ch);
    d0 += w0;
    d1 += w1;
#pragma unroll
    for (int j = 0; j < 8; ++j) {
      a0[j] = fmaf(w0, (float)v0[j], a0[j]);
      a1[j] = fmaf(w1, (float)v1[j], a1[j]);
    }
  }
  if (i < c) {
    const int s0 = csr_src[s + i];
    float e0 = asrc[s0 * 4 + head] + ad;
    e0 = (e0 > 0.f) ? e0 : kNegSlope * e0;
    const float w0 = expf(e0);
    const half8 v0 = *(const half8*)(h + (size_t)s0 * 512 + ch);
    d0 += w0;
#pragma unroll
    for (int j = 0; j < 8; ++j) a0[j] = fmaf(w0, (float)v0[j], a0[j]);
  }
  const float inv = 1.f / (d0 + d1 + 1e-16f);
  half8 H;
#pragma unroll
  for (int j = 0; j < 8; ++j) {
    float v = (a0[j] + a1[j]) * inv + bias[ch + j];
    v = (v > 0.f) ? v : expm1f(v);  // elu
    H[j] = (_Float16)v;
  }
  *(half8*)(outH + (size_t)node * 512 + ch) = H;
}

// ---------- GAT aggregate, layer 3 (H=1, fp32, fused scores) ----------
__global__ void gat_agg_l3(const float* __restrict__ h,
                           const float* __restrict__ asrc,
                           const float* __restrict__ adst,
                           const int* __restrict__ start, const int* __restrict__ cnt,
                           const int* __restrict__ csr_src,
                           const float* __restrict__ bias,
                           float* __restrict__ out, int n_nodes) {
  const int gtid = blockIdx.x * blockDim.x + threadIdx.x;
  const int node = gtid >> 6;
  const int lane = threadIdx.x & 63;
  if (node >= n_nodes) return;
  const int s = start[node];
  const int c = cnt[node];
  const float ad = adst[node];
  float2 a0 = make_float2(0.f, 0.f);
  float2 a1 = make_float2(0.f, 0.f);
  float d0 = 0.f, d1 = 0.f;
  int i = 0;
  for (; i + 2 <= c; i += 2) {
    const int s0 = csr_src[s + i];
    const int s1 = csr_src[s + i + 1];
    float e0 = asrc[s0] + ad;
    float e1 = asrc[s1] + ad;
    e0 = (e0 > 0.f) ? e0 : kNegSlope * e0;
    e1 = (e1 > 0.f) ? e1 : kNegSlope * e1;
    const float w0 = expf(e0);
    const float w1 = expf(e1);
    const float2 v0 = *(const float2*)(h + (size_t)s0 * 128 + lane * 2);
    const float2 v1 = *(const float2*)(h + (size_t)s1 * 128 + lane * 2);
    d0 += w0;
    d1 += w1;
    a0.x = fmaf(w0, v0.x, a0.x); a1.x = fmaf(w1, v1.x, a1.x);
    a0.y = fmaf(w0, v0.y, a0.y); a1.y = fmaf(w1, v1.y, a1.y);
  }
  if (i < c) {
    const int s0 = csr_src[s + i];
    float e0 = asrc[s0] + ad;
    e0 = (e0 > 0.f) ? e0 : kNegSlope * e0;
    const float w0 = expf(e0);
    const float2 v0 = *(const float2*)(h + (size_t)s0 * 128 + lane * 2);
    d0 += w0;
    a0.x = fmaf(w0, v0.x, a0.x);
    a0.y = fmaf(w0, v0.y, a0.y);
  }
  const float inv = 1.f / (d0 + d1 + 1e-16f);
  *(float2*)(out + (size_t)node * 128 + lane * 2) =
      make_float2((a0.x + a1.x) * inv + bias[lane * 2],
                  (a0.y + a1.y) * inv + bias[lane * 2 + 1]);
}

// ---------------- global max pool over sorted batch -------------------
__global__ void pool_max(const float* __restrict__ x, const int* __restrict__ batch,
                         float* __restrict__ emb, int n_nodes) {
  __shared__ int lohi[2];
  const int g = blockIdx.x;
  if (threadIdx.x == 0) {
    int lo = 0, hi = n_nodes;
    while (lo < hi) {
      const int mid = (lo + hi) >> 1;
      if (batch[mid] < g) lo = mid + 1; else hi = mid;
    }
    lohi[0] = lo;
    hi = n_nodes;
    while (lo < hi) {
      const int mid = (lo + hi) >> 1;
      if (batch[mid] < g + 1) lo = mid + 1; else hi = mid;
    }
    lohi[1] = lo;
  }
  __syncthreads();
  const int lo = lohi[0], hi = lohi[1];
  const int c = threadIdx.x;  // 128 channels
  float m = -1e30f;
  for (int nid = lo; nid < hi; ++nid) m = fmaxf(m, x[(size_t)nid * 128 + c]);
  emb[g * 128 + c] = (lo < hi) ? m : 0.f;
}

// ---------------- final MLP head --------------------------------------
__global__ void mlp_head(const float* __restrict__ e1, const float* __restrict__ e2,
                         const float* __restrict__ mw1, const float* __restrict__ mb1,
                         const float* __restrict__ mw2, const float* __restrict__ mb2,
                         float* __restrict__ out) {
  __shared__ float z[256];
  __shared__ float red[128];
  const int g = blockIdx.x;
  const int j = threadIdx.x;  // 128
  z[j] = e1[g * 128 + j];
  z[j + 128] = e2[g * 128 + j];
  __syncthreads();
  float acc = mb1[j];
  for (int k = 0; k < 256; ++k) acc = fmaf(z[k], mw1[k * 128 + j], acc);
  acc = fmaxf(acc, 0.f) * mw2[j];
  red[j] = acc;
  __syncthreads();
  for (int s = 64; s > 0; s >>= 1) {
    if (j < s) red[j] += red[j + s];
    __syncthreads();
  }
  if (j == 0) out[g] = red[0] + mb2[0];
}

// ---------------- launcher --------------------------------------------
namespace {
struct Bufs {
  _Float16 *R1h, *R2h;
  float *R1f, *R2f, *R2fb, *asrc, *adst;
  int *cnt, *start, *cursor, *csr, *total;
  _Float16 *Wth1, *Wth2, *Wth3;
  float* emb;
  size_t need;
};

Bufs plan(void* d_ws, int M, int E) {
  Bufs b;
  char* w = (char*)d_ws;
  size_t off = 0;
  auto take = [&](size_t bytes) -> void* {
    void* p = w + off;
    off += (bytes + 255) & ~(size_t)255;
    return p;
  };
  b.R1h = (_Float16*)take((size_t)M * 512 * 2);  // f16 activations
  b.R1f = (float*)b.R1h;                         // layer-3 out alias [M,128]
  b.R2h = (_Float16*)take((size_t)M * 512 * 2);  // h f16; l3 fp32 x2 alias
  b.R2f = (float*)b.R2h;
  b.R2fb = b.R2f + (size_t)M * 128;
  b.asrc = (float*)take((size_t)M * 4 * 4);
  b.adst = (float*)take((size_t)M * 4 * 4);
  b.cnt = (int*)take((size_t)M * 4);
  b.start = (int*)take((size_t)M * 4);
  b.cursor = (int*)take((size_t)M * 4);
  b.csr = (int*)take((size_t)E * 4);
  b.total = (int*)take(256);
  b.Wth1 = (_Float16*)take((size_t)64 * 512 * 2);
  b.Wth2 = (_Float16*)take((size_t)512 * 512 * 2);
  b.Wth3 = (_Float16*)take((size_t)512 * 128 * 2);
  b.emb = (float*)take((size_t)2 * kG * 128 * 4);
  b.need = off;
  return b;
}

void run_layers(const Bufs& b, void* const* d_in, int M, hipStream_t stream) {
  const float* as1 = (const float*)d_in[7];
  const float* ad1 = (const float*)d_in[8];
  const float* b1 = (const float*)d_in[9];
  const float* as2 = (const float*)d_in[11];
  const float* ad2 = (const float*)d_in[12];
  const float* b2 = (const float*)d_in[13];
  const float* as3 = (const float*)d_in[15];
  const float* ad3 = (const float*)d_in[16];
  const float* b3 = (const float*)d_in[17];
  const int nodeBlocks = (M * 64) / 256;  // 1 wave/node
  const dim3 g4((M + 127) / 128, 4, 1);
  const dim3 g3((M + 127) / 128, 1, 2);   // layer-3 split-K=2

  // layer 1: [M,64] @ [64,512], h -> f16 (A1h aliases R1h)
  gemm_f16<1><<<g4, 256, 0, stream>>>(b.R1h, b.Wth1, b.R2h, M, 512, 64, 0);
  node_alpha8<<<nodeBlocks, 256, 0, stream>>>(b.R2h, as1, ad1, b.asrc, b.adst, M);
  gat_agg4<<<nodeBlocks, 256, 0, stream>>>(b.R2h, b.asrc, b.adst, b.start, b.cnt,
                                           b.csr, b1, b.R1h, M);
  // layer 2: [M,512] @ [512,512], h -> f16
  gemm_f16<1><<<g4, 256, 0, stream>>>(b.R1h, b.Wth2, b.R2h, M, 512, 512, 0);
  node_alpha8<<<nodeBlocks, 256, 0, stream>>>(b.R2h, as2, ad2, b.asrc, b.adst, M);
  gat_agg4<<<nodeBlocks, 256, 0, stream>>>(b.R2h, b.asrc, b.adst, b.start, b.cnt,
                                           b.csr, b2, b.R1h, M);
  // layer 3: [M,512] @ [512,128], split-K=2, H=1, no elu, fp32 out
  gemm_f16<0><<<g3, 256, 0, stream>>>(b.R1h, b.Wth3, b.R2f, M, 128, 512,
                                      (size_t)M * 128);
  node_alpha_l3<<<nodeBlocks, 256, 0, stream>>>(b.R2f, b.R2fb, as3, ad3, b.asrc,
                                                b.adst, M);
  gat_agg_l3<<<nodeBlocks, 256, 0, stream>>>(b.R2f, b.asrc, b.adst, b.start, b.cnt,
                                             b.csr, b3, b.R1f, M);
}
}  // namespace

extern "C" void kernel_launch(void* const* d_in, const int* in_sizes, int n_in,
                              void* d_out, int out_size, void* d_ws, size_t ws_size,
                              hipStream_t stream) {
  (void)in_sizes; (void)n_in; (void)out_size;
  const float* W1 = (const float*)d_in[6];
  const float* W2 = (const float*)d_in[10];
  const float* W3 = (const float*)d_in[14];
  const float* mw1 = (const float*)d_in[18];
  const float* mb1 = (const float*)d_in[19];
  const float* mw2 = (const float*)d_in[20];
  const float* mb2 = (const float*)d_in[21];

  // Prefer combined (both encoders batched, M=2N) if it fits the workspace.
  Bufs bc = plan(d_ws, 2 * kN, 2 * kE2);
  const bool combined = bc.need <= ws_size;
  Bufs b = combined ? bc : plan(d_ws, kN, kE2);

  const int wtot = 64 * 512 + 512 * 512 + 512 * 128;
  wt_split_all<<<(wtot + 255) / 256, 256, 0, stream>>>(W1, b.Wth1, W2, b.Wth2, W3,
                                                       b.Wth3);
  if (combined) {
    const int M = 2 * kN;
    const int* ei0 = (const int*)d_in[1];
    const int* ei1 = (const int*)d_in[4];
    prep2<<<(2 * kN * 64 + 255) / 256, 256, 0, stream>>>(
        (const float*)d_in[0], (const float*)d_in[3], b.R1h, b.cnt, b.total);
    count_edges<<<(kE + 255) / 256, 256, 0, stream>>>(ei0 + kE, b.cnt, kE, 0);
    count_edges<<<(kE + 255) / 256, 256, 0, stream>>>(ei1 + kE, b.cnt, kE, kN);
    alloc_ranges<<<(M + 255) / 256, 256, 0, stream>>>(b.cnt, b.start, b.cursor,
                                                      b.total, b.csr, M);
    fill_edges<<<(kE + 255) / 256, 256, 0, stream>>>(ei0, ei0 + kE, b.cursor, b.csr,
                                                     kE, 0);
    fill_edges<<<(kE + 255) / 256, 256, 0, stream>>>(ei1, ei1 + kE, b.cursor, b.csr,
                                                     kE, kN);
    run_layers(b, d_in, M, stream);
    for (int enc = 0; enc < 2; ++enc) {
      const int* batch = (const int*)d_in[enc * 3 + 2];
      pool_max<<<kG, 128, 0, stream>>>(b.R1f + (size_t)enc * kN * 128, batch,
                                       b.emb + (size_t)enc * kG * 128, kN);
    }
  } else {
    for (int enc = 0; enc < 2; ++enc) {
      const float* x = (const float*)d_in[enc * 3 + 0];
      const int* ei = (const int*)d_in[enc * 3 + 1];
      const int* batch = (const int*)d_in[enc * 3 + 2];
      prep<<<(kN * 64 + 255) / 256, 256, 0, stream>>>(x, b.R1h, b.cnt, b.total,
                                                      kN * 64, kN);
      count_edges<<<(kE + 255) / 256, 256, 0, stream>>>(ei + kE, b.cnt, kE, 0);
      alloc_ranges<<<(kN + 255) / 256, 256, 0, stream>>>(b.cnt, b.start, b.cursor,
                                                         b.total, b.csr, kN);
      fill_edges<<<(kE + 255) / 256, 256, 0, stream>>>(ei, ei + kE, b.cursor, b.csr,
                                                       kE, 0);
      run_layers(b, d_in, kN, stream);
      pool_max<<<kG, 128, 0, stream>>>(b.R1f, batch, b.emb + (size_t)enc * kG * 128,
                                       kN);
    }
  }
  mlp_head<<<kG, 128, 0, stream>>>(b.emb, b.emb + (size_t)kG * 128, mw1, mb1, mw2,
                                   mb2, (float*)d_out);
}

// Round 11
// 754.977 us; speedup vs baseline: 1.6077x; 1.1305x over previous
//
#include <hip/hip_runtime.h>
#include <cstdint>

namespace {
constexpr int kN = 50000;          // nodes per encoder
constexpr int kE = 200000;         // directed edges per encoder (pre self-loop)
constexpr int kE2 = kE + kN;       // with self loops (per encoder)
constexpr int kG = 256;            // graphs per encoder
constexpr float kNegSlope = 0.2f;
}

using half8   = __attribute__((ext_vector_type(8))) _Float16;
using floatx4 = __attribute__((ext_vector_type(4))) float;

__device__ __forceinline__ void gld_lds16(const void* g, void* l) {
  __builtin_amdgcn_global_load_lds(
      (const __attribute__((address_space(1))) unsigned int*)g,
      (__attribute__((address_space(3))) unsigned int*)l, 16, 0, 0);
}

// fast exp: e^x = 2^(x*log2(e)) via hardware v_exp_f32 (no libm call)
__device__ __forceinline__ float fexp(float x) {
  return __builtin_amdgcn_exp2f(x * 1.44269504088896f);
}

// ---------------- fp16 MFMA GEMM: C[M,N] = A[M,K] @ B[K,N] -----------
// Single-product fp16 (fp32 accumulate). A row-major f16 [M,K]; B
// pre-transposed f16 [N,K]. 128x128 tile, BK=32, 256 threads = 4 waves.
// OUTF16: C stored as f16 (layers 1-2 h) vs fp32 (layer-3).
template <int OUTF16>
__global__ __launch_bounds__(256) void gemm_f16(
    const _Float16* __restrict__ A, const _Float16* __restrict__ B,
    void* __restrict__ Cv, int M, int N, int K) {
  __shared__ alignas(16) char smem[16384];
  char* sA = smem;
  char* sB = smem + 8192;
  const int t = threadIdx.x;
  const int w = t >> 6;
  const int l = t & 63;
  const int bm = blockIdx.x * 128;
  const int bn = blockIdx.y * 128;
  const int wm = (w & 1) * 64;
  const int wn = (w >> 1) * 64;
  const int quad = l >> 4;
  const int lrow = l & 15;

  floatx4 acc[4][4];
#pragma unroll
  for (int mi = 0; mi < 4; ++mi)
#pragma unroll
    for (int ni = 0; ni < 4; ++ni) acc[mi][ni] = (floatx4){0.f, 0.f, 0.f, 0.f};

  for (int k0 = 0; k0 < K; k0 += 32) {
#pragma unroll
    for (int j = 0; j < 2; ++j) {
      const int s = w * 128 + j * 64 + l;          // slot id 0..511
      const int row = ((s >> 6) << 4) + (s & 15);  // 0..127
      const int q = (s >> 4) & 3;
      int ga = bm + row;
      ga = (ga < M) ? ga : (M - 1);                // clamp: keep lanes active
      gld_lds16(A + (size_t)ga * K + k0 + q * 8, sA + s * 16);
      gld_lds16(B + (size_t)(bn + row) * K + k0 + q * 8, sB + s * 16);
    }
    __syncthreads();
    half8 fa[4], fb[4];
#pragma unroll
    for (int mi = 0; mi < 4; ++mi)
      fa[mi] = *(const half8*)(sA + ((wm >> 4) + mi) * 1024 + l * 16);
#pragma unroll
    for (int ni = 0; ni < 4; ++ni)
      fb[ni] = *(const half8*)(sB + ((wn >> 4) + ni) * 1024 + l * 16);
#pragma unroll
    for (int mi = 0; mi < 4; ++mi)
#pragma unroll
      for (int ni = 0; ni < 4; ++ni)
        acc[mi][ni] = __builtin_amdgcn_mfma_f32_16x16x32_f16(fa[mi], fb[ni],
                                                             acc[mi][ni], 0, 0, 0);
    __syncthreads();
  }
  // epilogue: C/D layout col=lane&15, row=quad*4+reg
  const int colbase = bn + wn + lrow;
#pragma unroll
  for (int mi = 0; mi < 4; ++mi) {
    const int rbase = bm + wm + mi * 16 + quad * 4;
#pragma unroll
    for (int r = 0; r < 4; ++r) {
      const int grow = rbase + r;
      if (grow < M) {
        if constexpr (OUTF16) {
          _Float16* C = (_Float16*)Cv;
#pragma unroll
          for (int ni = 0; ni < 4; ++ni)
            C[(size_t)grow * N + colbase + ni * 16] = (_Float16)acc[mi][ni][r];
        } else {
          float* C = (float*)Cv;
#pragma unroll
          for (int ni = 0; ni < 4; ++ni)
            C[(size_t)grow * N + colbase + ni * 16] = acc[mi][ni][r];
        }
      }
    }
  }
}

// ------- all three weight transposes + f16 casts in one kernel --------
__global__ void wt_split_all(const float* __restrict__ W1, _Float16* Th1,
                             const float* __restrict__ W2, _Float16* Th2,
                             const float* __restrict__ W3, _Float16* Th3) {
  int idx = blockIdx.x * blockDim.x + threadIdx.x;
  const float* W;
  _Float16* Th;
  int K, N;
  if (idx < 64 * 512) {
    W = W1; Th = Th1; K = 64; N = 512;
  } else if (idx < 64 * 512 + 512 * 512) {
    idx -= 64 * 512;
    W = W2; Th = Th2; K = 512; N = 512;
  } else if (idx < 64 * 512 + 512 * 512 + 512 * 128) {
    idx -= 64 * 512 + 512 * 512;
    W = W3; Th = Th3; K = 512; N = 128;
  } else {
    return;
  }
  const int k = idx / N;
  const int n = idx - k * N;
  Th[n * K + k] = (_Float16)W[idx];
}

// ------- combined prep: both x casts + cnt=1 (2N) + total=0 -----------
__global__ void prep2(const float* __restrict__ x0, const float* __restrict__ x1,
                      _Float16* __restrict__ Xh, int* __restrict__ cnt,
                      int* __restrict__ total) {
  const int idx = blockIdx.x * blockDim.x + threadIdx.x;
  const int half = kN * 64;
  if (idx < half) Xh[idx] = (_Float16)x0[idx];
  else if (idx < 2 * half) Xh[idx] = (_Float16)x1[idx - half];
  if (idx < 2 * kN) cnt[idx] = 1;  // the self loop
  if (idx == 0) *total = 0;
}
// ------- single-encoder prep (fallback path) --------------------------
__global__ void prep(const float* __restrict__ X, _Float16* __restrict__ Xh,
                     int* __restrict__ cnt, int* __restrict__ total, int nsplit,
                     int n) {
  const int idx = blockIdx.x * blockDim.x + threadIdx.x;
  if (idx < nsplit) Xh[idx] = (_Float16)X[idx];
  if (idx < n) cnt[idx] = 1;
  if (idx == 0) *total = 0;
}

// ------- per-node attention dots (layers 1-2, f16 h) ------------------
__global__ void node_alpha8(const _Float16* __restrict__ h,
                            const float* __restrict__ a_src,
                            const float* __restrict__ a_dst,
                            float* __restrict__ asrc,
                            float* __restrict__ adst, int n_nodes) {
  const int gtid = blockIdx.x * blockDim.x + threadIdx.x;
  const int node = gtid >> 6;
  const int lane = threadIdx.x & 63;
  if (node >= n_nodes) return;
  const int head = lane >> 4;
  const half8 hv = *(const half8*)(h + (size_t)node * 512 + lane * 8);
  float s1 = 0.f, s2 = 0.f;
#pragma unroll
  for (int j = 0; j < 8; ++j) {
    const float v = (float)hv[j];
    s1 = fmaf(v, a_src[lane * 8 + j], s1);
    s2 = fmaf(v, a_dst[lane * 8 + j], s2);
  }
#pragma unroll
  for (int off = 1; off < 16; off <<= 1) {
    s1 += __shfl_xor(s1, off);
    s2 += __shfl_xor(s2, off);
  }
  if ((lane & 15) == 0) {
    asrc[node * 4 + head] = s1;
    adst[node * 4 + head] = s2;
  }
}

// ------- layer-3 alpha: dots over fp32 h [M,128] (H=1) ----------------
__global__ void node_alpha_l3(const float* __restrict__ h,
                              const float* __restrict__ a_src,
                              const float* __restrict__ a_dst,
                              float* __restrict__ asrc, float* __restrict__ adst,
                              int n_nodes) {
  const int gtid = blockIdx.x * blockDim.x + threadIdx.x;
  const int node = gtid >> 6;
  const int lane = threadIdx.x & 63;
  if (node >= n_nodes) return;
  const float2 v = *(const float2*)(h + (size_t)node * 128 + lane * 2);
  float s1 = fmaf(v.x, a_src[lane * 2], v.y * a_src[lane * 2 + 1]);
  float s2 = fmaf(v.x, a_dst[lane * 2], v.y * a_dst[lane * 2 + 1]);
#pragma unroll
  for (int off = 1; off < 64; off <<= 1) {
    s1 += __shfl_xor(s1, off);
    s2 += __shfl_xor(s2, off);
  }
  if (lane == 0) {
    asrc[node] = s1;
    adst[node] = s2;
  }
}

// ---------------- CSR (by dst) build ----------------------------------
// Combined: both encoders' edges in one dispatch.
__global__ void count_edges2(const int* __restrict__ d0, const int* __restrict__ d1,
                             int* __restrict__ cnt) {
  const int i = blockIdx.x * blockDim.x + threadIdx.x;
  if (i < kE) atomicAdd(&cnt[d0[i]], 1);
  else if (i < 2 * kE) atomicAdd(&cnt[d1[i - kE] + kN], 1);
}
__global__ void fill_edges2(const int* __restrict__ s0, const int* __restrict__ d0,
                            const int* __restrict__ s1, const int* __restrict__ d1,
                            int* __restrict__ cursor, int* __restrict__ csr) {
  const int i = blockIdx.x * blockDim.x + threadIdx.x;
  if (i < kE) {
    const int p = atomicAdd(&cursor[d0[i]], 1);
    csr[p] = s0[i];
  } else if (i < 2 * kE) {
    const int j = i - kE;
    const int p = atomicAdd(&cursor[d1[j] + kN], 1);
    csr[p] = s1[j] + kN;
  }
}
__global__ void count_edges(const int* __restrict__ dst, int* __restrict__ cnt,
                            int ne) {
  const int i = blockIdx.x * blockDim.x + threadIdx.x;
  if (i < ne) atomicAdd(&cnt[dst[i]], 1);
}
__global__ void fill_edges(const int* __restrict__ src, const int* __restrict__ dst,
                           int* __restrict__ cursor, int* __restrict__ csr, int ne) {
  const int i = blockIdx.x * blockDim.x + threadIdx.x;
  if (i < ne) {
    const int p = atomicAdd(&cursor[dst[i]], 1);
    csr[p] = src[i];
  }
}
__global__ void alloc_ranges(const int* __restrict__ cnt, int* __restrict__ start,
                             int* __restrict__ cursor, int* __restrict__ total,
                             int* __restrict__ csr, int n) {
  const int i = blockIdx.x * blockDim.x + threadIdx.x;
  const int lane = threadIdx.x & 63;
  const int v = (i < n) ? cnt[i] : 0;
  int sc = v;
#pragma unroll
  for (int off = 1; off < 64; off <<= 1) {
    const int t = __shfl_up(sc, off);
    if (lane >= off) sc += t;
  }
  const int wtot = __shfl(sc, 63);
  int base = 0;
  if (lane == 63) base = atomicAdd(total, wtot);
  base = __shfl(base, 63);
  const int st = base + sc - v;
  if (i < n) {
    start[i] = st;
    cursor[i] = st + 1;
    csr[st] = i;  // self loop first
  }
}

// ---------------- GAT aggregate, layers 1-2 (f16 h, fused scores) -----
__global__ void gat_agg4(const _Float16* __restrict__ h,
                         const float* __restrict__ asrc,
                         const float* __restrict__ adst,
                         const int* __restrict__ start, const int* __restrict__ cnt,
                         const int* __restrict__ csr_src,
                         const float* __restrict__ bias,
                         _Float16* __restrict__ outH, int n_nodes) {
  const int gtid = blockIdx.x * blockDim.x + threadIdx.x;
  const int node = gtid >> 6;
  const int lane = threadIdx.x & 63;
  if (node >= n_nodes) return;
  const int ch = lane * 8;
  const int head = lane >> 4;
  const int s = start[node];
  const int c = cnt[node];
  const float ad = adst[node * 4 + head];
  float a0[8], a1[8];
#pragma unroll
  for (int j = 0; j < 8; ++j) { a0[j] = 0.f; a1[j] = 0.f; }
  float d0 = 0.f, d1 = 0.f;
  int i = 0;
  for (; i + 2 <= c; i += 2) {
    const int s0 = csr_src[s + i];
    const int s1 = csr_src[s + i + 1];
    float e0 = asrc[s0 * 4 + head] + ad;
    float e1 = asrc[s1 * 4 + head] + ad;
    e0 = (e0 > 0.f) ? e0 : kNegSlope * e0;
    e1 = (e1 > 0.f) ? e1 : kNegSlope * e1;
    const float w0 = fexp(e0);
    const float w1 = fexp(e1);
    const half8 v0 = *(const half8*)(h + (size_t)s0 * 512 + ch);
    const half8 v1 = *(const half8*)(h + (size_t)s1 * 512 + ch);
    d0 += w0;
    d1 += w1;
#pragma unroll
    for (int j = 0; j < 8; ++j) {
      a0[j] = fmaf(w0, (float)v0[j], a0[j]);
      a1[j] = fmaf(w1, (float)v1[j], a1[j]);
    }
  }
  if (i < c) {
    const int s0 = csr_src[s + i];
    float e0 = asrc[s0 * 4 + head] + ad;
    e0 = (e0 > 0.f) ? e0 : kNegSlope * e0;
    const float w0 = fexp(e0);
    const half8 v0 = *(const half8*)(h + (size_t)s0 * 512 + ch);
    d0 += w0;
#pragma unroll
    for (int j = 0; j < 8; ++j) a0[j] = fmaf(w0, (float)v0[j], a0[j]);
  }
  const float inv = 1.f / (d0 + d1 + 1e-16f);
  half8 H;
#pragma unroll
  for (int j = 0; j < 8; ++j) {
    float v = (a0[j] + a1[j]) * inv + bias[ch + j];
    v = (v > 0.f) ? v : (fexp(v) - 1.f);  // elu via hw exp
    H[j] = (_Float16)v;
  }
  *(half8*)(outH + (size_t)node * 512 + ch) = H;
}

// ---------- GAT aggregate, layer 3 (H=1, fp32, fused scores) ----------
__global__ void gat_agg_l3(const float* __restrict__ h,
                           const float* __restrict__ asrc,
                           const float* __restrict__ adst,
                           const int* __restrict__ start, const int* __restrict__ cnt,
                           const int* __restrict__ csr_src,
                           const float* __restrict__ bias,
                           float* __restrict__ out, int n_nodes) {
  const int gtid = blockIdx.x * blockDim.x + threadIdx.x;
  const int node = gtid >> 6;
  const int lane = threadIdx.x & 63;
  if (node >= n_nodes) return;
  const int s = start[node];
  const int c = cnt[node];
  const float ad = adst[node];
  float2 a0 = make_float2(0.f, 0.f);
  float2 a1 = make_float2(0.f, 0.f);
  float d0 = 0.f, d1 = 0.f;
  int i = 0;
  for (; i + 2 <= c; i += 2) {
    const int s0 = csr_src[s + i];
    const int s1 = csr_src[s + i + 1];
    float e0 = asrc[s0] + ad;
    float e1 = asrc[s1] + ad;
    e0 = (e0 > 0.f) ? e0 : kNegSlope * e0;
    e1 = (e1 > 0.f) ? e1 : kNegSlope * e1;
    const float w0 = fexp(e0);
    const float w1 = fexp(e1);
    const float2 v0 = *(const float2*)(h + (size_t)s0 * 128 + lane * 2);
    const float2 v1 = *(const float2*)(h + (size_t)s1 * 128 + lane * 2);
    d0 += w0;
    d1 += w1;
    a0.x = fmaf(w0, v0.x, a0.x); a1.x = fmaf(w1, v1.x, a1.x);
    a0.y = fmaf(w0, v0.y, a0.y); a1.y = fmaf(w1, v1.y, a1.y);
  }
  if (i < c) {
    const int s0 = csr_src[s + i];
    float e0 = asrc[s0] + ad;
    e0 = (e0 > 0.f) ? e0 : kNegSlope * e0;
    const float w0 = fexp(e0);
    const float2 v0 = *(const float2*)(h + (size_t)s0 * 128 + lane * 2);
    d0 += w0;
    a0.x = fmaf(w0, v0.x, a0.x);
    a0.y = fmaf(w0, v0.y, a0.y);
  }
  const float inv = 1.f / (d0 + d1 + 1e-16f);
  *(float2*)(out + (size_t)node * 128 + lane * 2) =
      make_float2((a0.x + a1.x) * inv + bias[lane * 2],
                  (a0.y + a1.y) * inv + bias[lane * 2 + 1]);
}

// ---------------- global max pool over sorted batch -------------------
__global__ void pool_max(const float* __restrict__ x, const int* __restrict__ batch,
                         float* __restrict__ emb, int n_nodes) {
  __shared__ int lohi[2];
  const int g = blockIdx.x;
  if (threadIdx.x == 0) {
    int lo = 0, hi = n_nodes;
    while (lo < hi) {
      const int mid = (lo + hi) >> 1;
      if (batch[mid] < g) lo = mid + 1; else hi = mid;
    }
    lohi[0] = lo;
    hi = n_nodes;
    while (lo < hi) {
      const int mid = (lo + hi) >> 1;
      if (batch[mid] < g + 1) lo = mid + 1; else hi = mid;
    }
    lohi[1] = lo;
  }
  __syncthreads();
  const int lo = lohi[0], hi = lohi[1];
  const int c = threadIdx.x;  // 128 channels
  float m = -1e30f;
  for (int nid = lo; nid < hi; ++nid) m = fmaxf(m, x[(size_t)nid * 128 + c]);
  emb[g * 128 + c] = (lo < hi) ? m : 0.f;
}

// ---------------- final MLP head --------------------------------------
__global__ void mlp_head(const float* __restrict__ e1, const float* __restrict__ e2,
                         const float* __restrict__ mw1, const float* __restrict__ mb1,
                         const float* __restrict__ mw2, const float* __restrict__ mb2,
                         float* __restrict__ out) {
  __shared__ float z[256];
  __shared__ float red[128];
  const int g = blockIdx.x;
  const int j = threadIdx.x;  // 128
  z[j] = e1[g * 128 + j];
  z[j + 128] = e2[g * 128 + j];
  __syncthreads();
  float acc = mb1[j];
  for (int k = 0; k < 256; ++k) acc = fmaf(z[k], mw1[k * 128 + j], acc);
  acc = fmaxf(acc, 0.f) * mw2[j];
  red[j] = acc;
  __syncthreads();
  for (int s = 64; s > 0; s >>= 1) {
    if (j < s) red[j] += red[j + s];
    __syncthreads();
  }
  if (j == 0) out[g] = red[0] + mb2[0];
}

// ---------------- launcher --------------------------------------------
namespace {
struct Bufs {
  _Float16 *R1h, *R2h;
  float *R1f, *R2f, *asrc, *adst;
  int *cnt, *start, *cursor, *csr, *total;
  _Float16 *Wth1, *Wth2, *Wth3;
  float* emb;
  size_t need;
};

Bufs plan(void* d_ws, int M, int E) {
  Bufs b;
  char* w = (char*)d_ws;
  size_t off = 0;
  auto take = [&](size_t bytes) -> void* {
    void* p = w + off;
    off += (bytes + 255) & ~(size_t)255;
    return p;
  };
  b.R1h = (_Float16*)take((size_t)M * 512 * 2);  // f16 activations
  b.R1f = (float*)b.R1h;                         // layer-3 out alias [M,128]
  b.R2h = (_Float16*)take((size_t)M * 512 * 2);  // h f16; l3 fp32 alias
  b.R2f = (float*)b.R2h;
  b.asrc = (float*)take((size_t)M * 4 * 4);
  b.adst = (float*)take((size_t)M * 4 * 4);
  b.cnt = (int*)take((size_t)M * 4);
  b.start = (int*)take((size_t)M * 4);
  b.cursor = (int*)take((size_t)M * 4);
  b.csr = (int*)take((size_t)E * 4);
  b.total = (int*)take(256);
  b.Wth1 = (_Float16*)take((size_t)64 * 512 * 2);
  b.Wth2 = (_Float16*)take((size_t)512 * 512 * 2);
  b.Wth3 = (_Float16*)take((size_t)512 * 128 * 2);
  b.emb = (float*)take((size_t)2 * kG * 128 * 4);
  b.need = off;
  return b;
}

void run_layers(const Bufs& b, void* const* d_in, int M, hipStream_t stream) {
  const float* as1 = (const float*)d_in[7];
  const float* ad1 = (const float*)d_in[8];
  const float* b1 = (const float*)d_in[9];
  const float* as2 = (const float*)d_in[11];
  const float* ad2 = (const float*)d_in[12];
  const float* b2 = (const float*)d_in[13];
  const float* as3 = (const float*)d_in[15];
  const float* ad3 = (const float*)d_in[16];
  const float* b3 = (const float*)d_in[17];
  const int nodeBlocks = (M * 64) / 256;  // 1 wave/node
  const dim3 g4((M + 127) / 128, 4, 1);
  const dim3 g3((M + 127) / 128, 1, 1);

  // layer 1: [M,64] @ [64,512], h -> f16 (A1h aliases R1h)
  gemm_f16<1><<<g4, 256, 0, stream>>>(b.R1h, b.Wth1, b.R2h, M, 512, 64);
  node_alpha8<<<nodeBlocks, 256, 0, stream>>>(b.R2h, as1, ad1, b.asrc, b.adst, M);
  gat_agg4<<<nodeBlocks, 256, 0, stream>>>(b.R2h, b.asrc, b.adst, b.start, b.cnt,
                                           b.csr, b1, b.R1h, M);
  // layer 2: [M,512] @ [512,512], h -> f16
  gemm_f16<1><<<g4, 256, 0, stream>>>(b.R1h, b.Wth2, b.R2h, M, 512, 512);
  node_alpha8<<<nodeBlocks, 256, 0, stream>>>(b.R2h, as2, ad2, b.asrc, b.adst, M);
  gat_agg4<<<nodeBlocks, 256, 0, stream>>>(b.R2h, b.asrc, b.adst, b.start, b.cnt,
                                           b.csr, b2, b.R1h, M);
  // layer 3: [M,512] @ [512,128], H=1, no elu, fp32 out
  gemm_f16<0><<<g3, 256, 0, stream>>>(b.R1h, b.Wth3, b.R2f, M, 128, 512);
  node_alpha_l3<<<nodeBlocks, 256, 0, stream>>>(b.R2f, as3, ad3, b.asrc, b.adst, M);
  gat_agg_l3<<<nodeBlocks, 256, 0, stream>>>(b.R2f, b.asrc, b.adst, b.start, b.cnt,
                                             b.csr, b3, b.R1f, M);
}
}  // namespace

extern "C" void kernel_launch(void* const* d_in, const int* in_sizes, int n_in,
                              void* d_out, int out_size, void* d_ws, size_t ws_size,
                              hipStream_t stream) {
  (void)in_sizes; (void)n_in; (void)out_size;
  const float* W1 = (const float*)d_in[6];
  const float* W2 = (const float*)d_in[10];
  const float* W3 = (const float*)d_in[14];
  const float* mw1 = (const float*)d_in[18];
  const float* mb1 = (const float*)d_in[19];
  const float* mw2 = (const float*)d_in[20];
  const float* mb2 = (const float*)d_in[21];

  // Prefer combined (both encoders batched, M=2N) if it fits the workspace.
  Bufs bc = plan(d_ws, 2 * kN, 2 * kE2);
  const bool combined = bc.need <= ws_size;
  Bufs b = combined ? bc : plan(d_ws, kN, kE2);

  const int wtot = 64 * 512 + 512 * 512 + 512 * 128;
  wt_split_all<<<(wtot + 255) / 256, 256, 0, stream>>>(W1, b.Wth1, W2, b.Wth2, W3,
                                                       b.Wth3);
  if (combined) {
    const int M = 2 * kN;
    const int* ei0 = (const int*)d_in[1];
    const int* ei1 = (const int*)d_in[4];
    prep2<<<(2 * kN * 64 + 255) / 256, 256, 0, stream>>>(
        (const float*)d_in[0], (const float*)d_in[3], b.R1h, b.cnt, b.total);
    count_edges2<<<(2 * kE + 255) / 256, 256, 0, stream>>>(ei0 + kE, ei1 + kE,
                                                           b.cnt);
    alloc_ranges<<<(M + 255) / 256, 256, 0, stream>>>(b.cnt, b.start, b.cursor,
                                                      b.total, b.csr, M);
    fill_edges2<<<(2 * kE + 255) / 256, 256, 0, stream>>>(ei0, ei0 + kE, ei1,
                                                          ei1 + kE, b.cursor, b.csr);
    run_layers(b, d_in, M, stream);
    for (int enc = 0; enc < 2; ++enc) {
      const int* batch = (const int*)d_in[enc * 3 + 2];
      pool_max<<<kG, 128, 0, stream>>>(b.R1f + (size_t)enc * kN * 128, batch,
                                       b.emb + (size_t)enc * kG * 128, kN);
    }
  } else {
    for (int enc = 0; enc < 2; ++enc) {
      const float* x = (const float*)d_in[enc * 3 + 0];
      const int* ei = (const int*)d_in[enc * 3 + 1];
      const int* batch = (const int*)d_in[enc * 3 + 2];
      prep<<<(kN * 64 + 255) / 256, 256, 0, stream>>>(x, b.R1h, b.cnt, b.total,
                                                      kN * 64, kN);
      count_edges<<<(kE + 255) / 256, 256, 0, stream>>>(ei + kE, b.cnt, kE);
      alloc_ranges<<<(kN + 255) / 256, 256, 0, stream>>>(b.cnt, b.start, b.cursor,
                                                         b.total, b.csr, kN);
      fill_edges<<<(kE + 255) / 256, 256, 0, stream>>>(ei, ei + kE, b.cursor, b.csr,
                                                       kE);
      run_layers(b, d_in, kN, stream);
      pool_max<<<kG, 128, 0, stream>>>(b.R1f, batch, b.emb + (size_t)enc * kG * 128,
                                       kN);
    }
  }
  mlp_head<<<kG, 128, 0, stream>>>(b.emb, b.emb + (size_t)kG * 128, mw1, mb1, mw2,
                                   mb2, (float*)d_out);
}

// Round 12
// 754.483 us; speedup vs baseline: 1.6087x; 1.0007x over previous
//
#include <hip/hip_runtime.h>
#include <cstdint>

namespace {
constexpr int kN = 50000;          // nodes per encoder
constexpr int kE = 200000;         // directed edges per encoder (pre self-loop)
constexpr int kE2 = kE + kN;       // with self loops (per encoder)
constexpr int kG = 256;            // graphs per encoder
constexpr float kNegSlope = 0.2f;
}

using half8   = __attribute__((ext_vector_type(8))) _Float16;
using floatx4 = __attribute__((ext_vector_type(4))) float;

__device__ __forceinline__ void gld_lds16(const void* g, void* l) {
  __builtin_amdgcn_global_load_lds(
      (const __attribute__((address_space(1))) unsigned int*)g,
      (__attribute__((address_space(3))) unsigned int*)l, 16, 0, 0);
}

// fast exp: e^x = 2^(x*log2(e)) via hardware v_exp_f32 (no libm call)
__device__ __forceinline__ float fexp(float x) {
  return __builtin_amdgcn_exp2f(x * 1.44269504088896f);
}

// ---------------- fp16 MFMA GEMM: C[M,N] = A[M,K] @ B[K,N] -----------
// Single-product fp16 (fp32 accumulate). A row-major f16 [M,K]; B
// pre-transposed f16 [N,K]. 128x128 tile, BK=32, 256 threads = 4 waves.
// 1-D grid, NT col-tiles: bm=(id/NT)*128, bn=(id%NT)*128 — consecutive
// ids share the A row-tile (co-resident => A fetched from HBM once; the
// (782,4) 2-D grid streamed A twice: R11 FETCH=2xA).
// OUTF16: C stored as f16 (layers 1-2 h) vs fp32 (layer-3).
template <int OUTF16, int NT>
__global__ __launch_bounds__(256) void gemm_f16(
    const _Float16* __restrict__ A, const _Float16* __restrict__ B,
    void* __restrict__ Cv, int M, int N, int K) {
  __shared__ alignas(16) char smem[16384];
  char* sA = smem;
  char* sB = smem + 8192;
  const int t = threadIdx.x;
  const int w = t >> 6;
  const int l = t & 63;
  const int bm = (blockIdx.x / NT) * 128;
  const int bn = (blockIdx.x % NT) * 128;
  const int wm = (w & 1) * 64;
  const int wn = (w >> 1) * 64;
  const int quad = l >> 4;
  const int lrow = l & 15;

  floatx4 acc[4][4];
#pragma unroll
  for (int mi = 0; mi < 4; ++mi)
#pragma unroll
    for (int ni = 0; ni < 4; ++ni) acc[mi][ni] = (floatx4){0.f, 0.f, 0.f, 0.f};

  for (int k0 = 0; k0 < K; k0 += 32) {
#pragma unroll
    for (int j = 0; j < 2; ++j) {
      const int s = w * 128 + j * 64 + l;          // slot id 0..511
      const int row = ((s >> 6) << 4) + (s & 15);  // 0..127
      const int q = (s >> 4) & 3;
      int ga = bm + row;
      ga = (ga < M) ? ga : (M - 1);                // clamp: keep lanes active
      gld_lds16(A + (size_t)ga * K + k0 + q * 8, sA + s * 16);
      gld_lds16(B + (size_t)(bn + row) * K + k0 + q * 8, sB + s * 16);
    }
    __syncthreads();
    half8 fa[4], fb[4];
#pragma unroll
    for (int mi = 0; mi < 4; ++mi)
      fa[mi] = *(const half8*)(sA + ((wm >> 4) + mi) * 1024 + l * 16);
#pragma unroll
    for (int ni = 0; ni < 4; ++ni)
      fb[ni] = *(const half8*)(sB + ((wn >> 4) + ni) * 1024 + l * 16);
#pragma unroll
    for (int mi = 0; mi < 4; ++mi)
#pragma unroll
      for (int ni = 0; ni < 4; ++ni)
        acc[mi][ni] = __builtin_amdgcn_mfma_f32_16x16x32_f16(fa[mi], fb[ni],
                                                             acc[mi][ni], 0, 0, 0);
    __syncthreads();
  }
  // epilogue: C/D layout col=lane&15, row=quad*4+reg
  const int colbase = bn + wn + lrow;
#pragma unroll
  for (int mi = 0; mi < 4; ++mi) {
    const int rbase = bm + wm + mi * 16 + quad * 4;
#pragma unroll
    for (int r = 0; r < 4; ++r) {
      const int grow = rbase + r;
      if (grow < M) {
        if constexpr (OUTF16) {
          _Float16* C = (_Float16*)Cv;
#pragma unroll
          for (int ni = 0; ni < 4; ++ni)
            C[(size_t)grow * N + colbase + ni * 16] = (_Float16)acc[mi][ni][r];
        } else {
          float* C = (float*)Cv;
#pragma unroll
          for (int ni = 0; ni < 4; ++ni)
            C[(size_t)grow * N + colbase + ni * 16] = acc[mi][ni][r];
        }
      }
    }
  }
}

// ------- all three weight transposes + f16 casts in one kernel --------
__global__ void wt_split_all(const float* __restrict__ W1, _Float16* Th1,
                             const float* __restrict__ W2, _Float16* Th2,
                             const float* __restrict__ W3, _Float16* Th3) {
  int idx = blockIdx.x * blockDim.x + threadIdx.x;
  const float* W;
  _Float16* Th;
  int K, N;
  if (idx < 64 * 512) {
    W = W1; Th = Th1; K = 64; N = 512;
  } else if (idx < 64 * 512 + 512 * 512) {
    idx -= 64 * 512;
    W = W2; Th = Th2; K = 512; N = 512;
  } else if (idx < 64 * 512 + 512 * 512 + 512 * 128) {
    idx -= 64 * 512 + 512 * 512;
    W = W3; Th = Th3; K = 512; N = 128;
  } else {
    return;
  }
  const int k = idx / N;
  const int n = idx - k * N;
  Th[n * K + k] = (_Float16)W[idx];
}

// ------- combined prep: both x casts + cnt=1 (2N) + total=0 -----------
__global__ void prep2(const float* __restrict__ x0, const float* __restrict__ x1,
                      _Float16* __restrict__ Xh, int* __restrict__ cnt,
                      int* __restrict__ total) {
  const int idx = blockIdx.x * blockDim.x + threadIdx.x;
  const int half = kN * 64;
  if (idx < half) Xh[idx] = (_Float16)x0[idx];
  else if (idx < 2 * half) Xh[idx] = (_Float16)x1[idx - half];
  if (idx < 2 * kN) cnt[idx] = 1;  // the self loop
  if (idx == 0) *total = 0;
}
// ------- single-encoder prep (fallback path) --------------------------
__global__ void prep(const float* __restrict__ X, _Float16* __restrict__ Xh,
                     int* __restrict__ cnt, int* __restrict__ total, int nsplit,
                     int n) {
  const int idx = blockIdx.x * blockDim.x + threadIdx.x;
  if (idx < nsplit) Xh[idx] = (_Float16)X[idx];
  if (idx < n) cnt[idx] = 1;
  if (idx == 0) *total = 0;
}

// ------- per-node attention dots (layers 1-2, f16 h) ------------------
__global__ void node_alpha8(const _Float16* __restrict__ h,
                            const float* __restrict__ a_src,
                            const float* __restrict__ a_dst,
                            float* __restrict__ asrc,
                            float* __restrict__ adst, int n_nodes) {
  const int gtid = blockIdx.x * blockDim.x + threadIdx.x;
  const int node = gtid >> 6;
  const int lane = threadIdx.x & 63;
  if (node >= n_nodes) return;
  const int head = lane >> 4;
  const half8 hv = *(const half8*)(h + (size_t)node * 512 + lane * 8);
  float s1 = 0.f, s2 = 0.f;
#pragma unroll
  for (int j = 0; j < 8; ++j) {
    const float v = (float)hv[j];
    s1 = fmaf(v, a_src[lane * 8 + j], s1);
    s2 = fmaf(v, a_dst[lane * 8 + j], s2);
  }
#pragma unroll
  for (int off = 1; off < 16; off <<= 1) {
    s1 += __shfl_xor(s1, off);
    s2 += __shfl_xor(s2, off);
  }
  if ((lane & 15) == 0) {
    asrc[node * 4 + head] = s1;
    adst[node * 4 + head] = s2;
  }
}

// ------- layer-3 alpha: dots over fp32 h [M,128] (H=1) ----------------
__global__ void node_alpha_l3(const float* __restrict__ h,
                              const float* __restrict__ a_src,
                              const float* __restrict__ a_dst,
                              float* __restrict__ asrc, float* __restrict__ adst,
                              int n_nodes) {
  const int gtid = blockIdx.x * blockDim.x + threadIdx.x;
  const int node = gtid >> 6;
  const int lane = threadIdx.x & 63;
  if (node >= n_nodes) return;
  const float2 v = *(const float2*)(h + (size_t)node * 128 + lane * 2);
  float s1 = fmaf(v.x, a_src[lane * 2], v.y * a_src[lane * 2 + 1]);
  float s2 = fmaf(v.x, a_dst[lane * 2], v.y * a_dst[lane * 2 + 1]);
#pragma unroll
  for (int off = 1; off < 64; off <<= 1) {
    s1 += __shfl_xor(s1, off);
    s2 += __shfl_xor(s2, off);
  }
  if (lane == 0) {
    asrc[node] = s1;
    adst[node] = s2;
  }
}

// ---------------- CSR (by dst) build ----------------------------------
// Combined: both encoders' edges in one dispatch.
__global__ void count_edges2(const int* __restrict__ d0, const int* __restrict__ d1,
                             int* __restrict__ cnt) {
  const int i = blockIdx.x * blockDim.x + threadIdx.x;
  if (i < kE) atomicAdd(&cnt[d0[i]], 1);
  else if (i < 2 * kE) atomicAdd(&cnt[d1[i - kE] + kN], 1);
}
__global__ void fill_edges2(const int* __restrict__ s0, const int* __restrict__ d0,
                            const int* __restrict__ s1, const int* __restrict__ d1,
                            int* __restrict__ cursor, int* __restrict__ csr) {
  const int i = blockIdx.x * blockDim.x + threadIdx.x;
  if (i < kE) {
    const int p = atomicAdd(&cursor[d0[i]], 1);
    csr[p] = s0[i];
  } else if (i < 2 * kE) {
    const int j = i - kE;
    const int p = atomicAdd(&cursor[d1[j] + kN], 1);
    csr[p] = s1[j] + kN;
  }
}
__global__ void count_edges(const int* __restrict__ dst, int* __restrict__ cnt,
                            int ne) {
  const int i = blockIdx.x * blockDim.x + threadIdx.x;
  if (i < ne) atomicAdd(&cnt[dst[i]], 1);
}
__global__ void fill_edges(const int* __restrict__ src, const int* __restrict__ dst,
                           int* __restrict__ cursor, int* __restrict__ csr, int ne) {
  const int i = blockIdx.x * blockDim.x + threadIdx.x;
  if (i < ne) {
    const int p = atomicAdd(&cursor[dst[i]], 1);
    csr[p] = src[i];
  }
}
__global__ void alloc_ranges(const int* __restrict__ cnt, int* __restrict__ start,
                             int* __restrict__ cursor, int* __restrict__ total,
                             int* __restrict__ csr, int n) {
  const int i = blockIdx.x * blockDim.x + threadIdx.x;
  const int lane = threadIdx.x & 63;
  const int v = (i < n) ? cnt[i] : 0;
  int sc = v;
#pragma unroll
  for (int off = 1; off < 64; off <<= 1) {
    const int t = __shfl_up(sc, off);
    if (lane >= off) sc += t;
  }
  const int wtot = __shfl(sc, 63);
  int base = 0;
  if (lane == 63) base = atomicAdd(total, wtot);
  base = __shfl(base, 63);
  const int st = base + sc - v;
  if (i < n) {
    start[i] = st;
    cursor[i] = st + 1;
    csr[st] = i;  // self loop first
  }
}

// ---------------- GAT aggregate, layers 1-2 (f16 h, fused scores) -----
__global__ void gat_agg4(const _Float16* __restrict__ h,
                         const float* __restrict__ asrc,
                         const float* __restrict__ adst,
                         const int* __restrict__ start, const int* __restrict__ cnt,
                         const int* __restrict__ csr_src,
                         const float* __restrict__ bias,
                         _Float16* __restrict__ outH, int n_nodes) {
  const int gtid = blockIdx.x * blockDim.x + threadIdx.x;
  const int node = gtid >> 6;
  const int lane = threadIdx.x & 63;
  if (node >= n_nodes) return;
  const int ch = lane * 8;
  const int head = lane >> 4;
  const int s = start[node];
  const int c = cnt[node];
  const float ad = adst[node * 4 + head];
  float a0[8], a1[8];
#pragma unroll
  for (int j = 0; j < 8; ++j) { a0[j] = 0.f; a1[j] = 0.f; }
  float d0 = 0.f, d1 = 0.f;
  int i = 0;
  for (; i + 2 <= c; i += 2) {
    const int s0 = csr_src[s + i];
    const int s1 = csr_src[s + i + 1];
    float e0 = asrc[s0 * 4 + head] + ad;
    float e1 = asrc[s1 * 4 + head] + ad;
    e0 = (e0 > 0.f) ? e0 : kNegSlope * e0;
    e1 = (e1 > 0.f) ? e1 : kNegSlope * e1;
    const float w0 = fexp(e0);
    const float w1 = fexp(e1);
    const half8 v0 = *(const half8*)(h + (size_t)s0 * 512 + ch);
    const half8 v1 = *(const half8*)(h + (size_t)s1 * 512 + ch);
    d0 += w0;
    d1 += w1;
#pragma unroll
    for (int j = 0; j < 8; ++j) {
      a0[j] = fmaf(w0, (float)v0[j], a0[j]);
      a1[j] = fmaf(w1, (float)v1[j], a1[j]);
    }
  }
  if (i < c) {
    const int s0 = csr_src[s + i];
    float e0 = asrc[s0 * 4 + head] + ad;
    e0 = (e0 > 0.f) ? e0 : kNegSlope * e0;
    const float w0 = fexp(e0);
    const half8 v0 = *(const half8*)(h + (size_t)s0 * 512 + ch);
    d0 += w0;
#pragma unroll
    for (int j = 0; j < 8; ++j) a0[j] = fmaf(w0, (float)v0[j], a0[j]);
  }
  const float inv = 1.f / (d0 + d1 + 1e-16f);
  half8 H;
#pragma unroll
  for (int j = 0; j < 8; ++j) {
    float v = (a0[j] + a1[j]) * inv + bias[ch + j];
    v = (v > 0.f) ? v : (fexp(v) - 1.f);  // elu via hw exp
    H[j] = (_Float16)v;
  }
  *(half8*)(outH + (size_t)node * 512 + ch) = H;
}

// ---------- GAT aggregate, layer 3 (H=1, fp32, fused scores) ----------
__global__ void gat_agg_l3(const float* __restrict__ h,
                           const float* __restrict__ asrc,
                           const float* __restrict__ adst,
                           const int* __restrict__ start, const int* __restrict__ cnt,
                           const int* __restrict__ csr_src,
                           const float* __restrict__ bias,
                           float* __restrict__ out, int n_nodes) {
  const int gtid = blockIdx.x * blockDim.x + threadIdx.x;
  const int node = gtid >> 6;
  const int lane = threadIdx.x & 63;
  if (node >= n_nodes) return;
  const int s = start[node];
  const int c = cnt[node];
  const float ad = adst[node];
  float2 a0 = make_float2(0.f, 0.f);
  float2 a1 = make_float2(0.f, 0.f);
  float d0 = 0.f, d1 = 0.f;
  int i = 0;
  for (; i + 2 <= c; i += 2) {
    const int s0 = csr_src[s + i];
    const int s1 = csr_src[s + i + 1];
    float e0 = asrc[s0] + ad;
    float e1 = asrc[s1] + ad;
    e0 = (e0 > 0.f) ? e0 : kNegSlope * e0;
    e1 = (e1 > 0.f) ? e1 : kNegSlope * e1;
    const float w0 = fexp(e0);
    const float w1 = fexp(e1);
    const float2 v0 = *(const float2*)(h + (size_t)s0 * 128 + lane * 2);
    const float2 v1 = *(const float2*)(h + (size_t)s1 * 128 + lane * 2);
    d0 += w0;
    d1 += w1;
    a0.x = fmaf(w0, v0.x, a0.x); a1.x = fmaf(w1, v1.x, a1.x);
    a0.y = fmaf(w0, v0.y, a0.y); a1.y = fmaf(w1, v1.y, a1.y);
  }
  if (i < c) {
    const int s0 = csr_src[s + i];
    float e0 = asrc[s0] + ad;
    e0 = (e0 > 0.f) ? e0 : kNegSlope * e0;
    const float w0 = fexp(e0);
    const float2 v0 = *(const float2*)(h + (size_t)s0 * 128 + lane * 2);
    d0 += w0;
    a0.x = fmaf(w0, v0.x, a0.x);
    a0.y = fmaf(w0, v0.y, a0.y);
  }
  const float inv = 1.f / (d0 + d1 + 1e-16f);
  *(float2*)(out + (size_t)node * 128 + lane * 2) =
      make_float2((a0.x + a1.x) * inv + bias[lane * 2],
                  (a0.y + a1.y) * inv + bias[lane * 2 + 1]);
}

// ---------------- global max pool over sorted batch -------------------
__global__ void pool_max(const float* __restrict__ x, const int* __restrict__ batch,
                         float* __restrict__ emb, int n_nodes) {
  __shared__ int lohi[2];
  const int g = blockIdx.x;
  if (threadIdx.x == 0) {
    int lo = 0, hi = n_nodes;
    while (lo < hi) {
      const int mid = (lo + hi) >> 1;
      if (batch[mid] < g) lo = mid + 1; else hi = mid;
    }
    lohi[0] = lo;
    hi = n_nodes;
    while (lo < hi) {
      const int mid = (lo + hi) >> 1;
      if (batch[mid] < g + 1) lo = mid + 1; else hi = mid;
    }
    lohi[1] = lo;
  }
  __syncthreads();
  const int lo = lohi[0], hi = lohi[1];
  const int c = threadIdx.x;  // 128 channels
  float m = -1e30f;
  for (int nid = lo; nid < hi; ++nid) m = fmaxf(m, x[(size_t)nid * 128 + c]);
  emb[g * 128 + c] = (lo < hi) ? m : 0.f;
}

// ---------------- final MLP head --------------------------------------
__global__ void mlp_head(const float* __restrict__ e1, const float* __restrict__ e2,
                         const float* __restrict__ mw1, const float* __restrict__ mb1,
                         const float* __restrict__ mw2, const float* __restrict__ mb2,
                         float* __restrict__ out) {
  __shared__ float z[256];
  __shared__ float red[128];
  const int g = blockIdx.x;
  const int j = threadIdx.x;  // 128
  z[j] = e1[g * 128 + j];
  z[j + 128] = e2[g * 128 + j];
  __syncthreads();
  float acc = mb1[j];
  for (int k = 0; k < 256; ++k) acc = fmaf(z[k], mw1[k * 128 + j], acc);
  acc = fmaxf(acc, 0.f) * mw2[j];
  red[j] = acc;
  __syncthreads();
  for (int s = 64; s > 0; s >>= 1) {
    if (j < s) red[j] += red[j + s];
    __syncthreads();
  }
  if (j == 0) out[g] = red[0] + mb2[0];
}

// ---------------- launcher --------------------------------------------
namespace {
struct Bufs {
  _Float16 *R1h, *R2h;
  float *R1f, *R2f, *asrc, *adst;
  int *cnt, *start, *cursor, *csr, *total;
  _Float16 *Wth1, *Wth2, *Wth3;
  float* emb;
  size_t need;
};

Bufs plan(void* d_ws, int M, int E) {
  Bufs b;
  char* w = (char*)d_ws;
  size_t off = 0;
  auto take = [&](size_t bytes) -> void* {
    void* p = w + off;
    off += (bytes + 255) & ~(size_t)255;
    return p;
  };
  b.R1h = (_Float16*)take((size_t)M * 512 * 2);  // f16 activations
  b.R1f = (float*)b.R1h;                         // layer-3 out alias [M,128]
  b.R2h = (_Float16*)take((size_t)M * 512 * 2);  // h f16; l3 fp32 alias
  b.R2f = (float*)b.R2h;
  b.asrc = (float*)take((size_t)M * 4 * 4);
  b.adst = (float*)take((size_t)M * 4 * 4);
  b.cnt = (int*)take((size_t)M * 4);
  b.start = (int*)take((size_t)M * 4);
  b.cursor = (int*)take((size_t)M * 4);
  b.csr = (int*)take((size_t)E * 4);
  b.total = (int*)take(256);
  b.Wth1 = (_Float16*)take((size_t)64 * 512 * 2);
  b.Wth2 = (_Float16*)take((size_t)512 * 512 * 2);
  b.Wth3 = (_Float16*)take((size_t)512 * 128 * 2);
  b.emb = (float*)take((size_t)2 * kG * 128 * 4);
  b.need = off;
  return b;
}

void run_layers(const Bufs& b, void* const* d_in, int M, hipStream_t stream) {
  const float* as1 = (const float*)d_in[7];
  const float* ad1 = (const float*)d_in[8];
  const float* b1 = (const float*)d_in[9];
  const float* as2 = (const float*)d_in[11];
  const float* ad2 = (const float*)d_in[12];
  const float* b2 = (const float*)d_in[13];
  const float* as3 = (const float*)d_in[15];
  const float* ad3 = (const float*)d_in[16];
  const float* b3 = (const float*)d_in[17];
  const int nodeBlocks = (M * 64) / 256;  // 1 wave/node
  const int MT = (M + 127) / 128;

  // layer 1: [M,64] @ [64,512], h -> f16 (A1h aliases R1h)
  gemm_f16<1, 4><<<MT * 4, 256, 0, stream>>>(b.R1h, b.Wth1, b.R2h, M, 512, 64);
  node_alpha8<<<nodeBlocks, 256, 0, stream>>>(b.R2h, as1, ad1, b.asrc, b.adst, M);
  gat_agg4<<<nodeBlocks, 256, 0, stream>>>(b.R2h, b.asrc, b.adst, b.start, b.cnt,
                                           b.csr, b1, b.R1h, M);
  // layer 2: [M,512] @ [512,512], h -> f16
  gemm_f16<1, 4><<<MT * 4, 256, 0, stream>>>(b.R1h, b.Wth2, b.R2h, M, 512, 512);
  node_alpha8<<<nodeBlocks, 256, 0, stream>>>(b.R2h, as2, ad2, b.asrc, b.adst, M);
  gat_agg4<<<nodeBlocks, 256, 0, stream>>>(b.R2h, b.asrc, b.adst, b.start, b.cnt,
                                           b.csr, b2, b.R1h, M);
  // layer 3: [M,512] @ [512,128], H=1, no elu, fp32 out
  gemm_f16<0, 1><<<MT, 256, 0, stream>>>(b.R1h, b.Wth3, b.R2f, M, 128, 512);
  node_alpha_l3<<<nodeBlocks, 256, 0, stream>>>(b.R2f, as3, ad3, b.asrc, b.adst, M);
  gat_agg_l3<<<nodeBlocks, 256, 0, stream>>>(b.R2f, b.asrc, b.adst, b.start, b.cnt,
                                             b.csr, b3, b.R1f, M);
}
}  // namespace

extern "C" void kernel_launch(void* const* d_in, const int* in_sizes, int n_in,
                              void* d_out, int out_size, void* d_ws, size_t ws_size,
                              hipStream_t stream) {
  (void)in_sizes; (void)n_in; (void)out_size;
  const float* W1 = (const float*)d_in[6];
  const float* W2 = (const float*)d_in[10];
  const float* W3 = (const float*)d_in[14];
  const float* mw1 = (const float*)d_in[18];
  const float* mb1 = (const float*)d_in[19];
  const float* mw2 = (const float*)d_in[20];
  const float* mb2 = (const float*)d_in[21];

  // Prefer combined (both encoders batched, M=2N) if it fits the workspace.
  Bufs bc = plan(d_ws, 2 * kN, 2 * kE2);
  const bool combined = bc.need <= ws_size;
  Bufs b = combined ? bc : plan(d_ws, kN, kE2);

  const int wtot = 64 * 512 + 512 * 512 + 512 * 128;
  wt_split_all<<<(wtot + 255) / 256, 256, 0, stream>>>(W1, b.Wth1, W2, b.Wth2, W3,
                                                       b.Wth3);
  if (combined) {
    const int M = 2 * kN;
    const int* ei0 = (const int*)d_in[1];
    const int* ei1 = (const int*)d_in[4];
    prep2<<<(2 * kN * 64 + 255) / 256, 256, 0, stream>>>(
        (const float*)d_in[0], (const float*)d_in[3], b.R1h, b.cnt, b.total);
    count_edges2<<<(2 * kE + 255) / 256, 256, 0, stream>>>(ei0 + kE, ei1 + kE,
                                                           b.cnt);
    alloc_ranges<<<(M + 255) / 256, 256, 0, stream>>>(b.cnt, b.start, b.cursor,
                                                      b.total, b.csr, M);
    fill_edges2<<<(2 * kE + 255) / 256, 256, 0, stream>>>(ei0, ei0 + kE, ei1,
                                                          ei1 + kE, b.cursor, b.csr);
    run_layers(b, d_in, M, stream);
    for (int enc = 0; enc < 2; ++enc) {
      const int* batch = (const int*)d_in[enc * 3 + 2];
      pool_max<<<kG, 128, 0, stream>>>(b.R1f + (size_t)enc * kN * 128, batch,
                                       b.emb + (size_t)enc * kG * 128, kN);
    }
  } else {
    for (int enc = 0; enc < 2; ++enc) {
      const float* x = (const float*)d_in[enc * 3 + 0];
      const int* ei = (const int*)d_in[enc * 3 + 1];
      const int* batch = (const int*)d_in[enc * 3 + 2];
      prep<<<(kN * 64 + 255) / 256, 256, 0, stream>>>(x, b.R1h, b.cnt, b.total,
                                                      kN * 64, kN);
      count_edges<<<(kE + 255) / 256, 256, 0, stream>>>(ei + kE, b.cnt, kE);
      alloc_ranges<<<(kN + 255) / 256, 256, 0, stream>>>(b.cnt, b.start, b.cursor,
                                                         b.total, b.csr, kN);
      fill_edges<<<(kE + 255) / 256, 256, 0, stream>>>(ei, ei + kE, b.cursor, b.csr,
                                                       kE);
      run_layers(b, d_in, kN, stream);
      pool_max<<<kG, 128, 0, stream>>>(b.R1f, batch, b.emb + (size_t)enc * kG * 128,
                                       kN);
    }
  }
  mlp_head<<<kG, 128, 0, stream>>>(b.emb, b.emb + (size_t)kG * 128, mw1, mb1, mw2,
                                   mb2, (float*)d_out);
}

// Round 13
// 726.734 us; speedup vs baseline: 1.6702x; 1.0382x over previous
//
#include <hip/hip_runtime.h>
#include <cstdint>

namespace {
constexpr int kN = 50000;          // nodes per encoder
constexpr int kE = 200000;         // directed edges per encoder (pre self-loop)
constexpr int kE2 = kE + kN;       // with self loops (per encoder)
constexpr int kG = 256;            // graphs per encoder
constexpr float kNegSlope = 0.2f;
}

using half8   = __attribute__((ext_vector_type(8))) _Float16;
using floatx4 = __attribute__((ext_vector_type(4))) float;

__device__ __forceinline__ void gld_lds16(const void* g, void* l) {
  __builtin_amdgcn_global_load_lds(
      (const __attribute__((address_space(1))) unsigned int*)g,
      (__attribute__((address_space(3))) unsigned int*)l, 16, 0, 0);
}

// fast exp: e^x = 2^(x*log2(e)) via hardware v_exp_f32 (no libm call)
__device__ __forceinline__ float fexp(float x) {
  return __builtin_amdgcn_exp2f(x * 1.44269504088896f);
}

// ---------------- fp16 MFMA GEMM: C[M,N] = A[M,K] @ B[K,N] -----------
// Single-product fp16 (fp32 accumulate). A row-major f16 [M,K]; B
// pre-transposed f16 [N,K]. 128x128 tile, BK=32, 256 threads = 4 waves.
// NT=4: XCD-aware swizzle — blocks land on XCD (id%8); giving row-tile
// r=(s>>2)*8+(id&7), col=s&3 (s=id>>3) puts all 4 col-tiles of a row on
// ONE XCD (ids differ by 8) so A is filled into one L2 once (R12 FETCH
// was 2xA: col-tiles spread across non-coherent per-XCD L2s).
// __launch_bounds__(256,4): cap 128 regs/wave (acc=64 is half) => 4
// waves/SIMD instead of 3 (R12: 72+64=136 regs -> 28% occupancy).
template <int OUTF16, int NT>
__global__ __launch_bounds__(256, 4) void gemm_f16(
    const _Float16* __restrict__ A, const _Float16* __restrict__ B,
    void* __restrict__ Cv, int M, int N, int K) {
  __shared__ alignas(16) char smem[16384];
  char* sA = smem;
  char* sB = smem + 8192;
  const int t = threadIdx.x;
  const int w = t >> 6;
  const int l = t & 63;
  int bm, bn;
  if constexpr (NT == 1) {
    bm = blockIdx.x * 128;
    bn = 0;
  } else {  // NT == 4
    const int x = blockIdx.x & 7;
    const int s = blockIdx.x >> 3;
    bm = (((s >> 2) << 3) + x) * 128;
    bn = (s & 3) * 128;
    if (bm >= M) return;  // padded row-tiles (whole block exits: no barrier)
  }
  const int wm = (w & 1) * 64;
  const int wn = (w >> 1) * 64;
  const int quad = l >> 4;
  const int lrow = l & 15;

  floatx4 acc[4][4];
#pragma unroll
  for (int mi = 0; mi < 4; ++mi)
#pragma unroll
    for (int ni = 0; ni < 4; ++ni) acc[mi][ni] = (floatx4){0.f, 0.f, 0.f, 0.f};

  for (int k0 = 0; k0 < K; k0 += 32) {
#pragma unroll
    for (int j = 0; j < 2; ++j) {
      const int s = w * 128 + j * 64 + l;          // slot id 0..511
      const int row = ((s >> 6) << 4) + (s & 15);  // 0..127
      const int q = (s >> 4) & 3;
      int ga = bm + row;
      ga = (ga < M) ? ga : (M - 1);                // clamp: keep lanes active
      gld_lds16(A + (size_t)ga * K + k0 + q * 8, sA + s * 16);
      gld_lds16(B + (size_t)(bn + row) * K + k0 + q * 8, sB + s * 16);
    }
    __syncthreads();
    half8 fa[4], fb[4];
#pragma unroll
    for (int mi = 0; mi < 4; ++mi)
      fa[mi] = *(const half8*)(sA + ((wm >> 4) + mi) * 1024 + l * 16);
#pragma unroll
    for (int ni = 0; ni < 4; ++ni)
      fb[ni] = *(const half8*)(sB + ((wn >> 4) + ni) * 1024 + l * 16);
#pragma unroll
    for (int mi = 0; mi < 4; ++mi)
#pragma unroll
      for (int ni = 0; ni < 4; ++ni)
        acc[mi][ni] = __builtin_amdgcn_mfma_f32_16x16x32_f16(fa[mi], fb[ni],
                                                             acc[mi][ni], 0, 0, 0);
    __syncthreads();
  }
  // epilogue: C/D layout col=lane&15, row=quad*4+reg
  const int colbase = bn + wn + lrow;
#pragma unroll
  for (int mi = 0; mi < 4; ++mi) {
    const int rbase = bm + wm + mi * 16 + quad * 4;
#pragma unroll
    for (int r = 0; r < 4; ++r) {
      const int grow = rbase + r;
      if (grow < M) {
        if constexpr (OUTF16) {
          _Float16* C = (_Float16*)Cv;
#pragma unroll
          for (int ni = 0; ni < 4; ++ni)
            C[(size_t)grow * N + colbase + ni * 16] = (_Float16)acc[mi][ni][r];
        } else {
          float* C = (float*)Cv;
#pragma unroll
          for (int ni = 0; ni < 4; ++ni)
            C[(size_t)grow * N + colbase + ni * 16] = acc[mi][ni][r];
        }
      }
    }
  }
}

// ------- all three weight transposes + f16 casts in one kernel --------
__global__ void wt_split_all(const float* __restrict__ W1, _Float16* Th1,
                             const float* __restrict__ W2, _Float16* Th2,
                             const float* __restrict__ W3, _Float16* Th3) {
  int idx = blockIdx.x * blockDim.x + threadIdx.x;
  const float* W;
  _Float16* Th;
  int K, N;
  if (idx < 64 * 512) {
    W = W1; Th = Th1; K = 64; N = 512;
  } else if (idx < 64 * 512 + 512 * 512) {
    idx -= 64 * 512;
    W = W2; Th = Th2; K = 512; N = 512;
  } else if (idx < 64 * 512 + 512 * 512 + 512 * 128) {
    idx -= 64 * 512 + 512 * 512;
    W = W3; Th = Th3; K = 512; N = 128;
  } else {
    return;
  }
  const int k = idx / N;
  const int n = idx - k * N;
  Th[n * K + k] = (_Float16)W[idx];
}

// ------- combined prep: both x casts + cnt=1 (2N) + total=0 -----------
__global__ void prep2(const float* __restrict__ x0, const float* __restrict__ x1,
                      _Float16* __restrict__ Xh, int* __restrict__ cnt,
                      int* __restrict__ total) {
  const int idx = blockIdx.x * blockDim.x + threadIdx.x;
  const int half = kN * 64;
  if (idx < half) Xh[idx] = (_Float16)x0[idx];
  else if (idx < 2 * half) Xh[idx] = (_Float16)x1[idx - half];
  if (idx < 2 * kN) cnt[idx] = 1;  // the self loop
  if (idx == 0) *total = 0;
}
// ------- single-encoder prep (fallback path) --------------------------
__global__ void prep(const float* __restrict__ X, _Float16* __restrict__ Xh,
                     int* __restrict__ cnt, int* __restrict__ total, int nsplit,
                     int n) {
  const int idx = blockIdx.x * blockDim.x + threadIdx.x;
  if (idx < nsplit) Xh[idx] = (_Float16)X[idx];
  if (idx < n) cnt[idx] = 1;
  if (idx == 0) *total = 0;
}

// ------- per-node attention dots (layers 1-2, f16 h) ------------------
__global__ void node_alpha8(const _Float16* __restrict__ h,
                            const float* __restrict__ a_src,
                            const float* __restrict__ a_dst,
                            float* __restrict__ asrc,
                            float* __restrict__ adst, int n_nodes) {
  const int gtid = blockIdx.x * blockDim.x + threadIdx.x;
  const int node = gtid >> 6;
  const int lane = threadIdx.x & 63;
  if (node >= n_nodes) return;
  const int head = lane >> 4;
  const half8 hv = *(const half8*)(h + (size_t)node * 512 + lane * 8);
  float s1 = 0.f, s2 = 0.f;
#pragma unroll
  for (int j = 0; j < 8; ++j) {
    const float v = (float)hv[j];
    s1 = fmaf(v, a_src[lane * 8 + j], s1);
    s2 = fmaf(v, a_dst[lane * 8 + j], s2);
  }
#pragma unroll
  for (int off = 1; off < 16; off <<= 1) {
    s1 += __shfl_xor(s1, off);
    s2 += __shfl_xor(s2, off);
  }
  if ((lane & 15) == 0) {
    asrc[node * 4 + head] = s1;
    adst[node * 4 + head] = s2;
  }
}

// ------- layer-3 alpha: dots over fp32 h [M,128] (H=1) ----------------
__global__ void node_alpha_l3(const float* __restrict__ h,
                              const float* __restrict__ a_src,
                              const float* __restrict__ a_dst,
                              float* __restrict__ asrc, float* __restrict__ adst,
                              int n_nodes) {
  const int gtid = blockIdx.x * blockDim.x + threadIdx.x;
  const int node = gtid >> 6;
  const int lane = threadIdx.x & 63;
  if (node >= n_nodes) return;
  const float2 v = *(const float2*)(h + (size_t)node * 128 + lane * 2);
  float s1 = fmaf(v.x, a_src[lane * 2], v.y * a_src[lane * 2 + 1]);
  float s2 = fmaf(v.x, a_dst[lane * 2], v.y * a_dst[lane * 2 + 1]);
#pragma unroll
  for (int off = 1; off < 64; off <<= 1) {
    s1 += __shfl_xor(s1, off);
    s2 += __shfl_xor(s2, off);
  }
  if (lane == 0) {
    asrc[node] = s1;
    adst[node] = s2;
  }
}

// ---------------- CSR (by dst) build ----------------------------------
__global__ void count_edges2(const int* __restrict__ d0, const int* __restrict__ d1,
                             int* __restrict__ cnt) {
  const int i = blockIdx.x * blockDim.x + threadIdx.x;
  if (i < kE) atomicAdd(&cnt[d0[i]], 1);
  else if (i < 2 * kE) atomicAdd(&cnt[d1[i - kE] + kN], 1);
}
__global__ void fill_edges2(const int* __restrict__ s0, const int* __restrict__ d0,
                            const int* __restrict__ s1, const int* __restrict__ d1,
                            int* __restrict__ cursor, int* __restrict__ csr) {
  const int i = blockIdx.x * blockDim.x + threadIdx.x;
  if (i < kE) {
    const int p = atomicAdd(&cursor[d0[i]], 1);
    csr[p] = s0[i];
  } else if (i < 2 * kE) {
    const int j = i - kE;
    const int p = atomicAdd(&cursor[d1[j] + kN], 1);
    csr[p] = s1[j] + kN;
  }
}
__global__ void count_edges(const int* __restrict__ dst, int* __restrict__ cnt,
                            int ne) {
  const int i = blockIdx.x * blockDim.x + threadIdx.x;
  if (i < ne) atomicAdd(&cnt[dst[i]], 1);
}
__global__ void fill_edges(const int* __restrict__ src, const int* __restrict__ dst,
                           int* __restrict__ cursor, int* __restrict__ csr, int ne) {
  const int i = blockIdx.x * blockDim.x + threadIdx.x;
  if (i < ne) {
    const int p = atomicAdd(&cursor[dst[i]], 1);
    csr[p] = src[i];
  }
}
__global__ void alloc_ranges(const int* __restrict__ cnt, int* __restrict__ start,
                             int* __restrict__ cursor, int* __restrict__ total,
                             int* __restrict__ csr, int n) {
  const int i = blockIdx.x * blockDim.x + threadIdx.x;
  const int lane = threadIdx.x & 63;
  const int v = (i < n) ? cnt[i] : 0;
  int sc = v;
#pragma unroll
  for (int off = 1; off < 64; off <<= 1) {
    const int t = __shfl_up(sc, off);
    if (lane >= off) sc += t;
  }
  const int wtot = __shfl(sc, 63);
  int base = 0;
  if (lane == 63) base = atomicAdd(total, wtot);
  base = __shfl(base, 63);
  const int st = base + sc - v;
  if (i < n) {
    start[i] = st;
    cursor[i] = st + 1;
    csr[st] = i;  // self loop first
  }
}

// ---------------- GAT aggregate, layers 1-2 (f16 h, fused scores) -----
__global__ void gat_agg4(const _Float16* __restrict__ h,
                         const float* __restrict__ asrc,
                         const float* __restrict__ adst,
                         const int* __restrict__ start, const int* __restrict__ cnt,
                         const int* __restrict__ csr_src,
                         const float* __restrict__ bias,
                         _Float16* __restrict__ outH, int n_nodes) {
  const int gtid = blockIdx.x * blockDim.x + threadIdx.x;
  const int node = gtid >> 6;
  const int lane = threadIdx.x & 63;
  if (node >= n_nodes) return;
  const int ch = lane * 8;
  const int head = lane >> 4;
  const int s = start[node];
  const int c = cnt[node];
  const float ad = adst[node * 4 + head];
  float a0[8], a1[8];
#pragma unroll
  for (int j = 0; j < 8; ++j) { a0[j] = 0.f; a1[j] = 0.f; }
  float d0 = 0.f, d1 = 0.f;
  int i = 0;
  for (; i + 2 <= c; i += 2) {
    const int s0 = csr_src[s + i];
    const int s1 = csr_src[s + i + 1];
    float e0 = asrc[s0 * 4 + head] + ad;
    float e1 = asrc[s1 * 4 + head] + ad;
    e0 = (e0 > 0.f) ? e0 : kNegSlope * e0;
    e1 = (e1 > 0.f) ? e1 : kNegSlope * e1;
    const float w0 = fexp(e0);
    const float w1 = fexp(e1);
    const half8 v0 = *(const half8*)(h + (size_t)s0 * 512 + ch);
    const half8 v1 = *(const half8*)(h + (size_t)s1 * 512 + ch);
    d0 += w0;
    d1 += w1;
#pragma unroll
    for (int j = 0; j < 8; ++j) {
      a0[j] = fmaf(w0, (float)v0[j], a0[j]);
      a1[j] = fmaf(w1, (float)v1[j], a1[j]);
    }
  }
  if (i < c) {
    const int s0 = csr_src[s + i];
    float e0 = asrc[s0 * 4 + head] + ad;
    e0 = (e0 > 0.f) ? e0 : kNegSlope * e0;
    const float w0 = fexp(e0);
    const half8 v0 = *(const half8*)(h + (size_t)s0 * 512 + ch);
    d0 += w0;
#pragma unroll
    for (int j = 0; j < 8; ++j) a0[j] = fmaf(w0, (float)v0[j], a0[j]);
  }
  const float inv = 1.f / (d0 + d1 + 1e-16f);
  half8 H;
#pragma unroll
  for (int j = 0; j < 8; ++j) {
    float v = (a0[j] + a1[j]) * inv + bias[ch + j];
    v = (v > 0.f) ? v : (fexp(v) - 1.f);  // elu via hw exp
    H[j] = (_Float16)v;
  }
  *(half8*)(outH + (size_t)node * 512 + ch) = H;
}

// ---------- GAT aggregate, layer 3 (H=1, fp32, fused scores) ----------
__global__ void gat_agg_l3(const float* __restrict__ h,
                           const float* __restrict__ asrc,
                           const float* __restrict__ adst,
                           const int* __restrict__ start, const int* __restrict__ cnt,
                           const int* __restrict__ csr_src,
                           const float* __restrict__ bias,
                           float* __restrict__ out, int n_nodes) {
  const int gtid = blockIdx.x * blockDim.x + threadIdx.x;
  const int node = gtid >> 6;
  const int lane = threadIdx.x & 63;
  if (node >= n_nodes) return;
  const int s = start[node];
  const int c = cnt[node];
  const float ad = adst[node];
  float2 a0 = make_float2(0.f, 0.f);
  float2 a1 = make_float2(0.f, 0.f);
  float d0 = 0.f, d1 = 0.f;
  int i = 0;
  for (; i + 2 <= c; i += 2) {
    const int s0 = csr_src[s + i];
    const int s1 = csr_src[s + i + 1];
    float e0 = asrc[s0] + ad;
    float e1 = asrc[s1] + ad;
    e0 = (e0 > 0.f) ? e0 : kNegSlope * e0;
    e1 = (e1 > 0.f) ? e1 : kNegSlope * e1;
    const float w0 = fexp(e0);
    const float w1 = fexp(e1);
    const float2 v0 = *(const float2*)(h + (size_t)s0 * 128 + lane * 2);
    const float2 v1 = *(const float2*)(h + (size_t)s1 * 128 + lane * 2);
    d0 += w0;
    d1 += w1;
    a0.x = fmaf(w0, v0.x, a0.x); a1.x = fmaf(w1, v1.x, a1.x);
    a0.y = fmaf(w0, v0.y, a0.y); a1.y = fmaf(w1, v1.y, a1.y);
  }
  if (i < c) {
    const int s0 = csr_src[s + i];
    float e0 = asrc[s0] + ad;
    e0 = (e0 > 0.f) ? e0 : kNegSlope * e0;
    const float w0 = fexp(e0);
    const float2 v0 = *(const float2*)(h + (size_t)s0 * 128 + lane * 2);
    d0 += w0;
    a0.x = fmaf(w0, v0.x, a0.x);
    a0.y = fmaf(w0, v0.y, a0.y);
  }
  const float inv = 1.f / (d0 + d1 + 1e-16f);
  *(float2*)(out + (size_t)node * 128 + lane * 2) =
      make_float2((a0.x + a1.x) * inv + bias[lane * 2],
                  (a0.y + a1.y) * inv + bias[lane * 2 + 1]);
}

// ---------------- global max pool over sorted batch -------------------
__global__ void pool_max(const float* __restrict__ x, const int* __restrict__ batch,
                         float* __restrict__ emb, int n_nodes) {
  __shared__ int lohi[2];
  const int g = blockIdx.x;
  if (threadIdx.x == 0) {
    int lo = 0, hi = n_nodes;
    while (lo < hi) {
      const int mid = (lo + hi) >> 1;
      if (batch[mid] < g) lo = mid + 1; else hi = mid;
    }
    lohi[0] = lo;
    hi = n_nodes;
    while (lo < hi) {
      const int mid = (lo + hi) >> 1;
      if (batch[mid] < g + 1) lo = mid + 1; else hi = mid;
    }
    lohi[1] = lo;
  }
  __syncthreads();
  const int lo = lohi[0], hi = lohi[1];
  const int c = threadIdx.x;  // 128 channels
  float m = -1e30f;
  for (int nid = lo; nid < hi; ++nid) m = fmaxf(m, x[(size_t)nid * 128 + c]);
  emb[g * 128 + c] = (lo < hi) ? m : 0.f;
}

// ---------------- final MLP head --------------------------------------
__global__ void mlp_head(const float* __restrict__ e1, const float* __restrict__ e2,
                         const float* __restrict__ mw1, const float* __restrict__ mb1,
                         const float* __restrict__ mw2, const float* __restrict__ mb2,
                         float* __restrict__ out) {
  __shared__ float z[256];
  __shared__ float red[128];
  const int g = blockIdx.x;
  const int j = threadIdx.x;  // 128
  z[j] = e1[g * 128 + j];
  z[j + 128] = e2[g * 128 + j];
  __syncthreads();
  float acc = mb1[j];
  for (int k = 0; k < 256; ++k) acc = fmaf(z[k], mw1[k * 128 + j], acc);
  acc = fmaxf(acc, 0.f) * mw2[j];
  red[j] = acc;
  __syncthreads();
  for (int s = 64; s > 0; s >>= 1) {
    if (j < s) red[j] += red[j + s];
    __syncthreads();
  }
  if (j == 0) out[g] = red[0] + mb2[0];
}

// ---------------- launcher --------------------------------------------
namespace {
struct Bufs {
  _Float16 *R1h, *R2h;
  float *R1f, *R2f, *asrc, *adst;
  int *cnt, *start, *cursor, *csr, *total;
  _Float16 *Wth1, *Wth2, *Wth3;
  float* emb;
  size_t need;
};

Bufs plan(void* d_ws, int M, int E) {
  Bufs b;
  char* w = (char*)d_ws;
  size_t off = 0;
  auto take = [&](size_t bytes) -> void* {
    void* p = w + off;
    off += (bytes + 255) & ~(size_t)255;
    return p;
  };
  b.R1h = (_Float16*)take((size_t)M * 512 * 2);  // f16 activations
  b.R1f = (float*)b.R1h;                         // layer-3 out alias [M,128]
  b.R2h = (_Float16*)take((size_t)M * 512 * 2);  // h f16; l3 fp32 alias
  b.R2f = (float*)b.R2h;
  b.asrc = (float*)take((size_t)M * 4 * 4);
  b.adst = (float*)take((size_t)M * 4 * 4);
  b.cnt = (int*)take((size_t)M * 4);
  b.start = (int*)take((size_t)M * 4);
  b.cursor = (int*)take((size_t)M * 4);
  b.csr = (int*)take((size_t)E * 4);
  b.total = (int*)take(256);
  b.Wth1 = (_Float16*)take((size_t)64 * 512 * 2);
  b.Wth2 = (_Float16*)take((size_t)512 * 512 * 2);
  b.Wth3 = (_Float16*)take((size_t)512 * 128 * 2);
  b.emb = (float*)take((size_t)2 * kG * 128 * 4);
  b.need = off;
  return b;
}

void run_layers(const Bufs& b, void* const* d_in, int M, hipStream_t stream) {
  const float* as1 = (const float*)d_in[7];
  const float* ad1 = (const float*)d_in[8];
  const float* b1 = (const float*)d_in[9];
  const float* as2 = (const float*)d_in[11];
  const float* ad2 = (const float*)d_in[12];
  const float* b2 = (const float*)d_in[13];
  const float* as3 = (const float*)d_in[15];
  const float* ad3 = (const float*)d_in[16];
  const float* b3 = (const float*)d_in[17];
  const int nodeBlocks = (M * 64) / 256;  // 1 wave/node
  const int MT = (M + 127) / 128;
  const int MTp = (MT + 7) & ~7;          // pad rows to multiple of 8 (XCD map)

  // layer 1: [M,64] @ [64,512], h -> f16 (A1h aliases R1h)
  gemm_f16<1, 4><<<MTp * 4, 256, 0, stream>>>(b.R1h, b.Wth1, b.R2h, M, 512, 64);
  node_alpha8<<<nodeBlocks, 256, 0, stream>>>(b.R2h, as1, ad1, b.asrc, b.adst, M);
  gat_agg4<<<nodeBlocks, 256, 0, stream>>>(b.R2h, b.asrc, b.adst, b.start, b.cnt,
                                           b.csr, b1, b.R1h, M);
  // layer 2: [M,512] @ [512,512], h -> f16
  gemm_f16<1, 4><<<MTp * 4, 256, 0, stream>>>(b.R1h, b.Wth2, b.R2h, M, 512, 512);
  node_alpha8<<<nodeBlocks, 256, 0, stream>>>(b.R2h, as2, ad2, b.asrc, b.adst, M);
  gat_agg4<<<nodeBlocks, 256, 0, stream>>>(b.R2h, b.asrc, b.adst, b.start, b.cnt,
                                           b.csr, b2, b.R1h, M);
  // layer 3: [M,512] @ [512,128], H=1, no elu, fp32 out
  gemm_f16<0, 1><<<MT, 256, 0, stream>>>(b.R1h, b.Wth3, b.R2f, M, 128, 512);
  node_alpha_l3<<<nodeBlocks, 256, 0, stream>>>(b.R2f, as3, ad3, b.asrc, b.adst, M);
  gat_agg_l3<<<nodeBlocks, 256, 0, stream>>>(b.R2f, b.asrc, b.adst, b.start, b.cnt,
                                             b.csr, b3, b.R1f, M);
}
}  // namespace

extern "C" void kernel_launch(void* const* d_in, const int* in_sizes, int n_in,
                              void* d_out, int out_size, void* d_ws, size_t ws_size,
                              hipStream_t stream) {
  (void)in_sizes; (void)n_in; (void)out_size;
  const float* W1 = (const float*)d_in[6];
  const float* W2 = (const float*)d_in[10];
  const float* W3 = (const float*)d_in[14];
  const float* mw1 = (const float*)d_in[18];
  const float* mb1 = (const float*)d_in[19];
  const float* mw2 = (const float*)d_in[20];
  const float* mb2 = (const float*)d_in[21];

  // Prefer combined (both encoders batched, M=2N) if it fits the workspace.
  Bufs bc = plan(d_ws, 2 * kN, 2 * kE2);
  const bool combined = bc.need <= ws_size;
  Bufs b = combined ? bc : plan(d_ws, kN, kE2);

  const int wtot = 64 * 512 + 512 * 512 + 512 * 128;
  wt_split_all<<<(wtot + 255) / 256, 256, 0, stream>>>(W1, b.Wth1, W2, b.Wth2, W3,
                                                       b.Wth3);
  if (combined) {
    const int M = 2 * kN;
    const int* ei0 = (const int*)d_in[1];
    const int* ei1 = (const int*)d_in[4];
    prep2<<<(2 * kN * 64 + 255) / 256, 256, 0, stream>>>(
        (const float*)d_in[0], (const float*)d_in[3], b.R1h, b.cnt, b.total);
    count_edges2<<<(2 * kE + 255) / 256, 256, 0, stream>>>(ei0 + kE, ei1 + kE,
                                                           b.cnt);
    alloc_ranges<<<(M + 255) / 256, 256, 0, stream>>>(b.cnt, b.start, b.cursor,
                                                      b.total, b.csr, M);
    fill_edges2<<<(2 * kE + 255) / 256, 256, 0, stream>>>(ei0, ei0 + kE, ei1,
                                                          ei1 + kE, b.cursor, b.csr);
    run_layers(b, d_in, M, stream);
    for (int enc = 0; enc < 2; ++enc) {
      const int* batch = (const int*)d_in[enc * 3 + 2];
      pool_max<<<kG, 128, 0, stream>>>(b.R1f + (size_t)enc * kN * 128, batch,
                                       b.emb + (size_t)enc * kG * 128, kN);
    }
  } else {
    for (int enc = 0; enc < 2; ++enc) {
      const float* x = (const float*)d_in[enc * 3 + 0];
      const int* ei = (const int*)d_in[enc * 3 + 1];
      const int* batch = (const int*)d_in[enc * 3 + 2];
      prep<<<(kN * 64 + 255) / 256, 256, 0, stream>>>(x, b.R1h, b.cnt, b.total,
                                                      kN * 64, kN);
      count_edges<<<(kE + 255) / 256, 256, 0, stream>>>(ei + kE, b.cnt, kE);
      alloc_ranges<<<(kN + 255) / 256, 256, 0, stream>>>(b.cnt, b.start, b.cursor,
                                                         b.total, b.csr, kN);
      fill_edges<<<(kE + 255) / 256, 256, 0, stream>>>(ei, ei + kE, b.cursor, b.csr,
                                                       kE);
      run_layers(b, d_in, kN, stream);
      pool_max<<<kG, 128, 0, stream>>>(b.R1f, batch, b.emb + (size_t)enc * kG * 128,
                                       kN);
    }
  }
  mlp_head<<<kG, 128, 0, stream>>>(b.emb, b.emb + (size_t)kG * 128, mw1, mb1, mw2,
                                   mb2, (float*)d_out);
}